// Round 4
// baseline (2631.738 us; speedup 1.0000x reference)
//
#include <hip/hip_runtime.h>
#include <type_traits>

typedef unsigned short u16;
typedef __bf16 bf16x8 __attribute__((ext_vector_type(8)));
typedef unsigned short u16x8 __attribute__((ext_vector_type(8)));
typedef unsigned short u16x4 __attribute__((ext_vector_type(4)));
typedef float f32x4 __attribute__((ext_vector_type(4)));

#define DEV __device__ __forceinline__

DEV u16 f2bf(float f) {
  unsigned u = __float_as_uint(f);
  u += 0x7fff + ((u >> 16) & 1);  // RNE
  return (u16)(u >> 16);
}
DEV float bf2f(u16 h) { return __uint_as_float((unsigned)h << 16); }

struct bfpair { u16 hi, lo; };
DEV bfpair split2(float v) {
  bfpair p;
  p.hi = f2bf(v);
  p.lo = f2bf(v - bf2f(p.hi));
  return p;
}

DEV f32x4 mfma_bf16(bf16x8 a, bf16x8 b, f32x4 c) {
  return __builtin_amdgcn_mfma_f32_16x16x32_bf16(a, b, c, 0, 0, 0);
}

DEV void gl2lds16(const u16* g, u16* l) {
  __builtin_amdgcn_global_load_lds((const __attribute__((address_space(1))) void*)g,
                                   (__attribute__((address_space(3))) void*)l, 16, 0, 0);
}

// ---------------- weight transpose + hi/lo split:  W[K,N] -> Whi/Wlo[n*K+k] ----------------
__global__ __launch_bounds__(256)
void wsplit_kernel(const float* __restrict__ W, u16* __restrict__ Whi,
                   u16* __restrict__ Wlo, int K, int N) {
  const int total = N * K;
  for (int i = blockIdx.x * 256 + threadIdx.x; i < total; i += gridDim.x * 256) {
    int n = i / K, k = i - n * K;
    bfpair p = split2(W[(size_t)k * N + n]);
    Whi[i] = p.hi;
    Wlo[i] = p.lo;
  }
}

// single-precision transposed weight (for proj_s)
__global__ __launch_bounds__(256)
void wT_kernel(const float* __restrict__ W, u16* __restrict__ WT, int K, int N) {
  const int total = N * K;
  for (int i = blockIdx.x * 256 + threadIdx.x; i < total; i += gridDim.x * 256) {
    int n = i / K, k = i - n * K;
    WT[i] = f2bf(W[(size_t)k * N + n]);
  }
}

// ---------------- per-row LN stats (rows of 512 fp32): stat[row] = {mean, rstd} ----------------
__global__ __launch_bounds__(256)
void lnstat_kernel(const float* __restrict__ X, float2* __restrict__ st) {
  const int row = (blockIdx.x << 2) + (threadIdx.x >> 6);
  const int l = threadIdx.x & 63;
  const float* x = X + ((size_t)row << 9) + l * 8;
  float v[8];
  *(float4*)&v[0] = *(const float4*)(x);
  *(float4*)&v[4] = *(const float4*)(x + 4);
  float s = 0.f, s2 = 0.f;
#pragma unroll
  for (int e = 0; e < 8; ++e) { s += v[e]; s2 += v[e] * v[e]; }
#pragma unroll
  for (int o = 1; o < 64; o <<= 1) { s += __shfl_xor(s, o, 64); s2 += __shfl_xor(s2, o, 64); }
  if (l == 0) {
    float mean = s * (1.f / 512.f);
    float rs = rsqrtf(s2 * (1.f / 512.f) - mean * mean + 1e-5f);
    st[row] = make_float2(mean, rs);
  }
}

// ---------------- split (3-term hi/lo) 128x128xBK64 GEMM, optional fused LN on A ----------------
// C = A_eff[M,K] * B^T  where B pre-split hi/lo bf16 [N][K].
// QKV==0: Cf fp32 (ldc) + bias.
// QKV==1: cols<1024 -> Cf fp32 (ld 1024); cols>=1024 -> Cv bf16 (ld 512).   [temporal qkv]
// QKV==2: cols<1024 -> Cq bf16 (ld 1024); cols>=1024 -> Cv bf16 (ld 512).   [spatial qkv]
template <bool LNA, int QKV>
__global__ __launch_bounds__(256)
void gemm_split(const float* __restrict__ Af, const u16* __restrict__ Bhi,
                const u16* __restrict__ Blo, const float2* __restrict__ st,
                const float* __restrict__ lng, const float* __restrict__ lnb,
                float* __restrict__ Cf, u16* __restrict__ Cq, u16* __restrict__ Cv,
                const float* __restrict__ bias, int lda, int ldb, int ldc, int K) {
  __shared__ u16 lsAh[128 * 64];
  __shared__ u16 lsAl[128 * 64];
  __shared__ u16 lsBh[128 * 64];
  __shared__ u16 lsBl[128 * 64];
  const int tid = threadIdx.x;
  const int w = tid >> 6, l = tid & 63;
  const int lr = l & 15, lg = l >> 4;
  const int wm = w >> 1, wn = w & 1;
  const int Row0 = blockIdx.x * 128, Col0 = blockIdx.y * 128;
  const int r0 = tid >> 4;          // A-stage row base
  const int col0 = (tid * 4) & 63;  // A-stage col base

  float2 stc[8];
  if (LNA) {
#pragma unroll
    for (int j = 0; j < 8; ++j) stc[j] = st[Row0 + j * 16 + r0];
  }

  f32x4 acc[4][4];
  const f32x4 zero = {0.f, 0.f, 0.f, 0.f};
#pragma unroll
  for (int m = 0; m < 4; ++m)
#pragma unroll
    for (int n = 0; n < 4; ++n) acc[m][n] = zero;

  for (int k0 = 0; k0 < K; k0 += 64) {
    __syncthreads();
    float4 g4, b4;
    if (LNA) {
      g4 = *(const float4*)(lng + k0 + col0);
      b4 = *(const float4*)(lnb + k0 + col0);
    }
#pragma unroll
    for (int j = 0; j < 8; ++j) {
      int row = j * 16 + r0;
      float4 v = *(const float4*)(Af + (size_t)(Row0 + row) * lda + k0 + col0);
      if (LNA) {
        float m = stc[j].x, rs = stc[j].y;
        v.x = (v.x - m) * rs * g4.x + b4.x;
        v.y = (v.y - m) * rs * g4.y + b4.y;
        v.z = (v.z - m) * rs * g4.z + b4.z;
        v.w = (v.w - m) * rs * g4.w + b4.w;
      }
      bfpair px = split2(v.x), py = split2(v.y), pz = split2(v.z), pw = split2(v.w);
      u16x4 hi = {px.hi, py.hi, pz.hi, pw.hi};
      u16x4 lo = {px.lo, py.lo, pz.lo, pw.lo};
      *(u16x4*)&lsAh[j * 1024 + tid * 4] = hi;
      *(u16x4*)&lsAl[j * 1024 + tid * 4] = lo;
    }
#pragma unroll
    for (int i = 0; i < 4; ++i) {
      int row = w * 32 + i * 8 + (l >> 3);
      int colb = (l & 7) * 8;
      gl2lds16(Bhi + (size_t)(Col0 + row) * ldb + k0 + colb, &lsBh[w * 2048 + i * 512]);
      gl2lds16(Blo + (size_t)(Col0 + row) * ldb + k0 + colb, &lsBl[w * 2048 + i * 512]);
    }
    __syncthreads();
#pragma unroll
    for (int kk = 0; kk < 64; kk += 32) {
      bf16x8 ah[4], al[4], bh[4], bl[4];
#pragma unroll
      for (int m = 0; m < 4; ++m) {
        ah[m] = *(const bf16x8*)&lsAh[(wm * 64 + m * 16 + lr) * 64 + kk + 8 * lg];
        al[m] = *(const bf16x8*)&lsAl[(wm * 64 + m * 16 + lr) * 64 + kk + 8 * lg];
      }
#pragma unroll
      for (int n = 0; n < 4; ++n) {
        bh[n] = *(const bf16x8*)&lsBh[(wn * 64 + n * 16 + lr) * 64 + kk + 8 * lg];
        bl[n] = *(const bf16x8*)&lsBl[(wn * 64 + n * 16 + lr) * 64 + kk + 8 * lg];
      }
#pragma unroll
      for (int m = 0; m < 4; ++m)
#pragma unroll
        for (int n = 0; n < 4; ++n) {
          acc[m][n] = mfma_bf16(al[m], bh[n], acc[m][n]);
          acc[m][n] = mfma_bf16(ah[m], bl[n], acc[m][n]);
          acc[m][n] = mfma_bf16(ah[m], bh[n], acc[m][n]);
        }
    }
  }

#pragma unroll
  for (int m = 0; m < 4; ++m)
#pragma unroll
    for (int n = 0; n < 4; ++n) {
      int gc = Col0 + wn * 64 + n * 16 + lr;
#pragma unroll
      for (int r = 0; r < 4; ++r) {
        int gr = Row0 + wm * 64 + m * 16 + lg * 4 + r;
        float v = acc[m][n][r];
        if constexpr (QKV == 1) {
          if (Col0 < 1024)
            Cf[(size_t)gr * 1024 + gc] = v;
          else
            Cv[(size_t)gr * 512 + gc - 1024] = f2bf(v);
        } else if constexpr (QKV == 2) {
          if (Col0 < 1024)
            Cq[(size_t)gr * 1024 + gc] = f2bf(v);
          else
            Cv[(size_t)gr * 512 + gc - 1024] = f2bf(v);
        } else {
          Cf[(size_t)gr * ldc + gc] = v + (bias ? bias[gc] : 0.f);
        }
      }
    }
}

// ---------------- single-precision 128x128x64 GEMM, B^T operand, batched ----------------
template <typename OUT_T, bool A_FP32, bool B_FP32>
__global__ __launch_bounds__(256)
void gemm_bt(const void* __restrict__ Av, const void* __restrict__ Bv,
             OUT_T* __restrict__ C, const float* __restrict__ bias,
             int lda, int ldb, int ldc, int K,
             long long sA, long long sB, long long sC, float scale) {
  __shared__ u16 lsA[128 * 64];
  __shared__ u16 lsB[128 * 64];
  const int tid = threadIdx.x;
  const int w = tid >> 6, l = tid & 63;
  const int lr = l & 15, lg = l >> 4;
  const int wm = w >> 1, wn = w & 1;
  const int Row0 = blockIdx.x * 128, Col0 = blockIdx.y * 128;
  const int bz = blockIdx.z;

  const u16* Ab16 = A_FP32 ? nullptr : (const u16*)Av + (size_t)bz * sA;
  const float* Af32 = A_FP32 ? (const float*)Av + (size_t)bz * sA : nullptr;
  const u16* Bb16 = B_FP32 ? nullptr : (const u16*)Bv + (size_t)bz * sB;
  const float* Bf32 = B_FP32 ? (const float*)Bv + (size_t)bz * sB : nullptr;

  f32x4 acc[4][4];
  const f32x4 zero = {0.f, 0.f, 0.f, 0.f};
#pragma unroll
  for (int m = 0; m < 4; ++m)
#pragma unroll
    for (int n = 0; n < 4; ++n) acc[m][n] = zero;

  for (int k0 = 0; k0 < K; k0 += 64) {
    __syncthreads();
    if constexpr (A_FP32) {
#pragma unroll
      for (int j = 0; j < 8; ++j) {
        int e = j * 1024 + tid * 4;
        int row = e >> 6, col = e & 63;
        float4 v = *(const float4*)(Af32 + (size_t)(Row0 + row) * lda + k0 + col);
        u16x4 o = {f2bf(v.x), f2bf(v.y), f2bf(v.z), f2bf(v.w)};
        *(u16x4*)&lsA[e] = o;
      }
    } else {
#pragma unroll
      for (int i = 0; i < 4; ++i) {
        int row = w * 32 + i * 8 + (l >> 3);
        int col = (l & 7) * 8;
        gl2lds16(Ab16 + (size_t)(Row0 + row) * lda + k0 + col, &lsA[w * 2048 + i * 512]);
      }
    }
    if constexpr (B_FP32) {
#pragma unroll
      for (int j = 0; j < 8; ++j) {
        int e = j * 1024 + tid * 4;
        int row = e >> 6, col = e & 63;
        float4 v = *(const float4*)(Bf32 + (size_t)(Col0 + row) * ldb + k0 + col);
        u16x4 o = {f2bf(v.x), f2bf(v.y), f2bf(v.z), f2bf(v.w)};
        *(u16x4*)&lsB[e] = o;
      }
    } else {
#pragma unroll
      for (int i = 0; i < 4; ++i) {
        int row = w * 32 + i * 8 + (l >> 3);
        int col = (l & 7) * 8;
        gl2lds16(Bb16 + (size_t)(Col0 + row) * ldb + k0 + col, &lsB[w * 2048 + i * 512]);
      }
    }
    __syncthreads();
#pragma unroll
    for (int kk = 0; kk < 64; kk += 32) {
      bf16x8 af[4], bfv[4];
#pragma unroll
      for (int m = 0; m < 4; ++m)
        af[m] = *(const bf16x8*)&lsA[(wm * 64 + m * 16 + lr) * 64 + kk + 8 * lg];
#pragma unroll
      for (int n = 0; n < 4; ++n)
        bfv[n] = *(const bf16x8*)&lsB[(wn * 64 + n * 16 + lr) * 64 + kk + 8 * lg];
#pragma unroll
      for (int m = 0; m < 4; ++m)
#pragma unroll
        for (int n = 0; n < 4; ++n) acc[m][n] = mfma_bf16(af[m], bfv[n], acc[m][n]);
    }
  }

  OUT_T* Cb = C + (size_t)bz * sC;
#pragma unroll
  for (int m = 0; m < 4; ++m)
#pragma unroll
    for (int n = 0; n < 4; ++n) {
      int gc = Col0 + wn * 64 + n * 16 + lr;
      float bv = bias ? bias[gc] : 0.f;
#pragma unroll
      for (int r = 0; r < 4; ++r) {
        int gr = Row0 + wm * 64 + m * 16 + lg * 4 + r;
        float v = acc[m][n][r] * scale + bv;
        if constexpr (std::is_same<OUT_T, u16>::value)
          Cb[(size_t)gr * ldc + gc] = f2bf(v);
        else
          Cb[(size_t)gr * ldc + gc] = v;
      }
    }
}

// ---------------- fused temporal attention (split QK^T, hi/lo P), one block per c; per-b ------
// QK: [t*1024+c][1024] fp32 (q|k), Vb: [t*1024+c][512] bf16, O: [t*1024+c][512] fp32
__global__ __launch_bounds__(256)
void attn_t_kernel(const float* __restrict__ QK, const u16* __restrict__ Vb,
                   float* __restrict__ O) {
  __shared__ u16 qh[32 * 264], ql[32 * 264];
  __shared__ u16 kh[32 * 264], kl[32 * 264];
  __shared__ u16 vT[512 * 40];
  __shared__ float Sf[32 * 32];
  __shared__ u16 Ph[32 * 40], Pl[32 * 40];

  const int tid = threadIdx.x;
  const int c = blockIdx.x;
  const int w = tid >> 6, l = tid & 63, lr = l & 15, lg = l >> 4;
  const int wr = w >> 1, wc = w & 1;

  f32x4 sacc = {0.f, 0.f, 0.f, 0.f};
  for (int kc = 0; kc < 512; kc += 256) {
    if (kc) __syncthreads();
#pragma unroll
    for (int j = 0; j < 8; ++j) {
      int e = j * 1024 + tid * 4;
      int t = e >> 8, col = e & 255;
      const float* rb = QK + ((size_t)(t << 10) + c) * 1024;
      float4 q4 = *(const float4*)(rb + kc + col);
      float4 k4 = *(const float4*)(rb + 512 + kc + col);
      bfpair q0 = split2(q4.x), q1 = split2(q4.y), q2 = split2(q4.z), q3 = split2(q4.w);
      bfpair k0 = split2(k4.x), k1 = split2(k4.y), k2 = split2(k4.z), k3 = split2(k4.w);
      u16x4 hq = {q0.hi, q1.hi, q2.hi, q3.hi};
      u16x4 lq = {q0.lo, q1.lo, q2.lo, q3.lo};
      u16x4 hk = {k0.hi, k1.hi, k2.hi, k3.hi};
      u16x4 lk = {k0.lo, k1.lo, k2.lo, k3.lo};
      *(u16x4*)&qh[t * 264 + col] = hq;
      *(u16x4*)&ql[t * 264 + col] = lq;
      *(u16x4*)&kh[t * 264 + col] = hk;
      *(u16x4*)&kl[t * 264 + col] = lk;
    }
    if (kc == 0) {
#pragma unroll
      for (int j = 0; j < 8; ++j) {
        int li = j * 2048 + tid * 8;
        int t = li >> 9, col = li & 511;
        u16x8 vv = *(const u16x8*)(Vb + ((size_t)(t << 10) + c) * 512 + col);
#pragma unroll
        for (int e = 0; e < 8; ++e) vT[(col + e) * 40 + t] = vv[e];
      }
    }
    __syncthreads();
#pragma unroll
    for (int kk = 0; kk < 256; kk += 32) {
      bf16x8 ah = *(const bf16x8*)&qh[(wr * 16 + lr) * 264 + kk + 8 * lg];
      bf16x8 al = *(const bf16x8*)&ql[(wr * 16 + lr) * 264 + kk + 8 * lg];
      bf16x8 bh = *(const bf16x8*)&kh[(wc * 16 + lr) * 264 + kk + 8 * lg];
      bf16x8 bl = *(const bf16x8*)&kl[(wc * 16 + lr) * 264 + kk + 8 * lg];
      sacc = mfma_bf16(al, bh, sacc);
      sacc = mfma_bf16(ah, bl, sacc);
      sacc = mfma_bf16(ah, bh, sacc);
    }
  }
#pragma unroll
  for (int r = 0; r < 4; ++r)
    Sf[(wr * 16 + lg * 4 + r) * 32 + wc * 16 + lr] = sacc[r] * 0.125f;
  __syncthreads();

  if (tid < 32) {
    float mx = -1e30f;
    for (int j = 0; j < 32; ++j) mx = fmaxf(mx, Sf[tid * 32 + j]);
    float s = 0.f;
    for (int j = 0; j < 32; ++j) s += __expf(Sf[tid * 32 + j] - mx);
    float inv = 1.f / s;
    for (int j = 0; j < 32; ++j) {
      float p = __expf(Sf[tid * 32 + j] - mx) * inv;
      bfpair pp = split2(p);
      Ph[tid * 40 + j] = pp.hi;
      Pl[tid * 40 + j] = pp.lo;
    }
  }
  __syncthreads();

  {
    const int mr = w >> 1, nh = w & 1;
    bf16x8 aph = *(const bf16x8*)&Ph[(mr * 16 + lr) * 40 + 8 * lg];
    bf16x8 apl = *(const bf16x8*)&Pl[(mr * 16 + lr) * 40 + 8 * lg];
#pragma unroll
    for (int j = 0; j < 16; ++j) {
      int nc = (nh * 16 + j) * 16;
      bf16x8 bv = *(const bf16x8*)&vT[(nc + lr) * 40 + 8 * lg];
      f32x4 o = {0.f, 0.f, 0.f, 0.f};
      o = mfma_bf16(apl, bv, o);
      o = mfma_bf16(aph, bv, o);
#pragma unroll
      for (int r = 0; r < 4; ++r) {
        int t = mr * 16 + lg * 4 + r;
        O[((size_t)(t << 10) + c) * 512 + nc + lr] = o[r];
      }
    }
  }
}

// ---------------- row softmax over 1024 fp32, in place ----------------
__global__ __launch_bounds__(256)
void softmax_kernel(float* __restrict__ S) {
  float* p = S + ((size_t)blockIdx.x << 10);
  const int tid = threadIdx.x, w = tid >> 6, l = tid & 63;
  __shared__ float red[8];
  float4 v = *(float4*)&p[tid << 2];
  float m = fmaxf(fmaxf(v.x, v.y), fmaxf(v.z, v.w));
#pragma unroll
  for (int o = 1; o < 64; o <<= 1) m = fmaxf(m, __shfl_xor(m, o, 64));
  if (l == 0) red[w] = m;
  __syncthreads();
  m = fmaxf(fmaxf(red[0], red[1]), fmaxf(red[2], red[3]));
  v.x = __expf(v.x - m); v.y = __expf(v.y - m);
  v.z = __expf(v.z - m); v.w = __expf(v.w - m);
  float s = v.x + v.y + v.z + v.w;
#pragma unroll
  for (int o = 1; o < 64; o <<= 1) s += __shfl_xor(s, o, 64);
  if (l == 0) red[4 + w] = s;
  __syncthreads();
  const float inv = 1.f / (red[4] + red[5] + red[6] + red[7]);
  v.x *= inv; v.y *= inv; v.z *= inv; v.w *= inv;
  *(float4*)&p[tid << 2] = v;
}

// ---------------- V transpose per (b,t): Vt[bt][d][c] = Vb[bt*1024+c][d] ----------------
__global__ __launch_bounds__(256)
void transpose_v_kernel(const u16* __restrict__ Vb, u16* __restrict__ Vt) {
  __shared__ u16 tl[64][72];
  const int bt = blockIdx.z;
  const int c0 = blockIdx.x << 6, d0 = blockIdx.y << 6;
  const int tid = threadIdx.x;
#pragma unroll
  for (int pass = 0; pass < 2; ++pass) {
    int r = (pass << 5) + (tid >> 3), cc = (tid & 7) << 3;
    *(u16x8*)&tl[r][cc] = *(const u16x8*)(Vb + ((size_t)(bt * 1024 + c0 + r)) * 512 + d0 + cc);
  }
  __syncthreads();
#pragma unroll
  for (int pass = 0; pass < 2; ++pass) {
    int rd = (pass << 5) + (tid >> 3), cc = (tid & 7) << 3;
    u16x8 o;
#pragma unroll
    for (int e = 0; e < 8; ++e) o[e] = tl[cc + e][rd];
    *(u16x8*)(Vt + ((size_t)(bt * 512 + d0 + rd)) * 1024 + c0 + cc) = o;
  }
}

extern "C" void kernel_launch(void* const* d_in, const int* in_sizes, int n_in,
                              void* d_out, int out_size, void* d_ws, size_t ws_size,
                              hipStream_t stream) {
  (void)in_sizes; (void)n_in; (void)out_size; (void)ws_size;
  const float* x      = (const float*)d_in[0];
  const float* gam_t  = (const float*)d_in[1];
  const float* bet_t  = (const float*)d_in[2];
  const float* wqkv_t = (const float*)d_in[3];
  const float* wout_t = (const float*)d_in[4];
  const float* bout_t = (const float*)d_in[5];
  const float* gam_s  = (const float*)d_in[6];
  const float* bet_s  = (const float*)d_in[7];
  const float* wqkv_s = (const float*)d_in[8];
  const float* wout_s = (const float*)d_in[9];
  const float* bout_s = (const float*)d_in[10];
  float* out = (float*)d_out;

  char* ws = (char*)d_ws;
  size_t off = 0;
  auto alloc = [&](size_t bytes) -> char* {
    char* p = ws + off;
    off = (off + bytes + 255) & ~(size_t)255;
    return p;
  };
  // Total ~369 MiB (fits 512 MiB workspace; round-3's 536 MiB overflowed).
  u16* wqkvT_t = (u16*)alloc((size_t)2 * 1536 * 512 * 2);   // hi | lo   3 MiB
  u16* woutT_t = (u16*)alloc((size_t)2 * 512 * 512 * 2);    //           1 MiB
  u16* wqkvT_s = (u16*)alloc((size_t)2 * 1536 * 512 * 2);   //           3 MiB
  u16* woutT_s = (u16*)alloc((size_t)512 * 512 * 2);        // single    0.5 MiB
  float2* stat = (float2*)alloc((size_t)65536 * 8);         //           0.5 MiB
  char* QKbuf  = alloc((size_t)128 * 1024 * 1024);          // union: per-b fp32 qk / full bf16 qk
  u16* Vb      = (u16*)alloc((size_t)65536 * 512 * 2);      //          64 MiB
  float* attnO = (float*)alloc((size_t)65536 * 512 * 4);    //         128 MiB
  float* S     = (float*)alloc((size_t)8 * 1024 * 1024 * 4);//          32 MiB
  u16* vT      = (u16*)alloc((size_t)8 * 512 * 1024 * 2);   //           8 MiB

  const size_t WQKV_NK = (size_t)1536 * 512;
  const size_t WOUT_NK = (size_t)512 * 512;
  const dim3 blk(256);

  wsplit_kernel<<<768, blk, 0, stream>>>(wqkv_t, wqkvT_t, wqkvT_t + WQKV_NK, 512, 1536);
  wsplit_kernel<<<256, blk, 0, stream>>>(wout_t, woutT_t, woutT_t + WOUT_NK, 512, 512);
  wsplit_kernel<<<768, blk, 0, stream>>>(wqkv_s, wqkvT_s, wqkvT_s + WQKV_NK, 512, 1536);
  wT_kernel<<<256, blk, 0, stream>>>(wout_s, woutT_s, 512, 512);

  // ---- temporal (chunked per b: qk fp32 chunk = 128 MiB) ----
  lnstat_kernel<<<16384, blk, 0, stream>>>(x, stat);
  float* QKt = (float*)QKbuf;  // [32768][1024] fp32 per b
  for (int b = 0; b < 2; ++b) {
    const float* xb = x + (size_t)b * 32768 * 512;
    gemm_split<true, 1><<<dim3(256, 12, 1), blk, 0, stream>>>(
        xb, wqkvT_t, wqkvT_t + WQKV_NK, stat + (size_t)b * 32768, gam_t, bet_t,
        QKt, nullptr, Vb + (size_t)b * 32768 * 512, nullptr, 512, 512, 0, 512);
    attn_t_kernel<<<1024, blk, 0, stream>>>(
        QKt, Vb + (size_t)b * 32768 * 512, attnO + (size_t)b * 32768 * 512);
  }
  gemm_split<false, 0><<<dim3(512, 4, 1), blk, 0, stream>>>(
      attnO, woutT_t, woutT_t + WOUT_NK, nullptr, nullptr, nullptr,
      out, nullptr, nullptr, bout_t, 512, 512, 512, 512);

  // ---- spatial (qk single bf16, full 128 MiB in QKbuf) ----
  lnstat_kernel<<<16384, blk, 0, stream>>>(out, stat);
  u16* QKs = (u16*)QKbuf;  // [65536][1024] bf16 (q|k)
  gemm_split<true, 2><<<dim3(512, 12, 1), blk, 0, stream>>>(
      out, wqkvT_s, wqkvT_s + WQKV_NK, stat, gam_s, bet_s,
      nullptr, QKs, Vb, nullptr, 512, 512, 0, 512);

  u16* attnOb = (u16*)attnO;
  for (int ch = 0; ch < 8; ++ch) {  // 8 (b,t) batches per chunk
    const u16* qkc = QKs + (size_t)ch * 8 * 1024 * 1024;
    const u16* vbc = Vb + (size_t)ch * 8 * 1024 * 512;
    u16* attc = attnOb + (size_t)ch * 8 * 1024 * 512;
    transpose_v_kernel<<<dim3(16, 8, 8), blk, 0, stream>>>(vbc, vT);
    gemm_bt<float, false, false><<<dim3(8, 8, 8), blk, 0, stream>>>(
        qkc, qkc + 512, S, nullptr, 1024, 1024, 1024, 512,
        1024LL * 1024, 1024LL * 1024, 1024LL * 1024, 0.125f);
    softmax_kernel<<<8192, blk, 0, stream>>>(S);
    gemm_bt<u16, true, false><<<dim3(8, 4, 8), blk, 0, stream>>>(
        S, vT, attc, nullptr, 1024, 1024, 512, 1024,
        1024LL * 1024, 512LL * 1024, 1024LL * 512, 1.f);
  }

  gemm_bt<float, false, false><<<dim3(512, 4, 1), blk, 0, stream>>>(
      attnOb, woutT_s, out, bout_s, 512, 512, 512, 512, 0, 0, 0, 1.f);
}

// Round 5
// 1732.776 us; speedup vs baseline: 1.5188x; 1.5188x over previous
//
#include <hip/hip_runtime.h>
#include <type_traits>

typedef unsigned short u16;
typedef __bf16 bf16x8 __attribute__((ext_vector_type(8)));
typedef unsigned short u16x8 __attribute__((ext_vector_type(8)));
typedef unsigned short u16x4 __attribute__((ext_vector_type(4)));
typedef float f32x4 __attribute__((ext_vector_type(4)));

#define DEV __device__ __forceinline__

DEV u16 f2bf(float f) {
  unsigned u = __float_as_uint(f);
  u += 0x7fff + ((u >> 16) & 1);  // RNE
  return (u16)(u >> 16);
}
DEV float bf2f(u16 h) { return __uint_as_float((unsigned)h << 16); }

struct bfpair { u16 hi, lo; };
DEV bfpair split2(float v) {
  bfpair p;
  p.hi = f2bf(v);
  p.lo = f2bf(v - bf2f(p.hi));
  return p;
}

DEV f32x4 mfma_bf16(bf16x8 a, bf16x8 b, f32x4 c) {
  return __builtin_amdgcn_mfma_f32_16x16x32_bf16(a, b, c, 0, 0, 0);
}

DEV void gl2lds16(const u16* g, u16* l) {
  __builtin_amdgcn_global_load_lds((const __attribute__((address_space(1))) void*)g,
                                   (__attribute__((address_space(3))) void*)l, 16, 0, 0);
}

// LDS tile [128 rows][64 u16], XOR-swizzled: physical col = col ^ ((row&7)<<3).
// 16B granules spread across banks -> ds_read_b128 fragment reads go 16-way -> 2-way.
DEV int swz(int row, int col) { return row * 64 + (col ^ ((row & 7) << 3)); }

// ---------------- weight transpose + hi/lo split:  W[K,N] -> Whi/Wlo[n*K+k] ----------------
__global__ __launch_bounds__(256)
void wsplit_kernel(const float* __restrict__ W, u16* __restrict__ Whi,
                   u16* __restrict__ Wlo, int K, int N) {
  const int total = N * K;
  for (int i = blockIdx.x * 256 + threadIdx.x; i < total; i += gridDim.x * 256) {
    int n = i / K, k = i - n * K;
    bfpair p = split2(W[(size_t)k * N + n]);
    Whi[i] = p.hi;
    Wlo[i] = p.lo;
  }
}

// single-precision transposed weight (for proj_s)
__global__ __launch_bounds__(256)
void wT_kernel(const float* __restrict__ W, u16* __restrict__ WT, int K, int N) {
  const int total = N * K;
  for (int i = blockIdx.x * 256 + threadIdx.x; i < total; i += gridDim.x * 256) {
    int n = i / K, k = i - n * K;
    WT[i] = f2bf(W[(size_t)k * N + n]);
  }
}

// ---------------- per-row LN stats (rows of 512 fp32): stat[row] = {mean, rstd} ----------------
__global__ __launch_bounds__(256)
void lnstat_kernel(const float* __restrict__ X, float2* __restrict__ st) {
  const int row = (blockIdx.x << 2) + (threadIdx.x >> 6);
  const int l = threadIdx.x & 63;
  const float* x = X + ((size_t)row << 9) + l * 8;
  float v[8];
  *(float4*)&v[0] = *(const float4*)(x);
  *(float4*)&v[4] = *(const float4*)(x + 4);
  float s = 0.f, s2 = 0.f;
#pragma unroll
  for (int e = 0; e < 8; ++e) { s += v[e]; s2 += v[e] * v[e]; }
#pragma unroll
  for (int o = 1; o < 64; o <<= 1) { s += __shfl_xor(s, o, 64); s2 += __shfl_xor(s2, o, 64); }
  if (l == 0) {
    float mean = s * (1.f / 512.f);
    float rs = rsqrtf(s2 * (1.f / 512.f) - mean * mean + 1e-5f);
    st[row] = make_float2(mean, rs);
  }
}

// ---------------- split (3-term hi/lo) 128x128xBK64 GEMM, optional fused LN on A ----------------
// Row-tile = blockIdx.y, col-tile = blockIdx.x (x fastest -> consecutive blocks share A-tile).
// C = A_eff[M,K] * B^T  where B pre-split hi/lo bf16 [N][K].
// QKV==0: Cf fp32 (ldc) + bias.
// QKV==1: cols<1024 -> Cf fp32 (ld 1024); cols>=1024 -> Cv bf16 (ld 512).   [temporal qkv]
// QKV==2: cols<1024 -> Cq bf16 (ld 1024); cols>=1024 -> Cv bf16 (ld 512).   [spatial qkv]
template <bool LNA, int QKV>
__global__ __launch_bounds__(256)
void gemm_split(const float* __restrict__ Af, const u16* __restrict__ Bhi,
                const u16* __restrict__ Blo, const float2* __restrict__ st,
                const float* __restrict__ lng, const float* __restrict__ lnb,
                float* __restrict__ Cf, u16* __restrict__ Cq, u16* __restrict__ Cv,
                const float* __restrict__ bias, int lda, int ldb, int ldc, int K) {
  __shared__ u16 lsAh[128 * 64];
  __shared__ u16 lsAl[128 * 64];
  __shared__ u16 lsBh[128 * 64];
  __shared__ u16 lsBl[128 * 64];
  const int tid = threadIdx.x;
  const int w = tid >> 6, l = tid & 63;
  const int lr = l & 15, lg = l >> 4;
  const int wm = w >> 1, wn = w & 1;
  const int Row0 = blockIdx.y * 128, Col0 = blockIdx.x * 128;
  const int r0 = tid >> 4;          // A-stage row base (row = j*16 + r0)
  const int col0 = (tid * 4) & 63;  // A-stage col base
  const int scol = col0 ^ ((r0 & 7) << 3);       // swizzled store col for A-stage
  const int gcol = ((l & 7) ^ (l >> 3)) * 8;     // inverse-swizzled source col for gl2lds

  float2 stc[8];
  if (LNA) {
#pragma unroll
    for (int j = 0; j < 8; ++j) stc[j] = st[Row0 + j * 16 + r0];
  }

  f32x4 acc[4][4];
  const f32x4 zero = {0.f, 0.f, 0.f, 0.f};
#pragma unroll
  for (int m = 0; m < 4; ++m)
#pragma unroll
    for (int n = 0; n < 4; ++n) acc[m][n] = zero;

  // prologue: prefetch A(k0=0) into regs
  float4 areg[8];
#pragma unroll
  for (int j = 0; j < 8; ++j)
    areg[j] = *(const float4*)(Af + (size_t)(Row0 + j * 16 + r0) * lda + col0);

  for (int k0 = 0; k0 < K; k0 += 64) {
    __syncthreads();  // previous compute done with LDS
    // B staging first (async, overlaps A split/writes)
#pragma unroll
    for (int i = 0; i < 4; ++i) {
      int row = w * 32 + i * 8 + (l >> 3);
      gl2lds16(Bhi + (size_t)(Col0 + row) * ldb + k0 + gcol, &lsBh[w * 2048 + i * 512]);
      gl2lds16(Blo + (size_t)(Col0 + row) * ldb + k0 + gcol, &lsBl[w * 2048 + i * 512]);
    }
    float4 g4, b4;
    if (LNA) {
      g4 = *(const float4*)(lng + k0 + col0);
      b4 = *(const float4*)(lnb + k0 + col0);
    }
#pragma unroll
    for (int j = 0; j < 8; ++j) {
      int row = j * 16 + r0;
      float4 v = areg[j];
      if (LNA) {
        float m = stc[j].x, rs = stc[j].y;
        v.x = (v.x - m) * rs * g4.x + b4.x;
        v.y = (v.y - m) * rs * g4.y + b4.y;
        v.z = (v.z - m) * rs * g4.z + b4.z;
        v.w = (v.w - m) * rs * g4.w + b4.w;
      }
      bfpair px = split2(v.x), py = split2(v.y), pz = split2(v.z), pw = split2(v.w);
      u16x4 hi = {px.hi, py.hi, pz.hi, pw.hi};
      u16x4 lo = {px.lo, py.lo, pz.lo, pw.lo};
      *(u16x4*)&lsAh[row * 64 + scol] = hi;
      *(u16x4*)&lsAl[row * 64 + scol] = lo;
    }
    // prefetch next A-tile into regs (in flight across the barrier)
    if (k0 + 64 < K) {
#pragma unroll
      for (int j = 0; j < 8; ++j)
        areg[j] = *(const float4*)(Af + (size_t)(Row0 + j * 16 + r0) * lda + k0 + 64 + col0);
    }
    __syncthreads();  // staged tile visible
#pragma unroll
    for (int kk = 0; kk < 64; kk += 32) {
      bf16x8 ah[4], al[4], bh[4], bl[4];
#pragma unroll
      for (int m = 0; m < 4; ++m) {
        int ra = wm * 64 + m * 16 + lr;
        ah[m] = *(const bf16x8*)&lsAh[swz(ra, kk + 8 * lg)];
        al[m] = *(const bf16x8*)&lsAl[swz(ra, kk + 8 * lg)];
      }
#pragma unroll
      for (int n = 0; n < 4; ++n) {
        int rb = wn * 64 + n * 16 + lr;
        bh[n] = *(const bf16x8*)&lsBh[swz(rb, kk + 8 * lg)];
        bl[n] = *(const bf16x8*)&lsBl[swz(rb, kk + 8 * lg)];
      }
#pragma unroll
      for (int m = 0; m < 4; ++m)
#pragma unroll
        for (int n = 0; n < 4; ++n) {
          acc[m][n] = mfma_bf16(al[m], bh[n], acc[m][n]);
          acc[m][n] = mfma_bf16(ah[m], bl[n], acc[m][n]);
          acc[m][n] = mfma_bf16(ah[m], bh[n], acc[m][n]);
        }
    }
  }

#pragma unroll
  for (int m = 0; m < 4; ++m)
#pragma unroll
    for (int n = 0; n < 4; ++n) {
      int gc = Col0 + wn * 64 + n * 16 + lr;
#pragma unroll
      for (int r = 0; r < 4; ++r) {
        int gr = Row0 + wm * 64 + m * 16 + lg * 4 + r;
        float v = acc[m][n][r];
        if constexpr (QKV == 1) {
          if (Col0 < 1024)
            Cf[(size_t)gr * 1024 + gc] = v;
          else
            Cv[(size_t)gr * 512 + gc - 1024] = f2bf(v);
        } else if constexpr (QKV == 2) {
          if (Col0 < 1024)
            Cq[(size_t)gr * 1024 + gc] = f2bf(v);
          else
            Cv[(size_t)gr * 512 + gc - 1024] = f2bf(v);
        } else {
          Cf[(size_t)gr * ldc + gc] = v + (bias ? bias[gc] : 0.f);
        }
      }
    }
}

// ---------------- single-precision 128x128x64 GEMM, B^T bf16, batched ----------------
// Row-tile = blockIdx.y, col-tile = blockIdx.x. A bf16 (gl2lds) or fp32 (reg-prefetch staged).
template <typename OUT_T, bool A_FP32>
__global__ __launch_bounds__(256)
void gemm_bt(const void* __restrict__ Av, const u16* __restrict__ Bt,
             OUT_T* __restrict__ C, const float* __restrict__ bias,
             int lda, int ldb, int ldc, int K,
             long long sA, long long sB, long long sC, float scale) {
  __shared__ u16 lsA[128 * 64];
  __shared__ u16 lsB[128 * 64];
  const int tid = threadIdx.x;
  const int w = tid >> 6, l = tid & 63;
  const int lr = l & 15, lg = l >> 4;
  const int wm = w >> 1, wn = w & 1;
  const int Row0 = blockIdx.y * 128, Col0 = blockIdx.x * 128;
  const int bz = blockIdx.z;
  const int r0 = tid >> 4;
  const int col0 = (tid * 4) & 63;
  const int scol = col0 ^ ((r0 & 7) << 3);
  const int gcol = ((l & 7) ^ (l >> 3)) * 8;

  const u16* Ab16 = A_FP32 ? nullptr : (const u16*)Av + (size_t)bz * sA;
  const float* Af32 = A_FP32 ? (const float*)Av + (size_t)bz * sA : nullptr;
  const u16* Bb = Bt + (size_t)bz * sB;

  f32x4 acc[4][4];
  const f32x4 zero = {0.f, 0.f, 0.f, 0.f};
#pragma unroll
  for (int m = 0; m < 4; ++m)
#pragma unroll
    for (int n = 0; n < 4; ++n) acc[m][n] = zero;

  float4 areg[8];
  if constexpr (A_FP32) {
#pragma unroll
    for (int j = 0; j < 8; ++j)
      areg[j] = *(const float4*)(Af32 + (size_t)(Row0 + j * 16 + r0) * lda + col0);
  }

  for (int k0 = 0; k0 < K; k0 += 64) {
    __syncthreads();
#pragma unroll
    for (int i = 0; i < 4; ++i) {
      int row = w * 32 + i * 8 + (l >> 3);
      gl2lds16(Bb + (size_t)(Col0 + row) * ldb + k0 + gcol, &lsB[w * 2048 + i * 512]);
    }
    if constexpr (A_FP32) {
#pragma unroll
      for (int j = 0; j < 8; ++j) {
        int row = j * 16 + r0;
        float4 v = areg[j];
        u16x4 o = {f2bf(v.x), f2bf(v.y), f2bf(v.z), f2bf(v.w)};
        *(u16x4*)&lsA[row * 64 + scol] = o;
      }
      if (k0 + 64 < K) {
#pragma unroll
        for (int j = 0; j < 8; ++j)
          areg[j] = *(const float4*)(Af32 + (size_t)(Row0 + j * 16 + r0) * lda + k0 + 64 + col0);
      }
    } else {
#pragma unroll
      for (int i = 0; i < 4; ++i) {
        int row = w * 32 + i * 8 + (l >> 3);
        gl2lds16(Ab16 + (size_t)(Row0 + row) * lda + k0 + gcol, &lsA[w * 2048 + i * 512]);
      }
    }
    __syncthreads();
#pragma unroll
    for (int kk = 0; kk < 64; kk += 32) {
      bf16x8 af[4], bfv[4];
#pragma unroll
      for (int m = 0; m < 4; ++m)
        af[m] = *(const bf16x8*)&lsA[swz(wm * 64 + m * 16 + lr, kk + 8 * lg)];
#pragma unroll
      for (int n = 0; n < 4; ++n)
        bfv[n] = *(const bf16x8*)&lsB[swz(wn * 64 + n * 16 + lr, kk + 8 * lg)];
#pragma unroll
      for (int m = 0; m < 4; ++m)
#pragma unroll
        for (int n = 0; n < 4; ++n) acc[m][n] = mfma_bf16(af[m], bfv[n], acc[m][n]);
    }
  }

  OUT_T* Cb = C + (size_t)bz * sC;
#pragma unroll
  for (int m = 0; m < 4; ++m)
#pragma unroll
    for (int n = 0; n < 4; ++n) {
      int gc = Col0 + wn * 64 + n * 16 + lr;
      float bv = bias ? bias[gc] : 0.f;
#pragma unroll
      for (int r = 0; r < 4; ++r) {
        int gr = Row0 + wm * 64 + m * 16 + lg * 4 + r;
        float v = acc[m][n][r] * scale + bv;
        if constexpr (std::is_same<OUT_T, u16>::value)
          Cb[(size_t)gr * ldc + gc] = f2bf(v);
        else
          Cb[(size_t)gr * ldc + gc] = v;
      }
    }
}

// ---------------- fused temporal attention (split QK^T, hi/lo P), one block per c; per-b ------
// QK: [t*1024+c][1024] fp32 (q|k), Vb: [t*1024+c][512] bf16, O: [t*1024+c][512] fp32
__global__ __launch_bounds__(256)
void attn_t_kernel(const float* __restrict__ QK, const u16* __restrict__ Vb,
                   float* __restrict__ O) {
  __shared__ u16 qh[32 * 264], ql[32 * 264];
  __shared__ u16 kh[32 * 264], kl[32 * 264];
  __shared__ u16 vT[512 * 40];
  __shared__ float Sf[32 * 32];
  __shared__ u16 Ph[32 * 40], Pl[32 * 40];

  const int tid = threadIdx.x;
  const int c = blockIdx.x;
  const int w = tid >> 6, l = tid & 63, lr = l & 15, lg = l >> 4;
  const int wr = w >> 1, wc = w & 1;

  f32x4 sacc = {0.f, 0.f, 0.f, 0.f};
  for (int kc = 0; kc < 512; kc += 256) {
    if (kc) __syncthreads();
#pragma unroll
    for (int j = 0; j < 8; ++j) {
      int e = j * 1024 + tid * 4;
      int t = e >> 8, col = e & 255;
      const float* rb = QK + ((size_t)(t << 10) + c) * 1024;
      float4 q4 = *(const float4*)(rb + kc + col);
      float4 k4 = *(const float4*)(rb + 512 + kc + col);
      bfpair q0 = split2(q4.x), q1 = split2(q4.y), q2 = split2(q4.z), q3 = split2(q4.w);
      bfpair k0 = split2(k4.x), k1 = split2(k4.y), k2 = split2(k4.z), k3 = split2(k4.w);
      u16x4 hq = {q0.hi, q1.hi, q2.hi, q3.hi};
      u16x4 lq = {q0.lo, q1.lo, q2.lo, q3.lo};
      u16x4 hk = {k0.hi, k1.hi, k2.hi, k3.hi};
      u16x4 lk = {k0.lo, k1.lo, k2.lo, k3.lo};
      *(u16x4*)&qh[t * 264 + col] = hq;
      *(u16x4*)&ql[t * 264 + col] = lq;
      *(u16x4*)&kh[t * 264 + col] = hk;
      *(u16x4*)&kl[t * 264 + col] = lk;
    }
    if (kc == 0) {
#pragma unroll
      for (int j = 0; j < 8; ++j) {
        int li = j * 2048 + tid * 8;
        int t = li >> 9, col = li & 511;
        u16x8 vv = *(const u16x8*)(Vb + ((size_t)(t << 10) + c) * 512 + col);
#pragma unroll
        for (int e = 0; e < 8; ++e) vT[(col + e) * 40 + t] = vv[e];
      }
    }
    __syncthreads();
#pragma unroll
    for (int kk = 0; kk < 256; kk += 32) {
      bf16x8 ah = *(const bf16x8*)&qh[(wr * 16 + lr) * 264 + kk + 8 * lg];
      bf16x8 al = *(const bf16x8*)&ql[(wr * 16 + lr) * 264 + kk + 8 * lg];
      bf16x8 bh = *(const bf16x8*)&kh[(wc * 16 + lr) * 264 + kk + 8 * lg];
      bf16x8 bl = *(const bf16x8*)&kl[(wc * 16 + lr) * 264 + kk + 8 * lg];
      sacc = mfma_bf16(al, bh, sacc);
      sacc = mfma_bf16(ah, bl, sacc);
      sacc = mfma_bf16(ah, bh, sacc);
    }
  }
#pragma unroll
  for (int r = 0; r < 4; ++r)
    Sf[(wr * 16 + lg * 4 + r) * 32 + wc * 16 + lr] = sacc[r] * 0.125f;
  __syncthreads();

  if (tid < 32) {
    float mx = -1e30f;
    for (int j = 0; j < 32; ++j) mx = fmaxf(mx, Sf[tid * 32 + j]);
    float s = 0.f;
    for (int j = 0; j < 32; ++j) s += __expf(Sf[tid * 32 + j] - mx);
    float inv = 1.f / s;
    for (int j = 0; j < 32; ++j) {
      float p = __expf(Sf[tid * 32 + j] - mx) * inv;
      bfpair pp = split2(p);
      Ph[tid * 40 + j] = pp.hi;
      Pl[tid * 40 + j] = pp.lo;
    }
  }
  __syncthreads();

  {
    const int mr = w >> 1, nh = w & 1;
    bf16x8 aph = *(const bf16x8*)&Ph[(mr * 16 + lr) * 40 + 8 * lg];
    bf16x8 apl = *(const bf16x8*)&Pl[(mr * 16 + lr) * 40 + 8 * lg];
#pragma unroll
    for (int j = 0; j < 16; ++j) {
      int nc = (nh * 16 + j) * 16;
      bf16x8 bv = *(const bf16x8*)&vT[(nc + lr) * 40 + 8 * lg];
      f32x4 o = {0.f, 0.f, 0.f, 0.f};
      o = mfma_bf16(apl, bv, o);
      o = mfma_bf16(aph, bv, o);
#pragma unroll
      for (int r = 0; r < 4; ++r) {
        int t = mr * 16 + lg * 4 + r;
        O[((size_t)(t << 10) + c) * 512 + nc + lr] = o[r];
      }
    }
  }
}

// ---------------- row softmax over 1024 fp32, in place ----------------
__global__ __launch_bounds__(256)
void softmax_kernel(float* __restrict__ S) {
  float* p = S + ((size_t)blockIdx.x << 10);
  const int tid = threadIdx.x, w = tid >> 6, l = tid & 63;
  __shared__ float red[8];
  float4 v = *(float4*)&p[tid << 2];
  float m = fmaxf(fmaxf(v.x, v.y), fmaxf(v.z, v.w));
#pragma unroll
  for (int o = 1; o < 64; o <<= 1) m = fmaxf(m, __shfl_xor(m, o, 64));
  if (l == 0) red[w] = m;
  __syncthreads();
  m = fmaxf(fmaxf(red[0], red[1]), fmaxf(red[2], red[3]));
  v.x = __expf(v.x - m); v.y = __expf(v.y - m);
  v.z = __expf(v.z - m); v.w = __expf(v.w - m);
  float s = v.x + v.y + v.z + v.w;
#pragma unroll
  for (int o = 1; o < 64; o <<= 1) s += __shfl_xor(s, o, 64);
  if (l == 0) red[4 + w] = s;
  __syncthreads();
  const float inv = 1.f / (red[4] + red[5] + red[6] + red[7]);
  v.x *= inv; v.y *= inv; v.z *= inv; v.w *= inv;
  *(float4*)&p[tid << 2] = v;
}

// ---------------- V transpose per (b,t): Vt[bt][d][c] = Vb[bt*1024+c][d] ----------------
__global__ __launch_bounds__(256)
void transpose_v_kernel(const u16* __restrict__ Vb, u16* __restrict__ Vt) {
  __shared__ u16 tl[64][72];
  const int bt = blockIdx.z;
  const int c0 = blockIdx.x << 6, d0 = blockIdx.y << 6;
  const int tid = threadIdx.x;
#pragma unroll
  for (int pass = 0; pass < 2; ++pass) {
    int r = (pass << 5) + (tid >> 3), cc = (tid & 7) << 3;
    *(u16x8*)&tl[r][cc] = *(const u16x8*)(Vb + ((size_t)(bt * 1024 + c0 + r)) * 512 + d0 + cc);
  }
  __syncthreads();
#pragma unroll
  for (int pass = 0; pass < 2; ++pass) {
    int rd = (pass << 5) + (tid >> 3), cc = (tid & 7) << 3;
    u16x8 o;
#pragma unroll
    for (int e = 0; e < 8; ++e) o[e] = tl[cc + e][rd];
    *(u16x8*)(Vt + ((size_t)(bt * 512 + d0 + rd)) * 1024 + c0 + cc) = o;
  }
}

extern "C" void kernel_launch(void* const* d_in, const int* in_sizes, int n_in,
                              void* d_out, int out_size, void* d_ws, size_t ws_size,
                              hipStream_t stream) {
  (void)in_sizes; (void)n_in; (void)out_size; (void)ws_size;
  const float* x      = (const float*)d_in[0];
  const float* gam_t  = (const float*)d_in[1];
  const float* bet_t  = (const float*)d_in[2];
  const float* wqkv_t = (const float*)d_in[3];
  const float* wout_t = (const float*)d_in[4];
  const float* bout_t = (const float*)d_in[5];
  const float* gam_s  = (const float*)d_in[6];
  const float* bet_s  = (const float*)d_in[7];
  const float* wqkv_s = (const float*)d_in[8];
  const float* wout_s = (const float*)d_in[9];
  const float* bout_s = (const float*)d_in[10];
  float* out = (float*)d_out;

  char* ws = (char*)d_ws;
  size_t off = 0;
  auto alloc = [&](size_t bytes) -> char* {
    char* p = ws + off;
    off = (off + bytes + 255) & ~(size_t)255;
    return p;
  };
  // Total ~369 MiB.
  u16* wqkvT_t = (u16*)alloc((size_t)2 * 1536 * 512 * 2);   // hi | lo
  u16* woutT_t = (u16*)alloc((size_t)2 * 512 * 512 * 2);
  u16* wqkvT_s = (u16*)alloc((size_t)2 * 1536 * 512 * 2);
  u16* woutT_s = (u16*)alloc((size_t)512 * 512 * 2);        // single
  float2* stat = (float2*)alloc((size_t)65536 * 8);
  char* QKbuf  = alloc((size_t)128 * 1024 * 1024);          // union: per-b fp32 qk / full bf16 qk
  u16* Vb      = (u16*)alloc((size_t)65536 * 512 * 2);
  float* attnO = (float*)alloc((size_t)65536 * 512 * 4);
  float* S     = (float*)alloc((size_t)8 * 1024 * 1024 * 4);
  u16* vT      = (u16*)alloc((size_t)8 * 512 * 1024 * 2);

  const size_t WQKV_NK = (size_t)1536 * 512;
  const size_t WOUT_NK = (size_t)512 * 512;
  const dim3 blk(256);

  wsplit_kernel<<<768, blk, 0, stream>>>(wqkv_t, wqkvT_t, wqkvT_t + WQKV_NK, 512, 1536);
  wsplit_kernel<<<256, blk, 0, stream>>>(wout_t, woutT_t, woutT_t + WOUT_NK, 512, 512);
  wsplit_kernel<<<768, blk, 0, stream>>>(wqkv_s, wqkvT_s, wqkvT_s + WQKV_NK, 512, 1536);
  wT_kernel<<<256, blk, 0, stream>>>(wout_s, woutT_s, 512, 512);

  // ---- temporal (chunked per b: qk fp32 chunk = 128 MiB) ----
  lnstat_kernel<<<16384, blk, 0, stream>>>(x, stat);
  float* QKt = (float*)QKbuf;  // [32768][1024] fp32 per b
  for (int b = 0; b < 2; ++b) {
    const float* xb = x + (size_t)b * 32768 * 512;
    gemm_split<true, 1><<<dim3(12, 256, 1), blk, 0, stream>>>(
        xb, wqkvT_t, wqkvT_t + WQKV_NK, stat + (size_t)b * 32768, gam_t, bet_t,
        QKt, nullptr, Vb + (size_t)b * 32768 * 512, nullptr, 512, 512, 0, 512);
    attn_t_kernel<<<1024, blk, 0, stream>>>(
        QKt, Vb + (size_t)b * 32768 * 512, attnO + (size_t)b * 32768 * 512);
  }
  gemm_split<false, 0><<<dim3(4, 512, 1), blk, 0, stream>>>(
      attnO, woutT_t, woutT_t + WOUT_NK, nullptr, nullptr, nullptr,
      out, nullptr, nullptr, bout_t, 512, 512, 512, 512);

  // ---- spatial (qk single bf16, full 128 MiB in QKbuf) ----
  lnstat_kernel<<<16384, blk, 0, stream>>>(out, stat);
  u16* QKs = (u16*)QKbuf;  // [65536][1024] bf16 (q|k)
  gemm_split<true, 2><<<dim3(12, 512, 1), blk, 0, stream>>>(
      out, wqkvT_s, wqkvT_s + WQKV_NK, stat, gam_s, bet_s,
      nullptr, QKs, Vb, nullptr, 512, 512, 0, 512);

  u16* attnOb = (u16*)attnO;
  for (int ch = 0; ch < 8; ++ch) {  // 8 (b,t) batches per chunk
    const u16* qkc = QKs + (size_t)ch * 8 * 1024 * 1024;
    const u16* vbc = Vb + (size_t)ch * 8 * 1024 * 512;
    u16* attc = attnOb + (size_t)ch * 8 * 1024 * 512;
    transpose_v_kernel<<<dim3(16, 8, 8), blk, 0, stream>>>(vbc, vT);
    gemm_bt<float, false><<<dim3(8, 8, 8), blk, 0, stream>>>(
        qkc, qkc + 512, S, nullptr, 1024, 1024, 1024, 512,
        1024LL * 1024, 1024LL * 1024, 1024LL * 1024, 0.125f);
    softmax_kernel<<<8192, blk, 0, stream>>>(S);
    gemm_bt<u16, true><<<dim3(4, 8, 8), blk, 0, stream>>>(
        S, vT, attc, nullptr, 1024, 1024, 512, 1024,
        1024LL * 1024, 512LL * 1024, 1024LL * 512, 1.f);
  }

  gemm_bt<float, false><<<dim3(4, 512, 1), blk, 0, stream>>>(
      attnOb, woutT_s, out, bout_s, 512, 512, 512, 512, 0, 0, 0, 1.f);
}

// Round 6
// 1138.155 us; speedup vs baseline: 2.3123x; 1.5224x over previous
//
#include <hip/hip_runtime.h>
#include <type_traits>

typedef unsigned short u16;
typedef _Float16 f16;
typedef f16 f16x8 __attribute__((ext_vector_type(8)));
typedef unsigned short u16x8 __attribute__((ext_vector_type(8)));
typedef unsigned short u16x4 __attribute__((ext_vector_type(4)));
typedef float f32x4 __attribute__((ext_vector_type(4)));

#define DEV __device__ __forceinline__

DEV u16 f2h(float f) { return __builtin_bit_cast(u16, (f16)f); }  // RNE
DEV float h2f(u16 u) { return (float)__builtin_bit_cast(f16, u); }

DEV f32x4 mfma_f16(f16x8 a, f16x8 b, f32x4 c) {
  return __builtin_amdgcn_mfma_f32_16x16x32_f16(a, b, c, 0, 0, 0);
}
DEV f16x8 ldf16(const u16* p) { return *(const f16x8*)p; }

DEV void gl2lds16(const u16* g, u16* l) {
  __builtin_amdgcn_global_load_lds((const __attribute__((address_space(1))) void*)g,
                                   (__attribute__((address_space(3))) void*)l, 16, 0, 0);
}

// LDS tile [128 rows][64 u16], XOR-swizzled: physical col = col ^ ((row&7)<<3).
DEV int swz(int row, int col) { return row * 64 + (col ^ ((row & 7) << 3)); }

// XCD-chunked remap: dispatched linear id d (round-robins XCD = d&7) -> work id so each
// XCD owns a contiguous chunk; consecutive same-XCD slots walk cols of one A row-panel.
DEV int xcd_remap(int d, int nwg) { return (d & 7) * (nwg >> 3) + (d >> 3); }

// ---------------- weight transpose fp32 -> fp16:  W[K,N] -> WT[n*K+k] ----------------
__global__ __launch_bounds__(256)
void wT_kernel(const float* __restrict__ W, u16* __restrict__ WT, int K, int N) {
  const int total = N * K;
  for (int i = blockIdx.x * 256 + threadIdx.x; i < total; i += gridDim.x * 256) {
    int n = i / K, k = i - n * K;
    WT[i] = f2h(W[(size_t)k * N + n]);
  }
}

// ---------------- per-row LN stats (rows of 512 fp32): stat[row] = {mean, rstd} ----------------
__global__ __launch_bounds__(256)
void lnstat_kernel(const float* __restrict__ X, float2* __restrict__ st) {
  const int row = (blockIdx.x << 2) + (threadIdx.x >> 6);
  const int l = threadIdx.x & 63;
  const float* x = X + ((size_t)row << 9) + l * 8;
  float v[8];
  *(float4*)&v[0] = *(const float4*)(x);
  *(float4*)&v[4] = *(const float4*)(x + 4);
  float s = 0.f, s2 = 0.f;
#pragma unroll
  for (int e = 0; e < 8; ++e) { s += v[e]; s2 += v[e] * v[e]; }
#pragma unroll
  for (int o = 1; o < 64; o <<= 1) { s += __shfl_xor(s, o, 64); s2 += __shfl_xor(s2, o, 64); }
  if (l == 0) {
    float mean = s * (1.f / 512.f);
    float rs = rsqrtf(s2 * (1.f / 512.f) - mean * mean + 1e-5f);
    st[row] = make_float2(mean, rs);
  }
}

// ---------------- fused LN + fp16 GEMM 128x128xBK64 (qkv): C = LN(A) @ B^T ----------------
// A fp32 reg-prefetched; B fp16 [N=1536][K] via global_load_lds. Cols<1024 -> Cq, else -> Cv.
__global__ __launch_bounds__(256)
void gemm_ln(const float* __restrict__ Af, const u16* __restrict__ Bt,
             const float2* __restrict__ st, const float* __restrict__ lng,
             const float* __restrict__ lnb, u16* __restrict__ Cq, u16* __restrict__ Cv,
             int lda, int ldb, int K) {
  __shared__ u16 lsA[128 * 64];
  __shared__ u16 lsB[128 * 64];
  const int tid = threadIdx.x;
  const int w = tid >> 6, l = tid & 63;
  const int lr = l & 15, lg = l >> 4;
  const int wm = w >> 1, wn = w & 1;
  const int gx = gridDim.x;
  const int wk = xcd_remap(blockIdx.y * gx + blockIdx.x, gx * gridDim.y);
  const int Row0 = (wk / gx) * 128, Col0 = (wk % gx) * 128;
  const int r0 = tid >> 4;
  const int col0 = (tid * 4) & 63;
  const int scol = col0 ^ ((r0 & 7) << 3);    // swizzled store col (A reg->LDS)
  const int gcol = ((l & 7) ^ (l >> 3)) * 8;  // inverse-swizzled src col (gl2lds)

  float2 stc[8];
#pragma unroll
  for (int j = 0; j < 8; ++j) stc[j] = st[Row0 + j * 16 + r0];

  f32x4 acc[4][4];
  const f32x4 zero = {0.f, 0.f, 0.f, 0.f};
#pragma unroll
  for (int m = 0; m < 4; ++m)
#pragma unroll
    for (int n = 0; n < 4; ++n) acc[m][n] = zero;

  float4 areg[8];
#pragma unroll
  for (int j = 0; j < 8; ++j)
    areg[j] = *(const float4*)(Af + (size_t)(Row0 + j * 16 + r0) * lda + col0);

  for (int k0 = 0; k0 < K; k0 += 64) {
    __syncthreads();
#pragma unroll
    for (int i = 0; i < 4; ++i) {
      int row = w * 32 + i * 8 + (l >> 3);
      gl2lds16(Bt + (size_t)(Col0 + row) * ldb + k0 + gcol, &lsB[w * 2048 + i * 512]);
    }
    float4 g4 = *(const float4*)(lng + k0 + col0);
    float4 b4 = *(const float4*)(lnb + k0 + col0);
#pragma unroll
    for (int j = 0; j < 8; ++j) {
      int row = j * 16 + r0;
      float4 v = areg[j];
      float m = stc[j].x, rs = stc[j].y;
      u16x4 o = {f2h((v.x - m) * rs * g4.x + b4.x), f2h((v.y - m) * rs * g4.y + b4.y),
                 f2h((v.z - m) * rs * g4.z + b4.z), f2h((v.w - m) * rs * g4.w + b4.w)};
      *(u16x4*)&lsA[row * 64 + scol] = o;
    }
    if (k0 + 64 < K) {
#pragma unroll
      for (int j = 0; j < 8; ++j)
        areg[j] = *(const float4*)(Af + (size_t)(Row0 + j * 16 + r0) * lda + k0 + 64 + col0);
    }
    __syncthreads();
#pragma unroll
    for (int kk = 0; kk < 64; kk += 32) {
      f16x8 af[4], bfv[4];
#pragma unroll
      for (int m = 0; m < 4; ++m)
        af[m] = ldf16(&lsA[swz(wm * 64 + m * 16 + lr, kk + 8 * lg)]);
#pragma unroll
      for (int n = 0; n < 4; ++n)
        bfv[n] = ldf16(&lsB[swz(wn * 64 + n * 16 + lr, kk + 8 * lg)]);
#pragma unroll
      for (int m = 0; m < 4; ++m)
#pragma unroll
        for (int n = 0; n < 4; ++n) acc[m][n] = mfma_f16(af[m], bfv[n], acc[m][n]);
    }
  }

#pragma unroll
  for (int m = 0; m < 4; ++m)
#pragma unroll
    for (int n = 0; n < 4; ++n) {
      int gc = Col0 + wn * 64 + n * 16 + lr;
#pragma unroll
      for (int r = 0; r < 4; ++r) {
        int gr = Row0 + wm * 64 + m * 16 + lg * 4 + r;
        u16 v = f2h(acc[m][n][r]);
        if (gc < 1024)
          Cq[(size_t)gr * 1024 + gc] = v;
        else
          Cv[(size_t)gr * 512 + gc - 1024] = v;
      }
    }
}

// ---------------- fp16 GEMM 128x128x64, A[M,K] fp16, B^T[N,K] fp16, batched ----------------
template <typename OUT_T, bool REMAP>
__global__ __launch_bounds__(256)
void gemm_bt(const u16* __restrict__ A, const u16* __restrict__ Bt,
             OUT_T* __restrict__ C, const float* __restrict__ bias,
             int lda, int ldb, int ldc, int K,
             long long sA, long long sB, long long sC, float scale) {
  __shared__ u16 lsA[128 * 64];
  __shared__ u16 lsB[128 * 64];
  const int tid = threadIdx.x;
  const int w = tid >> 6, l = tid & 63;
  const int lr = l & 15, lg = l >> 4;
  const int wm = w >> 1, wn = w & 1;
  int Row0, Col0;
  if constexpr (REMAP) {
    const int gx = gridDim.x;
    const int wk = xcd_remap(blockIdx.y * gx + blockIdx.x, gx * gridDim.y);
    Row0 = (wk / gx) * 128; Col0 = (wk % gx) * 128;
  } else {
    Row0 = blockIdx.y * 128; Col0 = blockIdx.x * 128;
  }
  const int bz = blockIdx.z;
  const int gcol = ((l & 7) ^ (l >> 3)) * 8;

  const u16* Ab = A + (size_t)bz * sA;
  const u16* Bb = Bt + (size_t)bz * sB;

  f32x4 acc[4][4];
  const f32x4 zero = {0.f, 0.f, 0.f, 0.f};
#pragma unroll
  for (int m = 0; m < 4; ++m)
#pragma unroll
    for (int n = 0; n < 4; ++n) acc[m][n] = zero;

  for (int k0 = 0; k0 < K; k0 += 64) {
    __syncthreads();
#pragma unroll
    for (int i = 0; i < 4; ++i) {
      int row = w * 32 + i * 8 + (l >> 3);
      gl2lds16(Ab + (size_t)(Row0 + row) * lda + k0 + gcol, &lsA[w * 2048 + i * 512]);
      gl2lds16(Bb + (size_t)(Col0 + row) * ldb + k0 + gcol, &lsB[w * 2048 + i * 512]);
    }
    __syncthreads();
#pragma unroll
    for (int kk = 0; kk < 64; kk += 32) {
      f16x8 af[4], bfv[4];
#pragma unroll
      for (int m = 0; m < 4; ++m)
        af[m] = ldf16(&lsA[swz(wm * 64 + m * 16 + lr, kk + 8 * lg)]);
#pragma unroll
      for (int n = 0; n < 4; ++n)
        bfv[n] = ldf16(&lsB[swz(wn * 64 + n * 16 + lr, kk + 8 * lg)]);
#pragma unroll
      for (int m = 0; m < 4; ++m)
#pragma unroll
        for (int n = 0; n < 4; ++n) acc[m][n] = mfma_f16(af[m], bfv[n], acc[m][n]);
    }
  }

  OUT_T* Cb = C + (size_t)bz * sC;
#pragma unroll
  for (int m = 0; m < 4; ++m)
#pragma unroll
    for (int n = 0; n < 4; ++n) {
      int gc = Col0 + wn * 64 + n * 16 + lr;
      float bv = bias ? bias[gc] : 0.f;
#pragma unroll
      for (int r = 0; r < 4; ++r) {
        int gr = Row0 + wm * 64 + m * 16 + lg * 4 + r;
        float v = acc[m][n][r] * scale + bv;
        if constexpr (std::is_same<OUT_T, u16>::value)
          Cb[(size_t)gr * ldc + gc] = f2h(v);
        else
          Cb[(size_t)gr * ldc + gc] = v;
      }
    }
}

// ---------------- fused temporal attention (fp16), one block per (b,c) ----------------
// QK: [row][1024] fp16 (q|k), Vb: [row][512] fp16, O: [row][512] fp16; row = b*32768+t*1024+c
__global__ __launch_bounds__(256)
void attn_t_kernel(const u16* __restrict__ QK, const u16* __restrict__ Vb,
                   u16* __restrict__ O) {
  __shared__ u16 qs[32 * 520];
  __shared__ u16 ks[32 * 520];
  __shared__ u16 vT[512 * 40];
  __shared__ float Sf[32 * 32];
  __shared__ u16 Pf[32 * 40];

  const int tid = threadIdx.x;
  const int bc = blockIdx.x;  // b*1024 + c
  const int w = tid >> 6, l = tid & 63, lr = l & 15, lg = l >> 4;
  const int wr = w >> 1, wc = w & 1;
  const size_t base = (size_t)(bc >> 10) * 32768 + (bc & 1023);

  // stage q,k rows (1 row = 1024 B = one wave gl2lds16); v transposed via regs
#pragma unroll
  for (int i = 0; i < 8; ++i) {
    int t = w * 8 + i;
    const u16* rb = QK + (base + (size_t)t * 1024) * 1024;
    gl2lds16(rb + l * 8, &qs[t * 520]);
    gl2lds16(rb + 512 + l * 8, &ks[t * 520]);
  }
#pragma unroll
  for (int j = 0; j < 8; ++j) {
    int li = j * 2048 + tid * 8;
    int t = li >> 9, col = li & 511;
    u16x8 vv = *(const u16x8*)(Vb + (base + (size_t)t * 1024) * 512 + col);
#pragma unroll
    for (int e = 0; e < 8; ++e) vT[(col + e) * 40 + t] = vv[e];
  }
  __syncthreads();

  // S = (q k^T) * 0.125, wave (wr,wc) -> one 16x16 tile
  f32x4 sacc = {0.f, 0.f, 0.f, 0.f};
#pragma unroll
  for (int kk = 0; kk < 512; kk += 32)
    sacc = mfma_f16(ldf16(&qs[(wr * 16 + lr) * 520 + kk + 8 * lg]),
                    ldf16(&ks[(wc * 16 + lr) * 520 + kk + 8 * lg]), sacc);
#pragma unroll
  for (int r = 0; r < 4; ++r)
    Sf[(wr * 16 + lg * 4 + r) * 32 + wc * 16 + lr] = sacc[r] * 0.125f;
  __syncthreads();

  if (tid < 32) {  // softmax, one row per thread
    float mx = -1e30f;
    for (int j = 0; j < 32; ++j) mx = fmaxf(mx, Sf[tid * 32 + j]);
    float s = 0.f;
    for (int j = 0; j < 32; ++j) s += __expf(Sf[tid * 32 + j] - mx);
    float inv = 1.f / s;
    for (int j = 0; j < 32; ++j) Pf[tid * 40 + j] = f2h(__expf(Sf[tid * 32 + j] - mx) * inv);
  }
  __syncthreads();

  {  // O = P @ V
    const int mr = w >> 1, nh = w & 1;
    f16x8 ap = ldf16(&Pf[(mr * 16 + lr) * 40 + 8 * lg]);
#pragma unroll
    for (int j = 0; j < 16; ++j) {
      int nc = (nh * 16 + j) * 16;
      f32x4 o = {0.f, 0.f, 0.f, 0.f};
      o = mfma_f16(ap, ldf16(&vT[(nc + lr) * 40 + 8 * lg]), o);
#pragma unroll
      for (int r = 0; r < 4; ++r) {
        int t = mr * 16 + lg * 4 + r;
        O[(base + (size_t)t * 1024) * 512 + nc + lr] = f2h(o[r]);
      }
    }
  }
}

// ---------------- row softmax over 1024 fp16, in place ----------------
__global__ __launch_bounds__(256)
void softmax16_kernel(u16* __restrict__ S) {
  u16* p = S + ((size_t)blockIdx.x << 10);
  const int tid = threadIdx.x, w = tid >> 6, l = tid & 63;
  __shared__ float red[8];
  u16x4 raw = *(u16x4*)&p[tid << 2];
  float v0 = h2f(raw[0]), v1 = h2f(raw[1]), v2 = h2f(raw[2]), v3 = h2f(raw[3]);
  float m = fmaxf(fmaxf(v0, v1), fmaxf(v2, v3));
#pragma unroll
  for (int o = 1; o < 64; o <<= 1) m = fmaxf(m, __shfl_xor(m, o, 64));
  if (l == 0) red[w] = m;
  __syncthreads();
  m = fmaxf(fmaxf(red[0], red[1]), fmaxf(red[2], red[3]));
  v0 = __expf(v0 - m); v1 = __expf(v1 - m); v2 = __expf(v2 - m); v3 = __expf(v3 - m);
  float s = v0 + v1 + v2 + v3;
#pragma unroll
  for (int o = 1; o < 64; o <<= 1) s += __shfl_xor(s, o, 64);
  if (l == 0) red[4 + w] = s;
  __syncthreads();
  const float inv = 1.f / (red[4] + red[5] + red[6] + red[7]);
  u16x4 o4 = {f2h(v0 * inv), f2h(v1 * inv), f2h(v2 * inv), f2h(v3 * inv)};
  *(u16x4*)&p[tid << 2] = o4;
}

// ---------------- V transpose per (b,t): Vt[bt][d][c] = Vb[bt*1024+c][d] ----------------
__global__ __launch_bounds__(256)
void transpose_v_kernel(const u16* __restrict__ Vb, u16* __restrict__ Vt) {
  __shared__ u16 tl[64][72];
  const int bt = blockIdx.z;
  const int c0 = blockIdx.x << 6, d0 = blockIdx.y << 6;
  const int tid = threadIdx.x;
#pragma unroll
  for (int pass = 0; pass < 2; ++pass) {
    int r = (pass << 5) + (tid >> 3), cc = (tid & 7) << 3;
    *(u16x8*)&tl[r][cc] = *(const u16x8*)(Vb + ((size_t)(bt * 1024 + c0 + r)) * 512 + d0 + cc);
  }
  __syncthreads();
#pragma unroll
  for (int pass = 0; pass < 2; ++pass) {
    int rd = (pass << 5) + (tid >> 3), cc = (tid & 7) << 3;
    u16x8 o;
#pragma unroll
    for (int e = 0; e < 8; ++e) o[e] = tl[cc + e][rd];
    *(u16x8*)(Vt + ((size_t)(bt * 512 + d0 + rd)) * 1024 + c0 + cc) = o;
  }
}

extern "C" void kernel_launch(void* const* d_in, const int* in_sizes, int n_in,
                              void* d_out, int out_size, void* d_ws, size_t ws_size,
                              hipStream_t stream) {
  (void)in_sizes; (void)n_in; (void)out_size; (void)ws_size;
  const float* x      = (const float*)d_in[0];
  const float* gam_t  = (const float*)d_in[1];
  const float* bet_t  = (const float*)d_in[2];
  const float* wqkv_t = (const float*)d_in[3];
  const float* wout_t = (const float*)d_in[4];
  const float* bout_t = (const float*)d_in[5];
  const float* gam_s  = (const float*)d_in[6];
  const float* bet_s  = (const float*)d_in[7];
  const float* wqkv_s = (const float*)d_in[8];
  const float* wout_s = (const float*)d_in[9];
  const float* bout_s = (const float*)d_in[10];
  float* out = (float*)d_out;

  char* ws = (char*)d_ws;
  size_t off = 0;
  auto alloc = [&](size_t bytes) -> char* {
    char* p = ws + off;
    off = (off + bytes + 255) & ~(size_t)255;
    return p;
  };
  // Total ~309 MiB.
  u16* wqkvT_t = (u16*)alloc((size_t)1536 * 512 * 2);
  u16* woutT_t = (u16*)alloc((size_t)512 * 512 * 2);
  u16* wqkvT_s = (u16*)alloc((size_t)1536 * 512 * 2);
  u16* woutT_s = (u16*)alloc((size_t)512 * 512 * 2);
  float2* stat = (float2*)alloc((size_t)65536 * 8);
  u16* QK      = (u16*)alloc((size_t)65536 * 1024 * 2);        // q|k fp16, 128 MiB
  u16* Vb      = (u16*)alloc((size_t)65536 * 512 * 2);         // 64 MiB
  u16* attnO   = (u16*)alloc((size_t)65536 * 512 * 2);         // 64 MiB
  u16* S       = (u16*)alloc((size_t)16 * 1024 * 1024 * 2);    // 32 MiB (16-bz chunk)
  u16* vT      = (u16*)alloc((size_t)16 * 512 * 1024 * 2);     // 16 MiB

  const dim3 blk(256);

  wT_kernel<<<768, blk, 0, stream>>>(wqkv_t, wqkvT_t, 512, 1536);
  wT_kernel<<<256, blk, 0, stream>>>(wout_t, woutT_t, 512, 512);
  wT_kernel<<<768, blk, 0, stream>>>(wqkv_s, wqkvT_s, 512, 1536);
  wT_kernel<<<256, blk, 0, stream>>>(wout_s, woutT_s, 512, 512);

  // ---- temporal ----
  lnstat_kernel<<<16384, blk, 0, stream>>>(x, stat);
  gemm_ln<<<dim3(12, 512, 1), blk, 0, stream>>>(
      x, wqkvT_t, stat, gam_t, bet_t, QK, Vb, 512, 512, 512);
  attn_t_kernel<<<2048, blk, 0, stream>>>(QK, Vb, attnO);
  gemm_bt<float, true><<<dim3(4, 512, 1), blk, 0, stream>>>(
      attnO, woutT_t, out, bout_t, 512, 512, 512, 512, 0, 0, 0, 1.f);

  // ---- spatial ----
  lnstat_kernel<<<16384, blk, 0, stream>>>(out, stat);
  gemm_ln<<<dim3(12, 512, 1), blk, 0, stream>>>(
      out, wqkvT_s, stat, gam_s, bet_s, QK, Vb, 512, 512, 512);

  for (int ch = 0; ch < 4; ++ch) {  // 16 (b,t) batches per chunk
    const u16* qkc = QK + (size_t)ch * 16 * 1024 * 1024;
    const u16* vbc = Vb + (size_t)ch * 16 * 1024 * 512;
    u16* attc = attnO + (size_t)ch * 16 * 1024 * 512;
    transpose_v_kernel<<<dim3(16, 8, 16), blk, 0, stream>>>(vbc, vT);
    gemm_bt<u16, false><<<dim3(8, 8, 16), blk, 0, stream>>>(
        qkc, qkc + 512, S, nullptr, 1024, 1024, 1024, 512,
        1024LL * 1024, 1024LL * 1024, 1024LL * 1024, 0.125f);
    softmax16_kernel<<<16384, blk, 0, stream>>>(S);
    gemm_bt<u16, false><<<dim3(4, 8, 16), blk, 0, stream>>>(
        S, vT, attc, nullptr, 1024, 1024, 512, 1024,
        1024LL * 1024, 512LL * 1024, 1024LL * 512, 1.f);
  }

  gemm_bt<float, true><<<dim3(4, 512, 1), blk, 0, stream>>>(
      attnO, woutT_s, out, bout_s, 512, 512, 512, 512, 0, 0, 0, 1.f);
}

// Round 7
// 1022.227 us; speedup vs baseline: 2.5745x; 1.1134x over previous
//
#include <hip/hip_runtime.h>
#include <type_traits>

typedef unsigned short u16;
typedef _Float16 f16;
typedef f16 f16x8 __attribute__((ext_vector_type(8)));
typedef unsigned short u16x8 __attribute__((ext_vector_type(8)));
typedef unsigned short u16x4 __attribute__((ext_vector_type(4)));
typedef float f32x4 __attribute__((ext_vector_type(4)));

#define DEV __device__ __forceinline__

DEV u16 f2h(float f) { return __builtin_bit_cast(u16, (f16)f); }  // RNE
DEV float h2f(u16 u) { return (float)__builtin_bit_cast(f16, u); }

DEV f32x4 mfma_f16(f16x8 a, f16x8 b, f32x4 c) {
  return __builtin_amdgcn_mfma_f32_16x16x32_f16(a, b, c, 0, 0, 0);
}
DEV f16x8 ldf16(const u16* p) { return *(const f16x8*)p; }

DEV void gl2lds16(const u16* g, u16* l) {
  __builtin_amdgcn_global_load_lds((const __attribute__((address_space(1))) void*)g,
                                   (__attribute__((address_space(3))) void*)l, 16, 0, 0);
}

// LDS tile [128 rows][64 u16], XOR-swizzled: physical col = col ^ ((row&7)<<3).
DEV int swz(int row, int col) { return row * 64 + (col ^ ((row & 7) << 3)); }

// XCD-chunked remap (nwg % 8 == 0): each XCD owns a contiguous work chunk.
DEV int xcd_remap(int d, int nwg) { return (d & 7) * (nwg >> 3) + (d >> 3); }

// ---------------- weight transpose fp32 -> fp16:  W[K,N] -> WT[n*K+k] ----------------
__global__ __launch_bounds__(256)
void wT_kernel(const float* __restrict__ W, u16* __restrict__ WT, int K, int N) {
  const int total = N * K;
  for (int i = blockIdx.x * 256 + threadIdx.x; i < total; i += gridDim.x * 256) {
    int n = i / K, k = i - n * K;
    WT[i] = f2h(W[(size_t)k * N + n]);
  }
}

// ---------------- fused LayerNorm (rows of 512 fp32) -> fp16 ----------------
__global__ __launch_bounds__(256)
void ln_kernel(const float* __restrict__ X, const float* __restrict__ G,
               const float* __restrict__ B, u16* __restrict__ H) {
  const int row = (blockIdx.x << 2) + (threadIdx.x >> 6);
  const int l = threadIdx.x & 63;
  const float* x = X + ((size_t)row << 9) + l * 8;
  float v[8];
  *(float4*)&v[0] = *(const float4*)(x);
  *(float4*)&v[4] = *(const float4*)(x + 4);
  float s = 0.f, s2 = 0.f;
#pragma unroll
  for (int e = 0; e < 8; ++e) { s += v[e]; s2 += v[e] * v[e]; }
#pragma unroll
  for (int o = 1; o < 64; o <<= 1) { s += __shfl_xor(s, o, 64); s2 += __shfl_xor(s2, o, 64); }
  const float mean = s * (1.f / 512.f);
  const float rs = rsqrtf(s2 * (1.f / 512.f) - mean * mean + 1e-5f);
  float g[8], bb[8];
  *(float4*)&g[0] = *(const float4*)(G + l * 8);
  *(float4*)&g[4] = *(const float4*)(G + l * 8 + 4);
  *(float4*)&bb[0] = *(const float4*)(B + l * 8);
  *(float4*)&bb[4] = *(const float4*)(B + l * 8 + 4);
  u16x8 o8;
#pragma unroll
  for (int e = 0; e < 8; ++e) o8[e] = f2h((v[e] - mean) * rs * g[e] + bb[e]);
  *(u16x8*)(H + ((size_t)row << 9) + l * 8) = o8;
}

// ---------------- qkv GEMM: pure fp16, both operands gl2lds, split Cq/Cv epilogue ----------
// A[M,512] fp16, B^T[1536,512] fp16. grid (12, M/128), XCD-remapped.
__global__ __launch_bounds__(256)
void gemm_qkv(const u16* __restrict__ A, const u16* __restrict__ Bt,
              u16* __restrict__ Cq, u16* __restrict__ Cv, int lda, int ldb, int K) {
  __shared__ u16 lsA[128 * 64];
  __shared__ u16 lsB[128 * 64];
  const int tid = threadIdx.x;
  const int w = tid >> 6, l = tid & 63;
  const int lr = l & 15, lg = l >> 4;
  const int wm = w >> 1, wn = w & 1;
  const int gx = gridDim.x;
  const int wk = xcd_remap(blockIdx.y * gx + blockIdx.x, gx * gridDim.y);
  const int Row0 = (wk / gx) * 128, Col0 = (wk % gx) * 128;
  const int gcol = ((l & 7) ^ (l >> 3)) * 8;  // inverse-swizzled src col

  f32x4 acc[4][4];
  const f32x4 zero = {0.f, 0.f, 0.f, 0.f};
#pragma unroll
  for (int m = 0; m < 4; ++m)
#pragma unroll
    for (int n = 0; n < 4; ++n) acc[m][n] = zero;

  for (int k0 = 0; k0 < K; k0 += 64) {
    __syncthreads();
#pragma unroll
    for (int i = 0; i < 4; ++i) {
      int row = w * 32 + i * 8 + (l >> 3);
      gl2lds16(A + (size_t)(Row0 + row) * lda + k0 + gcol, &lsA[w * 2048 + i * 512]);
      gl2lds16(Bt + (size_t)(Col0 + row) * ldb + k0 + gcol, &lsB[w * 2048 + i * 512]);
    }
    __syncthreads();
#pragma unroll
    for (int kk = 0; kk < 64; kk += 32) {
      f16x8 af[4], bfv[4];
#pragma unroll
      for (int m = 0; m < 4; ++m)
        af[m] = ldf16(&lsA[swz(wm * 64 + m * 16 + lr, kk + 8 * lg)]);
#pragma unroll
      for (int n = 0; n < 4; ++n)
        bfv[n] = ldf16(&lsB[swz(wn * 64 + n * 16 + lr, kk + 8 * lg)]);
#pragma unroll
      for (int m = 0; m < 4; ++m)
#pragma unroll
        for (int n = 0; n < 4; ++n) acc[m][n] = mfma_f16(af[m], bfv[n], acc[m][n]);
    }
  }

#pragma unroll
  for (int m = 0; m < 4; ++m)
#pragma unroll
    for (int n = 0; n < 4; ++n) {
      int gc = Col0 + wn * 64 + n * 16 + lr;
#pragma unroll
      for (int r = 0; r < 4; ++r) {
        int gr = Row0 + wm * 64 + m * 16 + lg * 4 + r;
        u16 v = f2h(acc[m][n][r]);
        if (gc < 1024)
          Cq[(size_t)gr * 1024 + gc] = v;
        else
          Cv[(size_t)gr * 512 + gc - 1024] = v;
      }
    }
}

// ---------------- fp16 GEMM 128x128x64, A[M,K] fp16, B^T[N,K] fp16, batched ----------------
template <typename OUT_T, bool REMAP>
__global__ __launch_bounds__(256)
void gemm_bt(const u16* __restrict__ A, const u16* __restrict__ Bt,
             OUT_T* __restrict__ C, const float* __restrict__ bias,
             int lda, int ldb, int ldc, int K,
             long long sA, long long sB, long long sC, float scale) {
  __shared__ u16 lsA[128 * 64];
  __shared__ u16 lsB[128 * 64];
  const int tid = threadIdx.x;
  const int w = tid >> 6, l = tid & 63;
  const int lr = l & 15, lg = l >> 4;
  const int wm = w >> 1, wn = w & 1;
  int Row0, Col0;
  if constexpr (REMAP) {
    const int gx = gridDim.x;
    const int wk = xcd_remap(blockIdx.y * gx + blockIdx.x, gx * gridDim.y);
    Row0 = (wk / gx) * 128; Col0 = (wk % gx) * 128;
  } else {
    Row0 = blockIdx.y * 128; Col0 = blockIdx.x * 128;
  }
  const int bz = blockIdx.z;
  const int gcol = ((l & 7) ^ (l >> 3)) * 8;

  const u16* Ab = A + (size_t)bz * sA;
  const u16* Bb = Bt + (size_t)bz * sB;

  f32x4 acc[4][4];
  const f32x4 zero = {0.f, 0.f, 0.f, 0.f};
#pragma unroll
  for (int m = 0; m < 4; ++m)
#pragma unroll
    for (int n = 0; n < 4; ++n) acc[m][n] = zero;

  for (int k0 = 0; k0 < K; k0 += 64) {
    __syncthreads();
#pragma unroll
    for (int i = 0; i < 4; ++i) {
      int row = w * 32 + i * 8 + (l >> 3);
      gl2lds16(Ab + (size_t)(Row0 + row) * lda + k0 + gcol, &lsA[w * 2048 + i * 512]);
      gl2lds16(Bb + (size_t)(Col0 + row) * ldb + k0 + gcol, &lsB[w * 2048 + i * 512]);
    }
    __syncthreads();
#pragma unroll
    for (int kk = 0; kk < 64; kk += 32) {
      f16x8 af[4], bfv[4];
#pragma unroll
      for (int m = 0; m < 4; ++m)
        af[m] = ldf16(&lsA[swz(wm * 64 + m * 16 + lr, kk + 8 * lg)]);
#pragma unroll
      for (int n = 0; n < 4; ++n)
        bfv[n] = ldf16(&lsB[swz(wn * 64 + n * 16 + lr, kk + 8 * lg)]);
#pragma unroll
      for (int m = 0; m < 4; ++m)
#pragma unroll
        for (int n = 0; n < 4; ++n) acc[m][n] = mfma_f16(af[m], bfv[n], acc[m][n]);
    }
  }

  OUT_T* Cb = C + (size_t)bz * sC;
#pragma unroll
  for (int m = 0; m < 4; ++m)
#pragma unroll
    for (int n = 0; n < 4; ++n) {
      int gc = Col0 + wn * 64 + n * 16 + lr;
      float bv = bias ? bias[gc] : 0.f;
#pragma unroll
      for (int r = 0; r < 4; ++r) {
        int gr = Row0 + wm * 64 + m * 16 + lg * 4 + r;
        float v = acc[m][n][r] * scale + bv;
        if constexpr (std::is_same<OUT_T, u16>::value)
          Cb[(size_t)gr * ldc + gc] = f2h(v);
        else
          Cb[(size_t)gr * ldc + gc] = v;
      }
    }
}

// ---------------- fused temporal attention (fp16), one block per (b,c) ----------------
// QK: [row][1024] fp16 (q|k), Vb: [row][512] fp16, O: [row][512] fp16; row = b*32768+t*1024+c
__global__ __launch_bounds__(256)
void attn_t_kernel(const u16* __restrict__ QK, const u16* __restrict__ Vb,
                   u16* __restrict__ O) {
  __shared__ u16 qs[32 * 520];
  __shared__ u16 ks[32 * 520];
  __shared__ u16 vT[512 * 40];
  __shared__ float Sf[32 * 32];
  __shared__ u16 Pf[32 * 40];

  const int tid = threadIdx.x;
  const int bc = blockIdx.x;  // b*1024 + c
  const int w = tid >> 6, l = tid & 63, lr = l & 15, lg = l >> 4;
  const int wr = w >> 1, wc = w & 1;
  const size_t base = (size_t)(bc >> 10) * 32768 + (bc & 1023);

#pragma unroll
  for (int i = 0; i < 8; ++i) {
    int t = w * 8 + i;
    const u16* rb = QK + (base + (size_t)t * 1024) * 1024;
    gl2lds16(rb + l * 8, &qs[t * 520]);
    gl2lds16(rb + 512 + l * 8, &ks[t * 520]);
  }
#pragma unroll
  for (int j = 0; j < 8; ++j) {
    int li = j * 2048 + tid * 8;
    int t = li >> 9, col = li & 511;
    u16x8 vv = *(const u16x8*)(Vb + (base + (size_t)t * 1024) * 512 + col);
#pragma unroll
    for (int e = 0; e < 8; ++e) vT[(col + e) * 40 + t] = vv[e];
  }
  __syncthreads();

  f32x4 sacc = {0.f, 0.f, 0.f, 0.f};
#pragma unroll
  for (int kk = 0; kk < 512; kk += 32)
    sacc = mfma_f16(ldf16(&qs[(wr * 16 + lr) * 520 + kk + 8 * lg]),
                    ldf16(&ks[(wc * 16 + lr) * 520 + kk + 8 * lg]), sacc);
#pragma unroll
  for (int r = 0; r < 4; ++r)
    Sf[(wr * 16 + lg * 4 + r) * 32 + wc * 16 + lr] = sacc[r] * 0.125f;
  __syncthreads();

  if (tid < 32) {
    float mx = -1e30f;
    for (int j = 0; j < 32; ++j) mx = fmaxf(mx, Sf[tid * 32 + j]);
    float s = 0.f;
    for (int j = 0; j < 32; ++j) s += __expf(Sf[tid * 32 + j] - mx);
    float inv = 1.f / s;
    for (int j = 0; j < 32; ++j) Pf[tid * 40 + j] = f2h(__expf(Sf[tid * 32 + j] - mx) * inv);
  }
  __syncthreads();

  {
    const int mr = w >> 1, nh = w & 1;
    f16x8 ap = ldf16(&Pf[(mr * 16 + lr) * 40 + 8 * lg]);
#pragma unroll
    for (int j = 0; j < 16; ++j) {
      int nc = (nh * 16 + j) * 16;
      f32x4 o = {0.f, 0.f, 0.f, 0.f};
      o = mfma_f16(ap, ldf16(&vT[(nc + lr) * 40 + 8 * lg]), o);
#pragma unroll
      for (int r = 0; r < 4; ++r) {
        int t = mr * 16 + lg * 4 + r;
        O[(base + (size_t)t * 1024) * 512 + nc + lr] = f2h(o[r]);
      }
    }
  }
}

// ---------------- row softmax over 1024 fp16, in place ----------------
__global__ __launch_bounds__(256)
void softmax16_kernel(u16* __restrict__ S) {
  u16* p = S + ((size_t)blockIdx.x << 10);
  const int tid = threadIdx.x, w = tid >> 6, l = tid & 63;
  __shared__ float red[8];
  u16x4 raw = *(u16x4*)&p[tid << 2];
  float v0 = h2f(raw[0]), v1 = h2f(raw[1]), v2 = h2f(raw[2]), v3 = h2f(raw[3]);
  float m = fmaxf(fmaxf(v0, v1), fmaxf(v2, v3));
#pragma unroll
  for (int o = 1; o < 64; o <<= 1) m = fmaxf(m, __shfl_xor(m, o, 64));
  if (l == 0) red[w] = m;
  __syncthreads();
  m = fmaxf(fmaxf(red[0], red[1]), fmaxf(red[2], red[3]));
  v0 = __expf(v0 - m); v1 = __expf(v1 - m); v2 = __expf(v2 - m); v3 = __expf(v3 - m);
  float s = v0 + v1 + v2 + v3;
#pragma unroll
  for (int o = 1; o < 64; o <<= 1) s += __shfl_xor(s, o, 64);
  if (l == 0) red[4 + w] = s;
  __syncthreads();
  const float inv = 1.f / (red[4] + red[5] + red[6] + red[7]);
  u16x4 o4 = {f2h(v0 * inv), f2h(v1 * inv), f2h(v2 * inv), f2h(v3 * inv)};
  *(u16x4*)&p[tid << 2] = o4;
}

// ---------------- V transpose per (b,t): Vt[bt][d][c] = Vb[bt*1024+c][d] ----------------
__global__ __launch_bounds__(256)
void transpose_v_kernel(const u16* __restrict__ Vb, u16* __restrict__ Vt) {
  __shared__ u16 tl[64][72];
  const int bt = blockIdx.z;
  const int c0 = blockIdx.x << 6, d0 = blockIdx.y << 6;
  const int tid = threadIdx.x;
#pragma unroll
  for (int pass = 0; pass < 2; ++pass) {
    int r = (pass << 5) + (tid >> 3), cc = (tid & 7) << 3;
    *(u16x8*)&tl[r][cc] = *(const u16x8*)(Vb + ((size_t)(bt * 1024 + c0 + r)) * 512 + d0 + cc);
  }
  __syncthreads();
#pragma unroll
  for (int pass = 0; pass < 2; ++pass) {
    int rd = (pass << 5) + (tid >> 3), cc = (tid & 7) << 3;
    u16x8 o;
#pragma unroll
    for (int e = 0; e < 8; ++e) o[e] = tl[cc + e][rd];
    *(u16x8*)(Vt + ((size_t)(bt * 512 + d0 + rd)) * 1024 + c0 + cc) = o;
  }
}

extern "C" void kernel_launch(void* const* d_in, const int* in_sizes, int n_in,
                              void* d_out, int out_size, void* d_ws, size_t ws_size,
                              hipStream_t stream) {
  (void)in_sizes; (void)n_in; (void)out_size; (void)ws_size;
  const float* x      = (const float*)d_in[0];
  const float* gam_t  = (const float*)d_in[1];
  const float* bet_t  = (const float*)d_in[2];
  const float* wqkv_t = (const float*)d_in[3];
  const float* wout_t = (const float*)d_in[4];
  const float* bout_t = (const float*)d_in[5];
  const float* gam_s  = (const float*)d_in[6];
  const float* bet_s  = (const float*)d_in[7];
  const float* wqkv_s = (const float*)d_in[8];
  const float* wout_s = (const float*)d_in[9];
  const float* bout_s = (const float*)d_in[10];
  float* out = (float*)d_out;

  char* ws = (char*)d_ws;
  size_t off = 0;
  auto alloc = [&](size_t bytes) -> char* {
    char* p = ws + off;
    off = (off + bytes + 255) & ~(size_t)255;
    return p;
  };
  // Total ~356 MiB (proven-safe zone). h aliases S (h dead before S is written).
  u16* wqkvT_t = (u16*)alloc((size_t)1536 * 512 * 2);
  u16* woutT_t = (u16*)alloc((size_t)512 * 512 * 2);
  u16* wqkvT_s = (u16*)alloc((size_t)1536 * 512 * 2);
  u16* woutT_s = (u16*)alloc((size_t)512 * 512 * 2);
  u16* QK      = (u16*)alloc((size_t)65536 * 1024 * 2);      // 128 MiB
  u16* Vb      = (u16*)alloc((size_t)65536 * 512 * 2);       //  64 MiB
  u16* attnO   = (u16*)alloc((size_t)65536 * 512 * 2);       //  64 MiB
  u16* S       = (u16*)alloc((size_t)32 * 1024 * 1024 * 2);  //  64 MiB (32-bz chunk)
  u16* vT      = (u16*)alloc((size_t)32 * 512 * 1024 * 2);   //  32 MiB
  u16* h       = S;                                          // alias: LN output (64 MiB)

  const dim3 blk(256);

  wT_kernel<<<768, blk, 0, stream>>>(wqkv_t, wqkvT_t, 512, 1536);
  wT_kernel<<<256, blk, 0, stream>>>(wout_t, woutT_t, 512, 512);
  wT_kernel<<<768, blk, 0, stream>>>(wqkv_s, wqkvT_s, 512, 1536);
  wT_kernel<<<256, blk, 0, stream>>>(wout_s, woutT_s, 512, 512);

  // ---- temporal ----
  ln_kernel<<<16384, blk, 0, stream>>>(x, gam_t, bet_t, h);
  gemm_qkv<<<dim3(12, 512, 1), blk, 0, stream>>>(h, wqkvT_t, QK, Vb, 512, 512, 512);
  attn_t_kernel<<<2048, blk, 0, stream>>>(QK, Vb, attnO);
  gemm_bt<float, true><<<dim3(4, 512, 1), blk, 0, stream>>>(
      attnO, woutT_t, out, bout_t, 512, 512, 512, 512, 0, 0, 0, 1.f);

  // ---- spatial ----
  ln_kernel<<<16384, blk, 0, stream>>>(out, gam_s, bet_s, h);
  gemm_qkv<<<dim3(12, 512, 1), blk, 0, stream>>>(h, wqkvT_s, QK, Vb, 512, 512, 512);

  for (int ch = 0; ch < 2; ++ch) {  // 32 (b,t) batches per chunk
    const u16* qkc = QK + (size_t)ch * 32 * 1024 * 1024;
    const u16* vbc = Vb + (size_t)ch * 32 * 1024 * 512;
    u16* attc = attnO + (size_t)ch * 32 * 1024 * 512;
    transpose_v_kernel<<<dim3(16, 8, 32), blk, 0, stream>>>(vbc, vT);
    gemm_bt<u16, false><<<dim3(8, 8, 32), blk, 0, stream>>>(
        qkc, qkc + 512, S, nullptr, 1024, 1024, 1024, 512,
        1024LL * 1024, 1024LL * 1024, 1024LL * 1024, 0.125f);
    softmax16_kernel<<<32768, blk, 0, stream>>>(S);
    gemm_bt<u16, false><<<dim3(4, 8, 32), blk, 0, stream>>>(
        S, vT, attc, nullptr, 1024, 1024, 512, 1024,
        1024LL * 1024, 512LL * 1024, 1024LL * 512, 1.f);
  }

  gemm_bt<float, true><<<dim3(4, 512, 1), blk, 0, stream>>>(
      attnO, woutT_s, out, bout_s, 512, 512, 512, 512, 0, 0, 0, 1.f);
}

// Round 8
// 954.946 us; speedup vs baseline: 2.7559x; 1.0705x over previous
//
#include <hip/hip_runtime.h>
#include <type_traits>

typedef unsigned short u16;
typedef _Float16 f16;
typedef f16 f16x8 __attribute__((ext_vector_type(8)));
typedef unsigned short u16x8 __attribute__((ext_vector_type(8)));
typedef unsigned short u16x4 __attribute__((ext_vector_type(4)));
typedef float f32x4 __attribute__((ext_vector_type(4)));

#define DEV __device__ __forceinline__

DEV u16 f2h(float f) { return __builtin_bit_cast(u16, (f16)f); }  // RNE
DEV float h2f(u16 u) { return (float)__builtin_bit_cast(f16, u); }

DEV f32x4 mfma_f16(f16x8 a, f16x8 b, f32x4 c) {
  return __builtin_amdgcn_mfma_f32_16x16x32_f16(a, b, c, 0, 0, 0);
}
DEV f16x8 ldf16(const u16* p) { return *(const f16x8*)p; }

DEV void gl2lds16(const u16* g, u16* l) {
  __builtin_amdgcn_global_load_lds((const __attribute__((address_space(1))) void*)g,
                                   (__attribute__((address_space(3))) void*)l, 16, 0, 0);
}

// LDS tile [128 rows][64 u16], XOR-swizzled: physical col = col ^ ((row&7)<<3).
DEV int swz(int row, int col) { return row * 64 + (col ^ ((row & 7) << 3)); }

// XCD-chunked remap (nwg % 8 == 0): each XCD owns a contiguous work chunk.
DEV int xcd_remap(int d, int nwg) { return (d & 7) * (nwg >> 3) + (d >> 3); }

// ---------------- weight transpose fp32 -> fp16:  W[K,N] -> WT[n*K+k] ----------------
__global__ __launch_bounds__(256)
void wT_kernel(const float* __restrict__ W, u16* __restrict__ WT, int K, int N) {
  const int total = N * K;
  for (int i = blockIdx.x * 256 + threadIdx.x; i < total; i += gridDim.x * 256) {
    int n = i / K, k = i - n * K;
    WT[i] = f2h(W[(size_t)k * N + n]);
  }
}

// ---------------- fused LayerNorm (rows of 512 fp32) -> fp16 ----------------
__global__ __launch_bounds__(256)
void ln_kernel(const float* __restrict__ X, const float* __restrict__ G,
               const float* __restrict__ B, u16* __restrict__ H) {
  const int row = (blockIdx.x << 2) + (threadIdx.x >> 6);
  const int l = threadIdx.x & 63;
  const float* x = X + ((size_t)row << 9) + l * 8;
  float v[8];
  *(float4*)&v[0] = *(const float4*)(x);
  *(float4*)&v[4] = *(const float4*)(x + 4);
  float s = 0.f, s2 = 0.f;
#pragma unroll
  for (int e = 0; e < 8; ++e) { s += v[e]; s2 += v[e] * v[e]; }
#pragma unroll
  for (int o = 1; o < 64; o <<= 1) { s += __shfl_xor(s, o, 64); s2 += __shfl_xor(s2, o, 64); }
  const float mean = s * (1.f / 512.f);
  const float rs = rsqrtf(s2 * (1.f / 512.f) - mean * mean + 1e-5f);
  float g[8], bb[8];
  *(float4*)&g[0] = *(const float4*)(G + l * 8);
  *(float4*)&g[4] = *(const float4*)(G + l * 8 + 4);
  *(float4*)&bb[0] = *(const float4*)(B + l * 8);
  *(float4*)&bb[4] = *(const float4*)(B + l * 8 + 4);
  u16x8 o8;
#pragma unroll
  for (int e = 0; e < 8; ++e) o8[e] = f2h((v[e] - mean) * rs * g[e] + bb[e]);
  *(u16x8*)(H + ((size_t)row << 9) + l * 8) = o8;
}

// ---------------- LayerNorm on fp16 rows of 512 -> fp16 ----------------
__global__ __launch_bounds__(256)
void ln16_kernel(const u16* __restrict__ X, const float* __restrict__ G,
                 const float* __restrict__ B, u16* __restrict__ H) {
  const int row = (blockIdx.x << 2) + (threadIdx.x >> 6);
  const int l = threadIdx.x & 63;
  u16x8 raw = *(const u16x8*)(X + ((size_t)row << 9) + l * 8);
  float v[8];
#pragma unroll
  for (int e = 0; e < 8; ++e) v[e] = h2f(raw[e]);
  float s = 0.f, s2 = 0.f;
#pragma unroll
  for (int e = 0; e < 8; ++e) { s += v[e]; s2 += v[e] * v[e]; }
#pragma unroll
  for (int o = 1; o < 64; o <<= 1) { s += __shfl_xor(s, o, 64); s2 += __shfl_xor(s2, o, 64); }
  const float mean = s * (1.f / 512.f);
  const float rs = rsqrtf(s2 * (1.f / 512.f) - mean * mean + 1e-5f);
  float g[8], bb[8];
  *(float4*)&g[0] = *(const float4*)(G + l * 8);
  *(float4*)&g[4] = *(const float4*)(G + l * 8 + 4);
  *(float4*)&bb[0] = *(const float4*)(B + l * 8);
  *(float4*)&bb[4] = *(const float4*)(B + l * 8 + 4);
  u16x8 o8;
#pragma unroll
  for (int e = 0; e < 8; ++e) o8[e] = f2h((v[e] - mean) * rs * g[e] + bb[e]);
  *(u16x8*)(H + ((size_t)row << 9) + l * 8) = o8;
}

// ---------------- qkv GEMM: pure fp16, gl2lds both operands, LDS-bounce epilogue ----------
// A[M,512] fp16, B^T[1536,512] fp16. grid (12, M/128), XCD-remapped. Cols<1024 -> Cq else Cv.
__global__ __launch_bounds__(256)
void gemm_qkv(const u16* __restrict__ A, const u16* __restrict__ Bt,
              u16* __restrict__ Cq, u16* __restrict__ Cv, int lda, int ldb, int K) {
  __shared__ u16 lds[2 * 128 * 64];  // lsA | lsB; reused as epilogue bounce [64][136]
  u16* lsA = lds;
  u16* lsB = lds + 128 * 64;
  const int tid = threadIdx.x;
  const int w = tid >> 6, l = tid & 63;
  const int lr = l & 15, lg = l >> 4;
  const int wm = w >> 1, wn = w & 1;
  const int gx = gridDim.x;
  const int wk = xcd_remap(blockIdx.y * gx + blockIdx.x, gx * gridDim.y);
  const int Row0 = (wk / gx) * 128, Col0 = (wk % gx) * 128;
  const int gcol = ((l & 7) ^ (l >> 3)) * 8;

  f32x4 acc[4][4];
  const f32x4 zero = {0.f, 0.f, 0.f, 0.f};
#pragma unroll
  for (int m = 0; m < 4; ++m)
#pragma unroll
    for (int n = 0; n < 4; ++n) acc[m][n] = zero;

  for (int k0 = 0; k0 < K; k0 += 64) {
    __syncthreads();
#pragma unroll
    for (int i = 0; i < 4; ++i) {
      int row = w * 32 + i * 8 + (l >> 3);
      gl2lds16(A + (size_t)(Row0 + row) * lda + k0 + gcol, &lsA[w * 2048 + i * 512]);
      gl2lds16(Bt + (size_t)(Col0 + row) * ldb + k0 + gcol, &lsB[w * 2048 + i * 512]);
    }
    __syncthreads();
#pragma unroll
    for (int kk = 0; kk < 64; kk += 32) {
      f16x8 af[4], bfv[4];
#pragma unroll
      for (int m = 0; m < 4; ++m)
        af[m] = ldf16(&lsA[swz(wm * 64 + m * 16 + lr, kk + 8 * lg)]);
#pragma unroll
      for (int n = 0; n < 4; ++n)
        bfv[n] = ldf16(&lsB[swz(wn * 64 + n * 16 + lr, kk + 8 * lg)]);
#pragma unroll
      for (int m = 0; m < 4; ++m)
#pragma unroll
        for (int n = 0; n < 4; ++n) acc[m][n] = mfma_f16(af[m], bfv[n], acc[m][n]);
    }
  }

  // coalesced epilogue: bounce each 64-row half through LDS, stream u16x8 stores
  const bool isV = (Col0 >= 1024);
#pragma unroll
  for (int p = 0; p < 2; ++p) {
    __syncthreads();
    if (wm == p) {
#pragma unroll
      for (int m = 0; m < 4; ++m)
#pragma unroll
        for (int n = 0; n < 4; ++n) {
          int col = wn * 64 + n * 16 + lr;
#pragma unroll
          for (int r = 0; r < 4; ++r)
            lds[(m * 16 + lg * 4 + r) * 136 + col] = f2h(acc[m][n][r]);
        }
    }
    __syncthreads();
#pragma unroll
    for (int it = 0; it < 4; ++it) {
      int cid = it * 256 + tid;
      int rl = cid >> 4, cc = (cid & 15) * 8;
      u16x8 vv = *(u16x8*)&lds[rl * 136 + cc];
      int gr = Row0 + p * 64 + rl;
      int gc = Col0 + cc;
      if (!isV)
        *(u16x8*)&Cq[(size_t)gr * 1024 + gc] = vv;
      else
        *(u16x8*)&Cv[(size_t)gr * 512 + gc - 1024] = vv;
    }
  }
}

// ---------------- fp16 GEMM 128x128x64, A[M,K], B^T[N,K], batched ----------------
// OUT16: LDS-bounce coalesced u16 epilogue; else fp32 direct stores.
template <bool OUT16, bool REMAP>
__global__ __launch_bounds__(256)
void gemm_bt(const u16* __restrict__ A, const u16* __restrict__ Bt,
             void* __restrict__ Cp, const float* __restrict__ bias,
             int lda, int ldb, int ldc, int K,
             long long sA, long long sB, long long sC, float scale) {
  __shared__ u16 lds[2 * 128 * 64];
  u16* lsA = lds;
  u16* lsB = lds + 128 * 64;
  const int tid = threadIdx.x;
  const int w = tid >> 6, l = tid & 63;
  const int lr = l & 15, lg = l >> 4;
  const int wm = w >> 1, wn = w & 1;
  int Row0, Col0;
  if constexpr (REMAP) {
    const int gx = gridDim.x;
    const int wk = xcd_remap(blockIdx.y * gx + blockIdx.x, gx * gridDim.y);
    Row0 = (wk / gx) * 128; Col0 = (wk % gx) * 128;
  } else {
    Row0 = blockIdx.y * 128; Col0 = blockIdx.x * 128;
  }
  const int bz = blockIdx.z;
  const int gcol = ((l & 7) ^ (l >> 3)) * 8;

  const u16* Ab = A + (size_t)bz * sA;
  const u16* Bb = Bt + (size_t)bz * sB;

  f32x4 acc[4][4];
  const f32x4 zero = {0.f, 0.f, 0.f, 0.f};
#pragma unroll
  for (int m = 0; m < 4; ++m)
#pragma unroll
    for (int n = 0; n < 4; ++n) acc[m][n] = zero;

  for (int k0 = 0; k0 < K; k0 += 64) {
    __syncthreads();
#pragma unroll
    for (int i = 0; i < 4; ++i) {
      int row = w * 32 + i * 8 + (l >> 3);
      gl2lds16(Ab + (size_t)(Row0 + row) * lda + k0 + gcol, &lsA[w * 2048 + i * 512]);
      gl2lds16(Bb + (size_t)(Col0 + row) * ldb + k0 + gcol, &lsB[w * 2048 + i * 512]);
    }
    __syncthreads();
#pragma unroll
    for (int kk = 0; kk < 64; kk += 32) {
      f16x8 af[4], bfv[4];
#pragma unroll
      for (int m = 0; m < 4; ++m)
        af[m] = ldf16(&lsA[swz(wm * 64 + m * 16 + lr, kk + 8 * lg)]);
#pragma unroll
      for (int n = 0; n < 4; ++n)
        bfv[n] = ldf16(&lsB[swz(wn * 64 + n * 16 + lr, kk + 8 * lg)]);
#pragma unroll
      for (int m = 0; m < 4; ++m)
#pragma unroll
        for (int n = 0; n < 4; ++n) acc[m][n] = mfma_f16(af[m], bfv[n], acc[m][n]);
    }
  }

  if constexpr (OUT16) {
    u16* Cb = (u16*)Cp + (size_t)bz * sC;
#pragma unroll
    for (int p = 0; p < 2; ++p) {
      __syncthreads();
      if (wm == p) {
#pragma unroll
        for (int m = 0; m < 4; ++m)
#pragma unroll
          for (int n = 0; n < 4; ++n) {
            int col = wn * 64 + n * 16 + lr;
            float bv = bias ? bias[Col0 + col] : 0.f;
#pragma unroll
            for (int r = 0; r < 4; ++r)
              lds[(m * 16 + lg * 4 + r) * 136 + col] = f2h(acc[m][n][r] * scale + bv);
          }
      }
      __syncthreads();
#pragma unroll
      for (int it = 0; it < 4; ++it) {
        int cid = it * 256 + tid;
        int rl = cid >> 4, cc = (cid & 15) * 8;
        u16x8 vv = *(u16x8*)&lds[rl * 136 + cc];
        *(u16x8*)&Cb[(size_t)(Row0 + p * 64 + rl) * ldc + Col0 + cc] = vv;
      }
    }
  } else {
    float* Cb = (float*)Cp + (size_t)bz * sC;
#pragma unroll
    for (int m = 0; m < 4; ++m)
#pragma unroll
      for (int n = 0; n < 4; ++n) {
        int gc = Col0 + wn * 64 + n * 16 + lr;
        float bv = bias ? bias[gc] : 0.f;
#pragma unroll
        for (int r = 0; r < 4; ++r) {
          int gr = Row0 + wm * 64 + m * 16 + lg * 4 + r;
          Cb[(size_t)gr * ldc + gc] = acc[m][n][r] * scale + bv;
        }
      }
  }
}

// ---------------- fused temporal attention (fp16), one block per (b,c) ----------------
// QK: [row][1024] fp16 (q|k), Vb: [row][512] fp16, O: [row][512] fp16; row = b*32768+t*1024+c
__global__ __launch_bounds__(256)
void attn_t_kernel(const u16* __restrict__ QK, const u16* __restrict__ Vb,
                   u16* __restrict__ O) {
  __shared__ u16 qs[32 * 520];
  __shared__ u16 ks[32 * 520];
  __shared__ u16 vT[512 * 40];
  __shared__ float Sf[32 * 32];
  __shared__ u16 Pf[32 * 40];

  const int tid = threadIdx.x;
  const int bc = blockIdx.x;  // b*1024 + c
  const int w = tid >> 6, l = tid & 63, lr = l & 15, lg = l >> 4;
  const int wr = w >> 1, wc = w & 1;
  const size_t base = (size_t)(bc >> 10) * 32768 + (bc & 1023);

#pragma unroll
  for (int i = 0; i < 8; ++i) {
    int t = w * 8 + i;
    const u16* rb = QK + (base + (size_t)t * 1024) * 1024;
    gl2lds16(rb + l * 8, &qs[t * 520]);
    gl2lds16(rb + 512 + l * 8, &ks[t * 520]);
  }
#pragma unroll
  for (int j = 0; j < 8; ++j) {
    int li = j * 2048 + tid * 8;
    int t = li >> 9, col = li & 511;
    u16x8 vv = *(const u16x8*)(Vb + (base + (size_t)t * 1024) * 512 + col);
#pragma unroll
    for (int e = 0; e < 8; ++e) vT[(col + e) * 40 + t] = vv[e];
  }
  __syncthreads();

  f32x4 sacc = {0.f, 0.f, 0.f, 0.f};
#pragma unroll
  for (int kk = 0; kk < 512; kk += 32)
    sacc = mfma_f16(ldf16(&qs[(wr * 16 + lr) * 520 + kk + 8 * lg]),
                    ldf16(&ks[(wc * 16 + lr) * 520 + kk + 8 * lg]), sacc);
#pragma unroll
  for (int r = 0; r < 4; ++r)
    Sf[(wr * 16 + lg * 4 + r) * 32 + wc * 16 + lr] = sacc[r] * 0.125f;
  __syncthreads();

  if (tid < 32) {
    float mx = -1e30f;
    for (int j = 0; j < 32; ++j) mx = fmaxf(mx, Sf[tid * 32 + j]);
    float s = 0.f;
    for (int j = 0; j < 32; ++j) s += __expf(Sf[tid * 32 + j] - mx);
    float inv = 1.f / s;
    for (int j = 0; j < 32; ++j) Pf[tid * 40 + j] = f2h(__expf(Sf[tid * 32 + j] - mx) * inv);
  }
  __syncthreads();

  {  // O = P @ V, staged into qs (free) for coalesced u16x8 stores
    const int mr = w >> 1, nh = w & 1;
    f16x8 ap = ldf16(&Pf[(mr * 16 + lr) * 40 + 8 * lg]);
#pragma unroll
    for (int j = 0; j < 16; ++j) {
      int nc = (nh * 16 + j) * 16;
      f32x4 o = {0.f, 0.f, 0.f, 0.f};
      o = mfma_f16(ap, ldf16(&vT[(nc + lr) * 40 + 8 * lg]), o);
#pragma unroll
      for (int r = 0; r < 4; ++r)
        qs[(mr * 16 + lg * 4 + r) * 520 + nc + lr] = f2h(o[r]);
    }
  }
  __syncthreads();
#pragma unroll
  for (int it = 0; it < 8; ++it) {
    int cid = it * 256 + tid;
    int t = cid >> 6, col = (cid & 63) * 8;
    u16x8 vv = *(u16x8*)&qs[t * 520 + col];
    *(u16x8*)&O[(base + (size_t)t * 1024) * 512 + col] = vv;
  }
}

// ---------------- row softmax over 1024 fp16, in place ----------------
__global__ __launch_bounds__(256)
void softmax16_kernel(u16* __restrict__ S) {
  u16* p = S + ((size_t)blockIdx.x << 10);
  const int tid = threadIdx.x, w = tid >> 6, l = tid & 63;
  __shared__ float red[8];
  u16x4 raw = *(u16x4*)&p[tid << 2];
  float v0 = h2f(raw[0]), v1 = h2f(raw[1]), v2 = h2f(raw[2]), v3 = h2f(raw[3]);
  float m = fmaxf(fmaxf(v0, v1), fmaxf(v2, v3));
#pragma unroll
  for (int o = 1; o < 64; o <<= 1) m = fmaxf(m, __shfl_xor(m, o, 64));
  if (l == 0) red[w] = m;
  __syncthreads();
  m = fmaxf(fmaxf(red[0], red[1]), fmaxf(red[2], red[3]));
  v0 = __expf(v0 - m); v1 = __expf(v1 - m); v2 = __expf(v2 - m); v3 = __expf(v3 - m);
  float s = v0 + v1 + v2 + v3;
#pragma unroll
  for (int o = 1; o < 64; o <<= 1) s += __shfl_xor(s, o, 64);
  if (l == 0) red[4 + w] = s;
  __syncthreads();
  const float inv = 1.f / (red[4] + red[5] + red[6] + red[7]);
  u16x4 o4 = {f2h(v0 * inv), f2h(v1 * inv), f2h(v2 * inv), f2h(v3 * inv)};
  *(u16x4*)&p[tid << 2] = o4;
}

// ---------------- V transpose per (b,t): Vt[bt][d][c] = Vb[bt*1024+c][d] ----------------
__global__ __launch_bounds__(256)
void transpose_v_kernel(const u16* __restrict__ Vb, u16* __restrict__ Vt) {
  __shared__ u16 tl[64][72];
  const int bt = blockIdx.z;
  const int c0 = blockIdx.x << 6, d0 = blockIdx.y << 6;
  const int tid = threadIdx.x;
#pragma unroll
  for (int pass = 0; pass < 2; ++pass) {
    int r = (pass << 5) + (tid >> 3), cc = (tid & 7) << 3;
    *(u16x8*)&tl[r][cc] = *(const u16x8*)(Vb + ((size_t)(bt * 1024 + c0 + r)) * 512 + d0 + cc);
  }
  __syncthreads();
#pragma unroll
  for (int pass = 0; pass < 2; ++pass) {
    int rd = (pass << 5) + (tid >> 3), cc = (tid & 7) << 3;
    u16x8 o;
#pragma unroll
    for (int e = 0; e < 8; ++e) o[e] = tl[cc + e][rd];
    *(u16x8*)(Vt + ((size_t)(bt * 512 + d0 + rd)) * 1024 + c0 + cc) = o;
  }
}

extern "C" void kernel_launch(void* const* d_in, const int* in_sizes, int n_in,
                              void* d_out, int out_size, void* d_ws, size_t ws_size,
                              hipStream_t stream) {
  (void)in_sizes; (void)n_in; (void)out_size; (void)ws_size;
  const float* x      = (const float*)d_in[0];
  const float* gam_t  = (const float*)d_in[1];
  const float* bet_t  = (const float*)d_in[2];
  const float* wqkv_t = (const float*)d_in[3];
  const float* wout_t = (const float*)d_in[4];
  const float* bout_t = (const float*)d_in[5];
  const float* gam_s  = (const float*)d_in[6];
  const float* bet_s  = (const float*)d_in[7];
  const float* wqkv_s = (const float*)d_in[8];
  const float* wout_s = (const float*)d_in[9];
  const float* bout_s = (const float*)d_in[10];
  float* out = (float*)d_out;

  char* ws = (char*)d_ws;
  size_t off = 0;
  auto alloc = [&](size_t bytes) -> char* {
    char* p = ws + off;
    off = (off + bytes + 255) & ~(size_t)255;
    return p;
  };
  // Total ~356 MiB. Aliases: h = S region; out1 (fp16 temporal output) = QK first half.
  u16* wqkvT_t = (u16*)alloc((size_t)1536 * 512 * 2);
  u16* woutT_t = (u16*)alloc((size_t)512 * 512 * 2);
  u16* wqkvT_s = (u16*)alloc((size_t)1536 * 512 * 2);
  u16* woutT_s = (u16*)alloc((size_t)512 * 512 * 2);
  u16* QK      = (u16*)alloc((size_t)65536 * 1024 * 2);      // 128 MiB
  u16* Vb      = (u16*)alloc((size_t)65536 * 512 * 2);       //  64 MiB
  u16* attnO   = (u16*)alloc((size_t)65536 * 512 * 2);       //  64 MiB
  u16* S       = (u16*)alloc((size_t)32 * 1024 * 1024 * 2);  //  64 MiB (32-bz chunk)
  u16* vT      = (u16*)alloc((size_t)32 * 512 * 1024 * 2);   //  32 MiB
  u16* h       = S;    // LN output (64 MiB), dead before S is written
  u16* out1    = QK;   // temporal block output fp16 (64 MiB): proj_t -> ln16 (then QK reused)

  const dim3 blk(256);

  wT_kernel<<<768, blk, 0, stream>>>(wqkv_t, wqkvT_t, 512, 1536);
  wT_kernel<<<256, blk, 0, stream>>>(wout_t, woutT_t, 512, 512);
  wT_kernel<<<768, blk, 0, stream>>>(wqkv_s, wqkvT_s, 512, 1536);
  wT_kernel<<<256, blk, 0, stream>>>(wout_s, woutT_s, 512, 512);

  // ---- temporal ----
  ln_kernel<<<16384, blk, 0, stream>>>(x, gam_t, bet_t, h);
  gemm_qkv<<<dim3(12, 512, 1), blk, 0, stream>>>(h, wqkvT_t, QK, Vb, 512, 512, 512);
  attn_t_kernel<<<2048, blk, 0, stream>>>(QK, Vb, attnO);
  gemm_bt<true, true><<<dim3(4, 512, 1), blk, 0, stream>>>(
      attnO, woutT_t, out1, bout_t, 512, 512, 512, 512, 0, 0, 0, 1.f);

  // ---- spatial ----
  ln16_kernel<<<16384, blk, 0, stream>>>(out1, gam_s, bet_s, h);
  gemm_qkv<<<dim3(12, 512, 1), blk, 0, stream>>>(h, wqkvT_s, QK, Vb, 512, 512, 512);

  for (int ch = 0; ch < 2; ++ch) {  // 32 (b,t) batches per chunk
    const u16* qkc = QK + (size_t)ch * 32 * 1024 * 1024;
    const u16* vbc = Vb + (size_t)ch * 32 * 1024 * 512;
    u16* attc = attnO + (size_t)ch * 32 * 1024 * 512;
    transpose_v_kernel<<<dim3(16, 8, 32), blk, 0, stream>>>(vbc, vT);
    gemm_bt<true, false><<<dim3(8, 8, 32), blk, 0, stream>>>(
        qkc, qkc + 512, S, nullptr, 1024, 1024, 1024, 512,
        1024LL * 1024, 1024LL * 1024, 1024LL * 1024, 0.125f);
    softmax16_kernel<<<32768, blk, 0, stream>>>(S);
    gemm_bt<true, false><<<dim3(4, 8, 32), blk, 0, stream>>>(
        S, vT, attc, nullptr, 1024, 1024, 512, 1024,
        1024LL * 1024, 512LL * 1024, 1024LL * 512, 1.f);
  }

  gemm_bt<false, true><<<dim3(4, 512, 1), blk, 0, stream>>>(
      attnO, woutT_s, out, bout_s, 512, 512, 512, 512, 0, 0, 0, 1.f);
}

// Round 10
// 893.431 us; speedup vs baseline: 2.9457x; 1.0689x over previous
//
#include <hip/hip_runtime.h>
#include <type_traits>

typedef unsigned short u16;
typedef _Float16 f16;
typedef f16 f16x8 __attribute__((ext_vector_type(8)));
typedef unsigned short u16x8 __attribute__((ext_vector_type(8)));
typedef unsigned short u16x4 __attribute__((ext_vector_type(4)));
typedef float f32x4 __attribute__((ext_vector_type(4)));

#define DEV __device__ __forceinline__

DEV u16 f2h(float f) { return __builtin_bit_cast(u16, (f16)f); }  // RNE
DEV float h2f(u16 u) { return (float)__builtin_bit_cast(f16, u); }

DEV f32x4 mfma_f16(f16x8 a, f16x8 b, f32x4 c) {
  return __builtin_amdgcn_mfma_f32_16x16x32_f16(a, b, c, 0, 0, 0);
}
DEV f16x8 ldf16(const u16* p) { return *(const f16x8*)p; }

DEV void gl2lds16(const u16* g, u16* l) {
  __builtin_amdgcn_global_load_lds((const __attribute__((address_space(1))) void*)g,
                                   (__attribute__((address_space(3))) void*)l, 16, 0, 0);
}

// LDS tile [128 rows][64 u16], XOR-swizzled: physical col = col ^ ((row&7)<<3).
DEV int swz(int row, int col) { return row * 64 + (col ^ ((row & 7) << 3)); }

// XCD-chunked remap (nwg % 8 == 0): each XCD owns a contiguous work chunk.
DEV int xcd_remap(int d, int nwg) { return (d & 7) * (nwg >> 3) + (d >> 3); }

// ---------------- all four weights: transpose fp32 -> fp16 in one launch ----------------
// 4 elements per thread: block `base` covers elements [base*1024, base*1024+1024).
__global__ __launch_bounds__(256)
void wT_all_kernel(const float* __restrict__ Wq_t, const float* __restrict__ Wo_t,
                   const float* __restrict__ Wq_s, const float* __restrict__ Wo_s,
                   u16* __restrict__ Tq_t, u16* __restrict__ To_t,
                   u16* __restrict__ Tq_s, u16* __restrict__ To_s) {
  const int bid = blockIdx.x;
  const float* W;
  u16* T;
  int N, base;
  if (bid < 768)       { W = Wq_t; T = Tq_t; N = 1536; base = bid; }
  else if (bid < 1024) { W = Wo_t; T = To_t; N = 512;  base = bid - 768; }
  else if (bid < 1792) { W = Wq_s; T = Tq_s; N = 1536; base = bid - 1024; }
  else                 { W = Wo_s; T = To_s; N = 512;  base = bid - 1792; }
#pragma unroll
  for (int j = 0; j < 4; ++j) {
    int i = base * 1024 + j * 256 + threadIdx.x;
    int n = i >> 9, k = i & 511;
    T[i] = f2h(W[(size_t)k * N + n]);
  }
}

// ---------------- fused LayerNorm (rows of 512 fp32) -> fp16 ----------------
__global__ __launch_bounds__(256)
void ln_kernel(const float* __restrict__ X, const float* __restrict__ G,
               const float* __restrict__ B, u16* __restrict__ H) {
  const int row = (blockIdx.x << 2) + (threadIdx.x >> 6);
  const int l = threadIdx.x & 63;
  const float* x = X + ((size_t)row << 9) + l * 8;
  float v[8];
  *(float4*)&v[0] = *(const float4*)(x);
  *(float4*)&v[4] = *(const float4*)(x + 4);
  float s = 0.f, s2 = 0.f;
#pragma unroll
  for (int e = 0; e < 8; ++e) { s += v[e]; s2 += v[e] * v[e]; }
#pragma unroll
  for (int o = 1; o < 64; o <<= 1) { s += __shfl_xor(s, o, 64); s2 += __shfl_xor(s2, o, 64); }
  const float mean = s * (1.f / 512.f);
  const float rs = rsqrtf(s2 * (1.f / 512.f) - mean * mean + 1e-5f);
  float g[8], bb[8];
  *(float4*)&g[0] = *(const float4*)(G + l * 8);
  *(float4*)&g[4] = *(const float4*)(G + l * 8 + 4);
  *(float4*)&bb[0] = *(const float4*)(B + l * 8);
  *(float4*)&bb[4] = *(const float4*)(B + l * 8 + 4);
  u16x8 o8;
#pragma unroll
  for (int e = 0; e < 8; ++e) o8[e] = f2h((v[e] - mean) * rs * g[e] + bb[e]);
  *(u16x8*)(H + ((size_t)row << 9) + l * 8) = o8;
}

// ---------------- LayerNorm on fp16 rows of 512 -> fp16 ----------------
__global__ __launch_bounds__(256)
void ln16_kernel(const u16* __restrict__ X, const float* __restrict__ G,
                 const float* __restrict__ B, u16* __restrict__ H) {
  const int row = (blockIdx.x << 2) + (threadIdx.x >> 6);
  const int l = threadIdx.x & 63;
  u16x8 raw = *(const u16x8*)(X + ((size_t)row << 9) + l * 8);
  float v[8];
#pragma unroll
  for (int e = 0; e < 8; ++e) v[e] = h2f(raw[e]);
  float s = 0.f, s2 = 0.f;
#pragma unroll
  for (int e = 0; e < 8; ++e) { s += v[e]; s2 += v[e] * v[e]; }
#pragma unroll
  for (int o = 1; o < 64; o <<= 1) { s += __shfl_xor(s, o, 64); s2 += __shfl_xor(s2, o, 64); }
  const float mean = s * (1.f / 512.f);
  const float rs = rsqrtf(s2 * (1.f / 512.f) - mean * mean + 1e-5f);
  float g[8], bb[8];
  *(float4*)&g[0] = *(const float4*)(G + l * 8);
  *(float4*)&g[4] = *(const float4*)(G + l * 8 + 4);
  *(float4*)&bb[0] = *(const float4*)(B + l * 8);
  *(float4*)&bb[4] = *(const float4*)(B + l * 8 + 4);
  u16x8 o8;
#pragma unroll
  for (int e = 0; e < 8; ++e) o8[e] = f2h((v[e] - mean) * rs * g[e] + bb[e]);
  *(u16x8*)(H + ((size_t)row << 9) + l * 8) = o8;
}

// ---------------- qkv GEMM: pure fp16, gl2lds both operands, LDS-bounce epilogue ----------
__global__ __launch_bounds__(256)
void gemm_qkv(const u16* __restrict__ A, const u16* __restrict__ Bt,
              u16* __restrict__ Cq, u16* __restrict__ Cv, int lda, int ldb, int K) {
  __shared__ u16 lds[2 * 128 * 64];  // lsA | lsB; reused as epilogue bounce [64][136]
  u16* lsA = lds;
  u16* lsB = lds + 128 * 64;
  const int tid = threadIdx.x;
  const int w = tid >> 6, l = tid & 63;
  const int lr = l & 15, lg = l >> 4;
  const int wm = w >> 1, wn = w & 1;
  const int gx = gridDim.x;
  const int wk = xcd_remap(blockIdx.y * gx + blockIdx.x, gx * gridDim.y);
  const int Row0 = (wk / gx) * 128, Col0 = (wk % gx) * 128;
  const int gcol = ((l & 7) ^ (l >> 3)) * 8;

  const u16* pA[4];
  const u16* pB[4];
#pragma unroll
  for (int i = 0; i < 4; ++i) {
    int row = w * 32 + i * 8 + (l >> 3);
    pA[i] = A + (size_t)(Row0 + row) * lda + gcol;
    pB[i] = Bt + (size_t)(Col0 + row) * ldb + gcol;
  }

  f32x4 acc[4][4];
  const f32x4 zero = {0.f, 0.f, 0.f, 0.f};
#pragma unroll
  for (int m = 0; m < 4; ++m)
#pragma unroll
    for (int n = 0; n < 4; ++n) acc[m][n] = zero;

  for (int k0 = 0; k0 < K; k0 += 64) {
    __syncthreads();
#pragma unroll
    for (int i = 0; i < 4; ++i) {
      gl2lds16(pA[i], &lsA[w * 2048 + i * 512]);
      gl2lds16(pB[i], &lsB[w * 2048 + i * 512]);
      pA[i] += 64;
      pB[i] += 64;
    }
    __syncthreads();
#pragma unroll
    for (int kk = 0; kk < 64; kk += 32) {
      f16x8 af[4], bfv[4];
#pragma unroll
      for (int m = 0; m < 4; ++m)
        af[m] = ldf16(&lsA[swz(wm * 64 + m * 16 + lr, kk + 8 * lg)]);
#pragma unroll
      for (int n = 0; n < 4; ++n)
        bfv[n] = ldf16(&lsB[swz(wn * 64 + n * 16 + lr, kk + 8 * lg)]);
#pragma unroll
      for (int m = 0; m < 4; ++m)
#pragma unroll
        for (int n = 0; n < 4; ++n) acc[m][n] = mfma_f16(af[m], bfv[n], acc[m][n]);
    }
  }

  const bool isV = (Col0 >= 1024);
#pragma unroll
  for (int p = 0; p < 2; ++p) {
    __syncthreads();
    if (wm == p) {
#pragma unroll
      for (int m = 0; m < 4; ++m)
#pragma unroll
        for (int n = 0; n < 4; ++n) {
          int col = wn * 64 + n * 16 + lr;
#pragma unroll
          for (int r = 0; r < 4; ++r)
            lds[(m * 16 + lg * 4 + r) * 136 + col] = f2h(acc[m][n][r]);
        }
    }
    __syncthreads();
#pragma unroll
    for (int it = 0; it < 4; ++it) {
      int cid = it * 256 + tid;
      int rl = cid >> 4, cc = (cid & 15) * 8;
      u16x8 vv = *(u16x8*)&lds[rl * 136 + cc];
      int gr = Row0 + p * 64 + rl;
      int gc = Col0 + cc;
      if (!isV)
        *(u16x8*)&Cq[(size_t)gr * 1024 + gc] = vv;
      else
        *(u16x8*)&Cv[(size_t)gr * 512 + gc - 1024] = vv;
    }
  }
}

// ---------------- fp16 GEMM 128x128x64, A[M,K], B^T[N,K], batched ----------------
// OUT16: LDS-bounce u16x8 epilogue; else LDS-bounce float4 epilogue.
template <bool OUT16, bool REMAP>
__global__ __launch_bounds__(256)
void gemm_bt(const u16* __restrict__ A, const u16* __restrict__ Bt,
             void* __restrict__ Cp, const float* __restrict__ bias,
             int lda, int ldb, int ldc, int K,
             long long sA, long long sB, long long sC, float scale) {
  __shared__ u16 lds[2 * 128 * 64];
  u16* lsA = lds;
  u16* lsB = lds + 128 * 64;
  const int tid = threadIdx.x;
  const int w = tid >> 6, l = tid & 63;
  const int lr = l & 15, lg = l >> 4;
  const int wm = w >> 1, wn = w & 1;
  int Row0, Col0;
  if constexpr (REMAP) {
    const int gx = gridDim.x;
    const int wk = xcd_remap(blockIdx.y * gx + blockIdx.x, gx * gridDim.y);
    Row0 = (wk / gx) * 128; Col0 = (wk % gx) * 128;
  } else {
    Row0 = blockIdx.y * 128; Col0 = blockIdx.x * 128;
  }
  const int bz = blockIdx.z;
  const int gcol = ((l & 7) ^ (l >> 3)) * 8;

  const u16* Ab = A + (size_t)bz * sA;
  const u16* Bb = Bt + (size_t)bz * sB;
  const u16* pA[4];
  const u16* pB[4];
#pragma unroll
  for (int i = 0; i < 4; ++i) {
    int row = w * 32 + i * 8 + (l >> 3);
    pA[i] = Ab + (size_t)(Row0 + row) * lda + gcol;
    pB[i] = Bb + (size_t)(Col0 + row) * ldb + gcol;
  }

  f32x4 acc[4][4];
  const f32x4 zero = {0.f, 0.f, 0.f, 0.f};
#pragma unroll
  for (int m = 0; m < 4; ++m)
#pragma unroll
    for (int n = 0; n < 4; ++n) acc[m][n] = zero;

  for (int k0 = 0; k0 < K; k0 += 64) {
    __syncthreads();
#pragma unroll
    for (int i = 0; i < 4; ++i) {
      gl2lds16(pA[i], &lsA[w * 2048 + i * 512]);
      gl2lds16(pB[i], &lsB[w * 2048 + i * 512]);
      pA[i] += 64;
      pB[i] += 64;
    }
    __syncthreads();
#pragma unroll
    for (int kk = 0; kk < 64; kk += 32) {
      f16x8 af[4], bfv[4];
#pragma unroll
      for (int m = 0; m < 4; ++m)
        af[m] = ldf16(&lsA[swz(wm * 64 + m * 16 + lr, kk + 8 * lg)]);
#pragma unroll
      for (int n = 0; n < 4; ++n)
        bfv[n] = ldf16(&lsB[swz(wn * 64 + n * 16 + lr, kk + 8 * lg)]);
#pragma unroll
      for (int m = 0; m < 4; ++m)
#pragma unroll
        for (int n = 0; n < 4; ++n) acc[m][n] = mfma_f16(af[m], bfv[n], acc[m][n]);
    }
  }

  if constexpr (OUT16) {
    u16* Cb = (u16*)Cp + (size_t)bz * sC;
#pragma unroll
    for (int p = 0; p < 2; ++p) {
      __syncthreads();
      if (wm == p) {
#pragma unroll
        for (int m = 0; m < 4; ++m)
#pragma unroll
          for (int n = 0; n < 4; ++n) {
            int col = wn * 64 + n * 16 + lr;
            float bv = bias ? bias[Col0 + col] : 0.f;
#pragma unroll
            for (int r = 0; r < 4; ++r)
              lds[(m * 16 + lg * 4 + r) * 136 + col] = f2h(acc[m][n][r] * scale + bv);
          }
      }
      __syncthreads();
#pragma unroll
      for (int it = 0; it < 4; ++it) {
        int cid = it * 256 + tid;
        int rl = cid >> 4, cc = (cid & 15) * 8;
        u16x8 vv = *(u16x8*)&lds[rl * 136 + cc];
        *(u16x8*)&Cb[(size_t)(Row0 + p * 64 + rl) * ldc + Col0 + cc] = vv;
      }
    }
  } else {
    // fp32 out: bounce 32-row quarters through LDS, stream float4
    float* Cb = (float*)Cp + (size_t)bz * sC;
    float* ldsF = (float*)lds;  // [32][132] fp32 = 16.9 KiB
#pragma unroll
    for (int q = 0; q < 4; ++q) {
      __syncthreads();
      if (wm == (q >> 1)) {
        int mBase = (q & 1) * 2;
#pragma unroll
        for (int mi = 0; mi < 2; ++mi) {
          int m = mBase + mi;
#pragma unroll
          for (int n = 0; n < 4; ++n) {
            int col = wn * 64 + n * 16 + lr;
            float bv = bias ? bias[Col0 + col] : 0.f;
#pragma unroll
            for (int r = 0; r < 4; ++r)
              ldsF[(mi * 16 + lg * 4 + r) * 132 + col] = acc[m][n][r] * scale + bv;
          }
        }
      }
      __syncthreads();
#pragma unroll
      for (int it = 0; it < 4; ++it) {
        int cid = it * 256 + tid;
        int rw = cid >> 5, c4 = (cid & 31) * 4;
        float4 v = *(float4*)&ldsF[rw * 132 + c4];
        *(float4*)&Cb[(size_t)(Row0 + q * 32 + rw) * ldc + Col0 + c4] = v;
      }
    }
  }
}

// ---------------- fused temporal attention (fp16), one block per (b,c) ----------------
// QK: [row][1024] fp16 (q|k), Vb: [row][512] fp16, O: [row][512] fp16; row = b*32768+t*1024+c
__global__ __launch_bounds__(256)
void attn_t_kernel(const u16* __restrict__ QK, const u16* __restrict__ Vb,
                   u16* __restrict__ O) {
  __shared__ u16 qs[32 * 520];
  __shared__ u16 ks[32 * 520];
  __shared__ u16 vT[512 * 40];
  __shared__ float Sf[32 * 36];
  __shared__ u16 Pf[32 * 40];

  const int tid = threadIdx.x;
  const int bc = blockIdx.x;  // b*1024 + c
  const int w = tid >> 6, l = tid & 63, lr = l & 15, lg = l >> 4;
  const int wr = w >> 1, wc = w & 1;
  const size_t base = (size_t)(bc >> 10) * 32768 + (bc & 1023);

#pragma unroll
  for (int i = 0; i < 8; ++i) {
    int t = w * 8 + i;
    const u16* rb = QK + (base + (size_t)t * 1024) * 1024;
    gl2lds16(rb + l * 8, &qs[t * 520]);
    gl2lds16(rb + 512 + l * 8, &ks[t * 520]);
  }
  {  // V staging, t-major lanes: conflict-free vT writes
    const int t = tid & 31;
    const int db0 = (tid >> 5) * 8;
    const u16* vrow = Vb + (base + (size_t)t * 1024) * 512;
#pragma unroll
    for (int j = 0; j < 8; ++j) {
      int db = db0 + j;
      u16x8 vv = *(const u16x8*)(vrow + db * 8);
#pragma unroll
      for (int e = 0; e < 8; ++e) vT[(db * 8 + e) * 40 + t] = vv[e];
    }
  }
  __syncthreads();

  f32x4 sacc = {0.f, 0.f, 0.f, 0.f};
#pragma unroll
  for (int kk = 0; kk < 512; kk += 32)
    sacc = mfma_f16(ldf16(&qs[(wr * 16 + lr) * 520 + kk + 8 * lg]),
                    ldf16(&ks[(wc * 16 + lr) * 520 + kk + 8 * lg]), sacc);
#pragma unroll
  for (int r = 0; r < 4; ++r)
    Sf[(wr * 16 + lg * 4 + r) * 36 + wc * 16 + lr] = sacc[r] * 0.125f;
  __syncthreads();

  {  // parallel softmax: 8 threads per row
    const int row = tid >> 3, c0 = (tid & 7) * 4;
    float4 sv = *(float4*)&Sf[row * 36 + c0];
    float mx = fmaxf(fmaxf(sv.x, sv.y), fmaxf(sv.z, sv.w));
#pragma unroll
    for (int o = 1; o < 8; o <<= 1) mx = fmaxf(mx, __shfl_xor(mx, o, 64));
    float e0 = __expf(sv.x - mx), e1 = __expf(sv.y - mx);
    float e2 = __expf(sv.z - mx), e3 = __expf(sv.w - mx);
    float sum = e0 + e1 + e2 + e3;
#pragma unroll
    for (int o = 1; o < 8; o <<= 1) sum += __shfl_xor(sum, o, 64);
    float inv = 1.f / sum;
    u16x4 p4 = {f2h(e0 * inv), f2h(e1 * inv), f2h(e2 * inv), f2h(e3 * inv)};
    *(u16x4*)&Pf[row * 40 + c0] = p4;
  }
  __syncthreads();

  {  // O = P @ V, staged into qs (free) for coalesced u16x8 stores
    const int mr = w >> 1, nh = w & 1;
    f16x8 ap = ldf16(&Pf[(mr * 16 + lr) * 40 + 8 * lg]);
#pragma unroll
    for (int j = 0; j < 16; ++j) {
      int nc = (nh * 16 + j) * 16;
      f32x4 o = {0.f, 0.f, 0.f, 0.f};
      o = mfma_f16(ap, ldf16(&vT[(nc + lr) * 40 + 8 * lg]), o);
#pragma unroll
      for (int r = 0; r < 4; ++r)
        qs[(mr * 16 + lg * 4 + r) * 520 + nc + lr] = f2h(o[r]);
    }
  }
  __syncthreads();
#pragma unroll
  for (int it = 0; it < 8; ++it) {
    int cid = it * 256 + tid;
    int t = cid >> 6, col = (cid & 63) * 8;
    u16x8 vv = *(u16x8*)&qs[t * 520 + col];
    *(u16x8*)&O[(base + (size_t)t * 1024) * 512 + col] = vv;
  }
}

// ---------------- row softmax over 1024 fp16, in place ----------------
__global__ __launch_bounds__(256)
void softmax16_kernel(u16* __restrict__ S) {
  u16* p = S + ((size_t)blockIdx.x << 10);
  const int tid = threadIdx.x, w = tid >> 6, l = tid & 63;
  __shared__ float red[8];
  u16x4 raw = *(u16x4*)&p[tid << 2];
  float v0 = h2f(raw[0]), v1 = h2f(raw[1]), v2 = h2f(raw[2]), v3 = h2f(raw[3]);
  float m = fmaxf(fmaxf(v0, v1), fmaxf(v2, v3));
#pragma unroll
  for (int o = 1; o < 64; o <<= 1) m = fmaxf(m, __shfl_xor(m, o, 64));
  if (l == 0) red[w] = m;
  __syncthreads();
  m = fmaxf(fmaxf(red[0], red[1]), fmaxf(red[2], red[3]));
  v0 = __expf(v0 - m); v1 = __expf(v1 - m); v2 = __expf(v2 - m); v3 = __expf(v3 - m);
  float s = v0 + v1 + v2 + v3;
#pragma unroll
  for (int o = 1; o < 64; o <<= 1) s += __shfl_xor(s, o, 64);
  if (l == 0) red[4 + w] = s;
  __syncthreads();
  const float inv = 1.f / (red[4] + red[5] + red[6] + red[7]);
  u16x4 o4 = {f2h(v0 * inv), f2h(v1 * inv), f2h(v2 * inv), f2h(v3 * inv)};
  *(u16x4*)&p[tid << 2] = o4;
}

// ---------------- V transpose per (b,t): Vt[bt][d][c] = Vb[bt*1024+c][d] ----------------
__global__ __launch_bounds__(256)
void transpose_v_kernel(const u16* __restrict__ Vb, u16* __restrict__ Vt) {
  __shared__ u16 tl[64][72];
  const int bt = blockIdx.z;
  const int c0 = blockIdx.x << 6, d0 = blockIdx.y << 6;
  const int tid = threadIdx.x;
#pragma unroll
  for (int pass = 0; pass < 2; ++pass) {
    int r = (pass << 5) + (tid >> 3), cc = (tid & 7) << 3;
    *(u16x8*)&tl[r][cc] = *(const u16x8*)(Vb + ((size_t)(bt * 1024 + c0 + r)) * 512 + d0 + cc);
  }
  __syncthreads();
#pragma unroll
  for (int pass = 0; pass < 2; ++pass) {
    int rd = (pass << 5) + (tid >> 3), cc = (tid & 7) << 3;
    u16x8 o;
#pragma unroll
    for (int e = 0; e < 8; ++e) o[e] = tl[cc + e][rd];
    *(u16x8*)(Vt + ((size_t)(bt * 512 + d0 + rd)) * 1024 + c0 + cc) = o;
  }
}

extern "C" void kernel_launch(void* const* d_in, const int* in_sizes, int n_in,
                              void* d_out, int out_size, void* d_ws, size_t ws_size,
                              hipStream_t stream) {
  (void)in_sizes; (void)n_in; (void)out_size; (void)ws_size;
  const float* x      = (const float*)d_in[0];
  const float* gam_t  = (const float*)d_in[1];
  const float* bet_t  = (const float*)d_in[2];
  const float* wqkv_t = (const float*)d_in[3];
  const float* wout_t = (const float*)d_in[4];
  const float* bout_t = (const float*)d_in[5];
  const float* gam_s  = (const float*)d_in[6];
  const float* bet_s  = (const float*)d_in[7];
  const float* wqkv_s = (const float*)d_in[8];
  const float* wout_s = (const float*)d_in[9];
  const float* bout_s = (const float*)d_in[10];
  float* out = (float*)d_out;

  char* ws = (char*)d_ws;
  size_t off = 0;
  auto alloc = [&](size_t bytes) -> char* {
    char* p = ws + off;
    off = (off + bytes + 255) & ~(size_t)255;
    return p;
  };
  // Total ~356 MiB. Aliases: h = S region; out1 (fp16 temporal output) = QK first half.
  u16* wqkvT_t = (u16*)alloc((size_t)1536 * 512 * 2);
  u16* woutT_t = (u16*)alloc((size_t)512 * 512 * 2);
  u16* wqkvT_s = (u16*)alloc((size_t)1536 * 512 * 2);
  u16* woutT_s = (u16*)alloc((size_t)512 * 512 * 2);
  u16* QK      = (u16*)alloc((size_t)65536 * 1024 * 2);      // 128 MiB
  u16* Vb      = (u16*)alloc((size_t)65536 * 512 * 2);       //  64 MiB
  u16* attnO   = (u16*)alloc((size_t)65536 * 512 * 2);       //  64 MiB
  u16* S       = (u16*)alloc((size_t)32 * 1024 * 1024 * 2);  //  64 MiB (32-bz chunk)
  u16* vT      = (u16*)alloc((size_t)32 * 512 * 1024 * 2);   //  32 MiB
  u16* h       = S;    // LN output (64 MiB), dead before S is written
  u16* out1    = QK;   // temporal block output fp16 (64 MiB)

  const dim3 blk(256);

  wT_all_kernel<<<2048, blk, 0, stream>>>(wqkv_t, wout_t, wqkv_s, wout_s,
                                          wqkvT_t, woutT_t, wqkvT_s, woutT_s);

  // ---- temporal ----
  ln_kernel<<<16384, blk, 0, stream>>>(x, gam_t, bet_t, h);
  gemm_qkv<<<dim3(12, 512, 1), blk, 0, stream>>>(h, wqkvT_t, QK, Vb, 512, 512, 512);
  attn_t_kernel<<<2048, blk, 0, stream>>>(QK, Vb, attnO);
  gemm_bt<true, true><<<dim3(4, 512, 1), blk, 0, stream>>>(
      attnO, woutT_t, out1, bout_t, 512, 512, 512, 512, 0, 0, 0, 1.f);

  // ---- spatial ----
  ln16_kernel<<<16384, blk, 0, stream>>>(out1, gam_s, bet_s, h);
  gemm_qkv<<<dim3(12, 512, 1), blk, 0, stream>>>(h, wqkvT_s, QK, Vb, 512, 512, 512);

  for (int ch = 0; ch < 2; ++ch) {  // 32 (b,t) batches per chunk
    const u16* qkc = QK + (size_t)ch * 32 * 1024 * 1024;
    const u16* vbc = Vb + (size_t)ch * 32 * 1024 * 512;
    u16* attc = attnO + (size_t)ch * 32 * 1024 * 512;
    transpose_v_kernel<<<dim3(16, 8, 32), blk, 0, stream>>>(vbc, vT);
    gemm_bt<true, false><<<dim3(8, 8, 32), blk, 0, stream>>>(
        qkc, qkc + 512, S, nullptr, 1024, 1024, 1024, 512,
        1024LL * 1024, 1024LL * 1024, 1024LL * 1024, 0.125f);
    softmax16_kernel<<<32768, blk, 0, stream>>>(S);
    gemm_bt<true, false><<<dim3(4, 8, 32), blk, 0, stream>>>(
        S, vT, attc, nullptr, 1024, 1024, 512, 1024,
        1024LL * 1024, 512LL * 1024, 1024LL * 512, 1.f);
  }

  gemm_bt<false, true><<<dim3(4, 512, 1), blk, 0, stream>>>(
      attnO, woutT_s, out, bout_s, 512, 512, 512, 512, 0, 0, 0, 1.f);
}

// Round 11
// 862.478 us; speedup vs baseline: 3.0514x; 1.0359x over previous
//
#include <hip/hip_runtime.h>
#include <type_traits>

typedef unsigned short u16;
typedef _Float16 f16;
typedef f16 f16x8 __attribute__((ext_vector_type(8)));
typedef unsigned short u16x8 __attribute__((ext_vector_type(8)));
typedef unsigned short u16x4 __attribute__((ext_vector_type(4)));
typedef float f32x4 __attribute__((ext_vector_type(4)));

#define DEV __device__ __forceinline__

DEV u16 f2h(float f) { return __builtin_bit_cast(u16, (f16)f); }  // RNE
DEV float h2f(u16 u) { return (float)__builtin_bit_cast(f16, u); }

DEV f32x4 mfma_f16(f16x8 a, f16x8 b, f32x4 c) {
  return __builtin_amdgcn_mfma_f32_16x16x32_f16(a, b, c, 0, 0, 0);
}
DEV f16x8 ldf16(const u16* p) { return *(const f16x8*)p; }

DEV void gl2lds16(const u16* g, u16* l) {
  __builtin_amdgcn_global_load_lds((const __attribute__((address_space(1))) void*)g,
                                   (__attribute__((address_space(3))) void*)l, 16, 0, 0);
}

// LDS tile [128 rows][64 u16], XOR-swizzled: physical col = col ^ ((row&7)<<3).
DEV int swz(int row, int col) { return row * 64 + (col ^ ((row & 7) << 3)); }

// XCD-chunked remap (nwg % 8 == 0): each XCD owns a contiguous work chunk.
DEV int xcd_remap(int d, int nwg) { return (d & 7) * (nwg >> 3) + (d >> 3); }

// ---------------- all four weights: transpose fp32 -> fp16 in one launch ----------------
// 4 elements per thread: block `base` covers elements [base*1024, base*1024+1024).
__global__ __launch_bounds__(256)
void wT_all_kernel(const float* __restrict__ Wq_t, const float* __restrict__ Wo_t,
                   const float* __restrict__ Wq_s, const float* __restrict__ Wo_s,
                   u16* __restrict__ Tq_t, u16* __restrict__ To_t,
                   u16* __restrict__ Tq_s, u16* __restrict__ To_s) {
  const int bid = blockIdx.x;
  const float* W;
  u16* T;
  int N, base;
  if (bid < 768)       { W = Wq_t; T = Tq_t; N = 1536; base = bid; }
  else if (bid < 1024) { W = Wo_t; T = To_t; N = 512;  base = bid - 768; }
  else if (bid < 1792) { W = Wq_s; T = Tq_s; N = 1536; base = bid - 1024; }
  else                 { W = Wo_s; T = To_s; N = 512;  base = bid - 1792; }
#pragma unroll
  for (int j = 0; j < 4; ++j) {
    int i = base * 1024 + j * 256 + threadIdx.x;
    int n = i >> 9, k = i & 511;
    T[i] = f2h(W[(size_t)k * N + n]);
  }
}

// ---------------- fused LayerNorm (rows of 512 fp32) -> fp16 ----------------
__global__ __launch_bounds__(256)
void ln_kernel(const float* __restrict__ X, const float* __restrict__ G,
               const float* __restrict__ B, u16* __restrict__ H) {
  const int row = (blockIdx.x << 2) + (threadIdx.x >> 6);
  const int l = threadIdx.x & 63;
  const float* x = X + ((size_t)row << 9) + l * 8;
  float v[8];
  *(float4*)&v[0] = *(const float4*)(x);
  *(float4*)&v[4] = *(const float4*)(x + 4);
  float s = 0.f, s2 = 0.f;
#pragma unroll
  for (int e = 0; e < 8; ++e) { s += v[e]; s2 += v[e] * v[e]; }
#pragma unroll
  for (int o = 1; o < 64; o <<= 1) { s += __shfl_xor(s, o, 64); s2 += __shfl_xor(s2, o, 64); }
  const float mean = s * (1.f / 512.f);
  const float rs = rsqrtf(s2 * (1.f / 512.f) - mean * mean + 1e-5f);
  float g[8], bb[8];
  *(float4*)&g[0] = *(const float4*)(G + l * 8);
  *(float4*)&g[4] = *(const float4*)(G + l * 8 + 4);
  *(float4*)&bb[0] = *(const float4*)(B + l * 8);
  *(float4*)&bb[4] = *(const float4*)(B + l * 8 + 4);
  u16x8 o8;
#pragma unroll
  for (int e = 0; e < 8; ++e) o8[e] = f2h((v[e] - mean) * rs * g[e] + bb[e]);
  *(u16x8*)(H + ((size_t)row << 9) + l * 8) = o8;
}

// ---------------- LayerNorm on fp16 rows of 512 -> fp16 ----------------
__global__ __launch_bounds__(256)
void ln16_kernel(const u16* __restrict__ X, const float* __restrict__ G,
                 const float* __restrict__ B, u16* __restrict__ H) {
  const int row = (blockIdx.x << 2) + (threadIdx.x >> 6);
  const int l = threadIdx.x & 63;
  u16x8 raw = *(const u16x8*)(X + ((size_t)row << 9) + l * 8);
  float v[8];
#pragma unroll
  for (int e = 0; e < 8; ++e) v[e] = h2f(raw[e]);
  float s = 0.f, s2 = 0.f;
#pragma unroll
  for (int e = 0; e < 8; ++e) { s += v[e]; s2 += v[e] * v[e]; }
#pragma unroll
  for (int o = 1; o < 64; o <<= 1) { s += __shfl_xor(s, o, 64); s2 += __shfl_xor(s2, o, 64); }
  const float mean = s * (1.f / 512.f);
  const float rs = rsqrtf(s2 * (1.f / 512.f) - mean * mean + 1e-5f);
  float g[8], bb[8];
  *(float4*)&g[0] = *(const float4*)(G + l * 8);
  *(float4*)&g[4] = *(const float4*)(G + l * 8 + 4);
  *(float4*)&bb[0] = *(const float4*)(B + l * 8);
  *(float4*)&bb[4] = *(const float4*)(B + l * 8 + 4);
  u16x8 o8;
#pragma unroll
  for (int e = 0; e < 8; ++e) o8[e] = f2h((v[e] - mean) * rs * g[e] + bb[e]);
  *(u16x8*)(H + ((size_t)row << 9) + l * 8) = o8;
}

// ---------------- qkv GEMM: pure fp16, gl2lds both operands, LDS-bounce epilogue ----------
// K templatized -> full unroll -> staging addresses fold to immediate offsets.
template <int K>
__global__ __launch_bounds__(256)
void gemm_qkv(const u16* __restrict__ A, const u16* __restrict__ Bt,
              u16* __restrict__ Cq, u16* __restrict__ Cv, int lda, int ldb) {
  __shared__ u16 lds[2 * 128 * 64];  // lsA | lsB; reused as epilogue bounce [64][136]
  u16* lsA = lds;
  u16* lsB = lds + 128 * 64;
  const int tid = threadIdx.x;
  const int w = tid >> 6, l = tid & 63;
  const int lr = l & 15, lg = l >> 4;
  const int wm = w >> 1, wn = w & 1;
  const int gx = gridDim.x;
  const int wk = xcd_remap(blockIdx.y * gx + blockIdx.x, gx * gridDim.y);
  const int Row0 = (wk / gx) * 128, Col0 = (wk % gx) * 128;
  const int gcol = ((l & 7) ^ (l >> 3)) * 8;

  const int srow = w * 32 + (l >> 3);  // this lane's staging row offset (i adds 8)
  const u16* baseA = A + (size_t)(Row0 + srow) * lda + gcol;
  const u16* baseB = Bt + (size_t)(Col0 + srow) * ldb + gcol;

  f32x4 acc[4][4];
  const f32x4 zero = {0.f, 0.f, 0.f, 0.f};
#pragma unroll
  for (int m = 0; m < 4; ++m)
#pragma unroll
    for (int n = 0; n < 4; ++n) acc[m][n] = zero;

#pragma unroll
  for (int k0 = 0; k0 < K; k0 += 64) {
    __syncthreads();
#pragma unroll
    for (int i = 0; i < 4; ++i) {
      gl2lds16(baseA + (size_t)(i * 8) * lda + k0, &lsA[w * 2048 + i * 512]);
      gl2lds16(baseB + (size_t)(i * 8) * ldb + k0, &lsB[w * 2048 + i * 512]);
    }
    __syncthreads();
#pragma unroll
    for (int kk = 0; kk < 64; kk += 32) {
      f16x8 af[4], bfv[4];
#pragma unroll
      for (int m = 0; m < 4; ++m)
        af[m] = ldf16(&lsA[swz(wm * 64 + m * 16 + lr, kk + 8 * lg)]);
#pragma unroll
      for (int n = 0; n < 4; ++n)
        bfv[n] = ldf16(&lsB[swz(wn * 64 + n * 16 + lr, kk + 8 * lg)]);
#pragma unroll
      for (int m = 0; m < 4; ++m)
#pragma unroll
        for (int n = 0; n < 4; ++n) acc[m][n] = mfma_f16(af[m], bfv[n], acc[m][n]);
    }
  }

  const bool isV = (Col0 >= 1024);
#pragma unroll
  for (int p = 0; p < 2; ++p) {
    __syncthreads();
    if (wm == p) {
#pragma unroll
      for (int m = 0; m < 4; ++m)
#pragma unroll
        for (int n = 0; n < 4; ++n) {
          int col = wn * 64 + n * 16 + lr;
#pragma unroll
          for (int r = 0; r < 4; ++r)
            lds[(m * 16 + lg * 4 + r) * 136 + col] = f2h(acc[m][n][r]);
        }
    }
    __syncthreads();
#pragma unroll
    for (int it = 0; it < 4; ++it) {
      int cid = it * 256 + tid;
      int rl = cid >> 4, cc = (cid & 15) * 8;
      u16x8 vv = *(u16x8*)&lds[rl * 136 + cc];
      int gr = Row0 + p * 64 + rl;
      int gc = Col0 + cc;
      if (!isV)
        *(u16x8*)&Cq[(size_t)gr * 1024 + gc] = vv;
      else
        *(u16x8*)&Cv[(size_t)gr * 512 + gc - 1024] = vv;
    }
  }
}

// ---------------- fp16 GEMM 128x128xK (unrolled), A[M,K], B^T[N,K], batched ----------------
// OUT16: LDS-bounce u16x8 epilogue; else LDS-bounce float4 epilogue.
template <bool OUT16, bool REMAP, int K>
__global__ __launch_bounds__(256)
void gemm_bt(const u16* __restrict__ A, const u16* __restrict__ Bt,
             void* __restrict__ Cp, const float* __restrict__ bias,
             int lda, int ldb, int ldc,
             long long sA, long long sB, long long sC, float scale) {
  __shared__ u16 lds[2 * 128 * 64];
  u16* lsA = lds;
  u16* lsB = lds + 128 * 64;
  const int tid = threadIdx.x;
  const int w = tid >> 6, l = tid & 63;
  const int lr = l & 15, lg = l >> 4;
  const int wm = w >> 1, wn = w & 1;
  int Row0, Col0;
  if constexpr (REMAP) {
    const int gx = gridDim.x;
    const int wk = xcd_remap(blockIdx.y * gx + blockIdx.x, gx * gridDim.y);
    Row0 = (wk / gx) * 128; Col0 = (wk % gx) * 128;
  } else {
    Row0 = blockIdx.y * 128; Col0 = blockIdx.x * 128;
  }
  const int bz = blockIdx.z;
  const int gcol = ((l & 7) ^ (l >> 3)) * 8;

  const int srow = w * 32 + (l >> 3);
  const u16* baseA = A + (size_t)bz * sA + (size_t)(Row0 + srow) * lda + gcol;
  const u16* baseB = Bt + (size_t)bz * sB + (size_t)(Col0 + srow) * ldb + gcol;

  f32x4 acc[4][4];
  const f32x4 zero = {0.f, 0.f, 0.f, 0.f};
#pragma unroll
  for (int m = 0; m < 4; ++m)
#pragma unroll
    for (int n = 0; n < 4; ++n) acc[m][n] = zero;

#pragma unroll
  for (int k0 = 0; k0 < K; k0 += 64) {
    __syncthreads();
#pragma unroll
    for (int i = 0; i < 4; ++i) {
      gl2lds16(baseA + (size_t)(i * 8) * lda + k0, &lsA[w * 2048 + i * 512]);
      gl2lds16(baseB + (size_t)(i * 8) * ldb + k0, &lsB[w * 2048 + i * 512]);
    }
    __syncthreads();
#pragma unroll
    for (int kk = 0; kk < 64; kk += 32) {
      f16x8 af[4], bfv[4];
#pragma unroll
      for (int m = 0; m < 4; ++m)
        af[m] = ldf16(&lsA[swz(wm * 64 + m * 16 + lr, kk + 8 * lg)]);
#pragma unroll
      for (int n = 0; n < 4; ++n)
        bfv[n] = ldf16(&lsB[swz(wn * 64 + n * 16 + lr, kk + 8 * lg)]);
#pragma unroll
      for (int m = 0; m < 4; ++m)
#pragma unroll
        for (int n = 0; n < 4; ++n) acc[m][n] = mfma_f16(af[m], bfv[n], acc[m][n]);
    }
  }

  if constexpr (OUT16) {
    u16* Cb = (u16*)Cp + (size_t)bz * sC;
#pragma unroll
    for (int p = 0; p < 2; ++p) {
      __syncthreads();
      if (wm == p) {
#pragma unroll
        for (int m = 0; m < 4; ++m)
#pragma unroll
          for (int n = 0; n < 4; ++n) {
            int col = wn * 64 + n * 16 + lr;
            float bv = bias ? bias[Col0 + col] : 0.f;
#pragma unroll
            for (int r = 0; r < 4; ++r)
              lds[(m * 16 + lg * 4 + r) * 136 + col] = f2h(acc[m][n][r] * scale + bv);
          }
      }
      __syncthreads();
#pragma unroll
      for (int it = 0; it < 4; ++it) {
        int cid = it * 256 + tid;
        int rl = cid >> 4, cc = (cid & 15) * 8;
        u16x8 vv = *(u16x8*)&lds[rl * 136 + cc];
        *(u16x8*)&Cb[(size_t)(Row0 + p * 64 + rl) * ldc + Col0 + cc] = vv;
      }
    }
  } else {
    // fp32 out: bounce 32-row quarters through LDS, stream float4
    float* Cb = (float*)Cp + (size_t)bz * sC;
    float* ldsF = (float*)lds;  // [32][132] fp32 = 16.9 KiB
#pragma unroll
    for (int q = 0; q < 4; ++q) {
      __syncthreads();
      if (wm == (q >> 1)) {
        int mBase = (q & 1) * 2;
#pragma unroll
        for (int mi = 0; mi < 2; ++mi) {
          int m = mBase + mi;
#pragma unroll
          for (int n = 0; n < 4; ++n) {
            int col = wn * 64 + n * 16 + lr;
            float bv = bias ? bias[Col0 + col] : 0.f;
#pragma unroll
            for (int r = 0; r < 4; ++r)
              ldsF[(mi * 16 + lg * 4 + r) * 132 + col] = acc[m][n][r] * scale + bv;
          }
        }
      }
      __syncthreads();
#pragma unroll
      for (int it = 0; it < 4; ++it) {
        int cid = it * 256 + tid;
        int rw = cid >> 5, c4 = (cid & 31) * 4;
        float4 v = *(float4*)&ldsF[rw * 132 + c4];
        *(float4*)&Cb[(size_t)(Row0 + q * 32 + rw) * ldc + Col0 + c4] = v;
      }
    }
  }
}

// ---------------- fused temporal attention (fp16), one block per (b,c) ----------------
// QK: [row][1024] fp16 (q|k), Vb: [row][512] fp16, O: [row][512] fp16; row = b*32768+t*1024+c
__global__ __launch_bounds__(256)
void attn_t_kernel(const u16* __restrict__ QK, const u16* __restrict__ Vb,
                   u16* __restrict__ O) {
  __shared__ u16 qs[32 * 520];
  __shared__ u16 ks[32 * 520];
  __shared__ u16 vT[512 * 40];
  __shared__ float Sf[32 * 36];
  __shared__ u16 Pf[32 * 40];

  const int tid = threadIdx.x;
  const int bc = blockIdx.x;  // b*1024 + c
  const int w = tid >> 6, l = tid & 63, lr = l & 15, lg = l >> 4;
  const int wr = w >> 1, wc = w & 1;
  const size_t base = (size_t)(bc >> 10) * 32768 + (bc & 1023);

#pragma unroll
  for (int i = 0; i < 8; ++i) {
    int t = w * 8 + i;
    const u16* rb = QK + (base + (size_t)t * 1024) * 1024;
    gl2lds16(rb + l * 8, &qs[t * 520]);
    gl2lds16(rb + 512 + l * 8, &ks[t * 520]);
  }
  {  // V staging, t-major lanes: conflict-free vT writes
    const int t = tid & 31;
    const int db0 = (tid >> 5) * 8;
    const u16* vrow = Vb + (base + (size_t)t * 1024) * 512;
#pragma unroll
    for (int j = 0; j < 8; ++j) {
      int db = db0 + j;
      u16x8 vv = *(const u16x8*)(vrow + db * 8);
#pragma unroll
      for (int e = 0; e < 8; ++e) vT[(db * 8 + e) * 40 + t] = vv[e];
    }
  }
  __syncthreads();

  f32x4 sacc = {0.f, 0.f, 0.f, 0.f};
#pragma unroll
  for (int kk = 0; kk < 512; kk += 32)
    sacc = mfma_f16(ldf16(&qs[(wr * 16 + lr) * 520 + kk + 8 * lg]),
                    ldf16(&ks[(wc * 16 + lr) * 520 + kk + 8 * lg]), sacc);
#pragma unroll
  for (int r = 0; r < 4; ++r)
    Sf[(wr * 16 + lg * 4 + r) * 36 + wc * 16 + lr] = sacc[r] * 0.125f;
  __syncthreads();

  {  // parallel softmax: 8 threads per row
    const int row = tid >> 3, c0 = (tid & 7) * 4;
    float4 sv = *(float4*)&Sf[row * 36 + c0];
    float mx = fmaxf(fmaxf(sv.x, sv.y), fmaxf(sv.z, sv.w));
#pragma unroll
    for (int o = 1; o < 8; o <<= 1) mx = fmaxf(mx, __shfl_xor(mx, o, 64));
    float e0 = __expf(sv.x - mx), e1 = __expf(sv.y - mx);
    float e2 = __expf(sv.z - mx), e3 = __expf(sv.w - mx);
    float sum = e0 + e1 + e2 + e3;
#pragma unroll
    for (int o = 1; o < 8; o <<= 1) sum += __shfl_xor(sum, o, 64);
    float inv = 1.f / sum;
    u16x4 p4 = {f2h(e0 * inv), f2h(e1 * inv), f2h(e2 * inv), f2h(e3 * inv)};
    *(u16x4*)&Pf[row * 40 + c0] = p4;
  }
  __syncthreads();

  {  // O = P @ V, staged into qs (free) for coalesced u16x8 stores
    const int mr = w >> 1, nh = w & 1;
    f16x8 ap = ldf16(&Pf[(mr * 16 + lr) * 40 + 8 * lg]);
#pragma unroll
    for (int j = 0; j < 16; ++j) {
      int nc = (nh * 16 + j) * 16;
      f32x4 o = {0.f, 0.f, 0.f, 0.f};
      o = mfma_f16(ap, ldf16(&vT[(nc + lr) * 40 + 8 * lg]), o);
#pragma unroll
      for (int r = 0; r < 4; ++r)
        qs[(mr * 16 + lg * 4 + r) * 520 + nc + lr] = f2h(o[r]);
    }
  }
  __syncthreads();
#pragma unroll
  for (int it = 0; it < 8; ++it) {
    int cid = it * 256 + tid;
    int t = cid >> 6, col = (cid & 63) * 8;
    u16x8 vv = *(u16x8*)&qs[t * 520 + col];
    *(u16x8*)&O[(base + (size_t)t * 1024) * 512 + col] = vv;
  }
}

// ---------------- row softmax over 1024 fp16, in place ----------------
__global__ __launch_bounds__(256)
void softmax16_kernel(u16* __restrict__ S) {
  u16* p = S + ((size_t)blockIdx.x << 10);
  const int tid = threadIdx.x, w = tid >> 6, l = tid & 63;
  __shared__ float red[8];
  u16x4 raw = *(u16x4*)&p[tid << 2];
  float v0 = h2f(raw[0]), v1 = h2f(raw[1]), v2 = h2f(raw[2]), v3 = h2f(raw[3]);
  float m = fmaxf(fmaxf(v0, v1), fmaxf(v2, v3));
#pragma unroll
  for (int o = 1; o < 64; o <<= 1) m = fmaxf(m, __shfl_xor(m, o, 64));
  if (l == 0) red[w] = m;
  __syncthreads();
  m = fmaxf(fmaxf(red[0], red[1]), fmaxf(red[2], red[3]));
  v0 = __expf(v0 - m); v1 = __expf(v1 - m); v2 = __expf(v2 - m); v3 = __expf(v3 - m);
  float s = v0 + v1 + v2 + v3;
#pragma unroll
  for (int o = 1; o < 64; o <<= 1) s += __shfl_xor(s, o, 64);
  if (l == 0) red[4 + w] = s;
  __syncthreads();
  const float inv = 1.f / (red[4] + red[5] + red[6] + red[7]);
  u16x4 o4 = {f2h(v0 * inv), f2h(v1 * inv), f2h(v2 * inv), f2h(v3 * inv)};
  *(u16x4*)&p[tid << 2] = o4;
}

// ---------------- V transpose per (b,t): Vt[bt][d][c] = Vb[bt*1024+c][d] ----------------
__global__ __launch_bounds__(256)
void transpose_v_kernel(const u16* __restrict__ Vb, u16* __restrict__ Vt) {
  __shared__ u16 tl[64][72];
  const int bt = blockIdx.z;
  const int c0 = blockIdx.x << 6, d0 = blockIdx.y << 6;
  const int tid = threadIdx.x;
#pragma unroll
  for (int pass = 0; pass < 2; ++pass) {
    int r = (pass << 5) + (tid >> 3), cc = (tid & 7) << 3;
    *(u16x8*)&tl[r][cc] = *(const u16x8*)(Vb + ((size_t)(bt * 1024 + c0 + r)) * 512 + d0 + cc);
  }
  __syncthreads();
#pragma unroll
  for (int pass = 0; pass < 2; ++pass) {
    int rd = (pass << 5) + (tid >> 3), cc = (tid & 7) << 3;
    u16x8 o;
#pragma unroll
    for (int e = 0; e < 8; ++e) o[e] = tl[cc + e][rd];
    *(u16x8*)(Vt + ((size_t)(bt * 512 + d0 + rd)) * 1024 + c0 + cc) = o;
  }
}

extern "C" void kernel_launch(void* const* d_in, const int* in_sizes, int n_in,
                              void* d_out, int out_size, void* d_ws, size_t ws_size,
                              hipStream_t stream) {
  (void)in_sizes; (void)n_in; (void)out_size; (void)ws_size;
  const float* x      = (const float*)d_in[0];
  const float* gam_t  = (const float*)d_in[1];
  const float* bet_t  = (const float*)d_in[2];
  const float* wqkv_t = (const float*)d_in[3];
  const float* wout_t = (const float*)d_in[4];
  const float* bout_t = (const float*)d_in[5];
  const float* gam_s  = (const float*)d_in[6];
  const float* bet_s  = (const float*)d_in[7];
  const float* wqkv_s = (const float*)d_in[8];
  const float* wout_s = (const float*)d_in[9];
  const float* bout_s = (const float*)d_in[10];
  float* out = (float*)d_out;

  char* ws = (char*)d_ws;
  size_t off = 0;
  auto alloc = [&](size_t bytes) -> char* {
    char* p = ws + off;
    off = (off + bytes + 255) & ~(size_t)255;
    return p;
  };
  // Total ~356 MiB. Aliases: h = S region; out1 (fp16 temporal output) = QK first half.
  u16* wqkvT_t = (u16*)alloc((size_t)1536 * 512 * 2);
  u16* woutT_t = (u16*)alloc((size_t)512 * 512 * 2);
  u16* wqkvT_s = (u16*)alloc((size_t)1536 * 512 * 2);
  u16* woutT_s = (u16*)alloc((size_t)512 * 512 * 2);
  u16* QK      = (u16*)alloc((size_t)65536 * 1024 * 2);      // 128 MiB
  u16* Vb      = (u16*)alloc((size_t)65536 * 512 * 2);       //  64 MiB
  u16* attnO   = (u16*)alloc((size_t)65536 * 512 * 2);       //  64 MiB
  u16* S       = (u16*)alloc((size_t)32 * 1024 * 1024 * 2);  //  64 MiB (32-bz chunk)
  u16* vT      = (u16*)alloc((size_t)32 * 512 * 1024 * 2);   //  32 MiB
  u16* h       = S;    // LN output (64 MiB), dead before S is written
  u16* out1    = QK;   // temporal block output fp16 (64 MiB)

  const dim3 blk(256);

  wT_all_kernel<<<2048, blk, 0, stream>>>(wqkv_t, wout_t, wqkv_s, wout_s,
                                          wqkvT_t, woutT_t, wqkvT_s, woutT_s);

  // ---- temporal ----
  ln_kernel<<<16384, blk, 0, stream>>>(x, gam_t, bet_t, h);
  gemm_qkv<512><<<dim3(12, 512, 1), blk, 0, stream>>>(h, wqkvT_t, QK, Vb, 512, 512);
  attn_t_kernel<<<2048, blk, 0, stream>>>(QK, Vb, attnO);
  gemm_bt<true, true, 512><<<dim3(4, 512, 1), blk, 0, stream>>>(
      attnO, woutT_t, out1, bout_t, 512, 512, 512, 0, 0, 0, 1.f);

  // ---- spatial ----
  ln16_kernel<<<16384, blk, 0, stream>>>(out1, gam_s, bet_s, h);
  gemm_qkv<512><<<dim3(12, 512, 1), blk, 0, stream>>>(h, wqkvT_s, QK, Vb, 512, 512);

  for (int ch = 0; ch < 2; ++ch) {  // 32 (b,t) batches per chunk
    const u16* qkc = QK + (size_t)ch * 32 * 1024 * 1024;
    const u16* vbc = Vb + (size_t)ch * 32 * 1024 * 512;
    u16* attc = attnO + (size_t)ch * 32 * 1024 * 512;
    transpose_v_kernel<<<dim3(16, 8, 32), blk, 0, stream>>>(vbc, vT);
    gemm_bt<true, false, 512><<<dim3(8, 8, 32), blk, 0, stream>>>(
        qkc, qkc + 512, S, nullptr, 1024, 1024, 1024,
        1024LL * 1024, 1024LL * 1024, 1024LL * 1024, 0.125f);
    softmax16_kernel<<<32768, blk, 0, stream>>>(S);
    gemm_bt<true, false, 1024><<<dim3(4, 8, 32), blk, 0, stream>>>(
        S, vT, attc, nullptr, 1024, 1024, 512,
        1024LL * 1024, 512LL * 1024, 1024LL * 512, 1.f);
  }

  gemm_bt<false, true, 512><<<dim3(4, 512, 1), blk, 0, stream>>>(
      attnO, woutT_s, out, bout_s, 512, 512, 512, 0, 0, 0, 1.f);
}

// Round 12
// 829.428 us; speedup vs baseline: 3.1730x; 1.0398x over previous
//
#include <hip/hip_runtime.h>
#include <type_traits>

typedef unsigned short u16;
typedef _Float16 f16;
typedef f16 f16x8 __attribute__((ext_vector_type(8)));
typedef unsigned short u16x8 __attribute__((ext_vector_type(8)));
typedef unsigned short u16x4 __attribute__((ext_vector_type(4)));
typedef float f32x4 __attribute__((ext_vector_type(4)));

#define DEV __device__ __forceinline__

DEV u16 f2h(float f) { return __builtin_bit_cast(u16, (f16)f); }  // RNE
DEV float h2f(u16 u) { return (float)__builtin_bit_cast(f16, u); }

DEV f32x4 mfma_f16(f16x8 a, f16x8 b, f32x4 c) {
  return __builtin_amdgcn_mfma_f32_16x16x32_f16(a, b, c, 0, 0, 0);
}
DEV f16x8 ldf16(const u16* p) { return *(const f16x8*)p; }

DEV void gl2lds16(const u16* g, u16* l) {
  __builtin_amdgcn_global_load_lds((const __attribute__((address_space(1))) void*)g,
                                   (__attribute__((address_space(3))) void*)l, 16, 0, 0);
}

// LDS tile [rows][64 u16], XOR-swizzled: physical col = col ^ ((row&7)<<3).
DEV int swz(int row, int col) { return row * 64 + (col ^ ((row & 7) << 3)); }

// XCD-chunked remap (nwg % 8 == 0): each XCD owns a contiguous work chunk.
DEV int xcd_remap(int d, int nwg) { return (d & 7) * (nwg >> 3) + (d >> 3); }

// ---------------- all four weights: transpose fp32 -> fp16 in one launch ----------------
__global__ __launch_bounds__(256)
void wT_all_kernel(const float* __restrict__ Wq_t, const float* __restrict__ Wo_t,
                   const float* __restrict__ Wq_s, const float* __restrict__ Wo_s,
                   u16* __restrict__ Tq_t, u16* __restrict__ To_t,
                   u16* __restrict__ Tq_s, u16* __restrict__ To_s) {
  const int bid = blockIdx.x;
  const float* W;
  u16* T;
  int N, base;
  if (bid < 768)       { W = Wq_t; T = Tq_t; N = 1536; base = bid; }
  else if (bid < 1024) { W = Wo_t; T = To_t; N = 512;  base = bid - 768; }
  else if (bid < 1792) { W = Wq_s; T = Tq_s; N = 1536; base = bid - 1024; }
  else                 { W = Wo_s; T = To_s; N = 512;  base = bid - 1792; }
#pragma unroll
  for (int j = 0; j < 4; ++j) {
    int i = base * 1024 + j * 256 + threadIdx.x;
    int n = i >> 9, k = i & 511;
    T[i] = f2h(W[(size_t)k * N + n]);
  }
}

// ---------------- fused LayerNorm (rows of 512 fp32) -> fp16 ----------------
__global__ __launch_bounds__(256)
void ln_kernel(const float* __restrict__ X, const float* __restrict__ G,
               const float* __restrict__ B, u16* __restrict__ H) {
  const int row = (blockIdx.x << 2) + (threadIdx.x >> 6);
  const int l = threadIdx.x & 63;
  const float* x = X + ((size_t)row << 9) + l * 8;
  float v[8];
  *(float4*)&v[0] = *(const float4*)(x);
  *(float4*)&v[4] = *(const float4*)(x + 4);
  float s = 0.f, s2 = 0.f;
#pragma unroll
  for (int e = 0; e < 8; ++e) { s += v[e]; s2 += v[e] * v[e]; }
#pragma unroll
  for (int o = 1; o < 64; o <<= 1) { s += __shfl_xor(s, o, 64); s2 += __shfl_xor(s2, o, 64); }
  const float mean = s * (1.f / 512.f);
  const float rs = rsqrtf(s2 * (1.f / 512.f) - mean * mean + 1e-5f);
  float g[8], bb[8];
  *(float4*)&g[0] = *(const float4*)(G + l * 8);
  *(float4*)&g[4] = *(const float4*)(G + l * 8 + 4);
  *(float4*)&bb[0] = *(const float4*)(B + l * 8);
  *(float4*)&bb[4] = *(const float4*)(B + l * 8 + 4);
  u16x8 o8;
#pragma unroll
  for (int e = 0; e < 8; ++e) o8[e] = f2h((v[e] - mean) * rs * g[e] + bb[e]);
  *(u16x8*)(H + ((size_t)row << 9) + l * 8) = o8;
}

// ---------------- LayerNorm on fp16 rows of 512 -> fp16 ----------------
__global__ __launch_bounds__(256)
void ln16_kernel(const u16* __restrict__ X, const float* __restrict__ G,
                 const float* __restrict__ B, u16* __restrict__ H) {
  const int row = (blockIdx.x << 2) + (threadIdx.x >> 6);
  const int l = threadIdx.x & 63;
  u16x8 raw = *(const u16x8*)(X + ((size_t)row << 9) + l * 8);
  float v[8];
#pragma unroll
  for (int e = 0; e < 8; ++e) v[e] = h2f(raw[e]);
  float s = 0.f, s2 = 0.f;
#pragma unroll
  for (int e = 0; e < 8; ++e) { s += v[e]; s2 += v[e] * v[e]; }
#pragma unroll
  for (int o = 1; o < 64; o <<= 1) { s += __shfl_xor(s, o, 64); s2 += __shfl_xor(s2, o, 64); }
  const float mean = s * (1.f / 512.f);
  const float rs = rsqrtf(s2 * (1.f / 512.f) - mean * mean + 1e-5f);
  float g[8], bb[8];
  *(float4*)&g[0] = *(const float4*)(G + l * 8);
  *(float4*)&g[4] = *(const float4*)(G + l * 8 + 4);
  *(float4*)&bb[0] = *(const float4*)(B + l * 8);
  *(float4*)&bb[4] = *(const float4*)(B + l * 8 + 4);
  u16x8 o8;
#pragma unroll
  for (int e = 0; e < 8; ++e) o8[e] = f2h((v[e] - mean) * rs * g[e] + bb[e]);
  *(u16x8*)(H + ((size_t)row << 9) + l * 8) = o8;
}

// ---------------- qkv GEMM: pure fp16, gl2lds both operands, LDS-bounce epilogue ----------
// VT=false: Cv = V rows [row][512].  VT=true: Cv = Vt [bt][512][1024], V written transposed.
template <bool VT, int K>
__global__ __launch_bounds__(256)
void gemm_qkv(const u16* __restrict__ A, const u16* __restrict__ Bt,
              u16* __restrict__ Cq, u16* __restrict__ Cv, int lda, int ldb) {
  __shared__ u16 lds[2 * 128 * 64];  // lsA | lsB; reused as epilogue bounce
  u16* lsA = lds;
  u16* lsB = lds + 128 * 64;
  const int tid = threadIdx.x;
  const int w = tid >> 6, l = tid & 63;
  const int lr = l & 15, lg = l >> 4;
  const int wm = w >> 1, wn = w & 1;
  const int gx = gridDim.x;
  const int wk = xcd_remap(blockIdx.y * gx + blockIdx.x, gx * gridDim.y);
  const int Row0 = (wk / gx) * 128, Col0 = (wk % gx) * 128;
  const int gcol = ((l & 7) ^ (l >> 3)) * 8;

  const int srow = w * 32 + (l >> 3);
  const u16* baseA = A + (size_t)(Row0 + srow) * lda + gcol;
  const u16* baseB = Bt + (size_t)(Col0 + srow) * ldb + gcol;

  f32x4 acc[4][4];
  const f32x4 zero = {0.f, 0.f, 0.f, 0.f};
#pragma unroll
  for (int m = 0; m < 4; ++m)
#pragma unroll
    for (int n = 0; n < 4; ++n) acc[m][n] = zero;

#pragma unroll
  for (int k0 = 0; k0 < K; k0 += 64) {
    __syncthreads();
#pragma unroll
    for (int i = 0; i < 4; ++i) {
      gl2lds16(baseA + (size_t)(i * 8) * lda + k0, &lsA[w * 2048 + i * 512]);
      gl2lds16(baseB + (size_t)(i * 8) * ldb + k0, &lsB[w * 2048 + i * 512]);
    }
    __syncthreads();
#pragma unroll
    for (int kk = 0; kk < 64; kk += 32) {
      f16x8 af[4], bfv[4];
#pragma unroll
      for (int m = 0; m < 4; ++m)
        af[m] = ldf16(&lsA[swz(wm * 64 + m * 16 + lr, kk + 8 * lg)]);
#pragma unroll
      for (int n = 0; n < 4; ++n)
        bfv[n] = ldf16(&lsB[swz(wn * 64 + n * 16 + lr, kk + 8 * lg)]);
#pragma unroll
      for (int m = 0; m < 4; ++m)
#pragma unroll
        for (int n = 0; n < 4; ++n) acc[m][n] = mfma_f16(af[m], bfv[n], acc[m][n]);
    }
  }

  const bool isV = (Col0 >= 1024);
  if (VT && isV) {
    // V written transposed: Vt[bt][d][c]; block tile = c-range [Row0&1023,+128) x d [Col0-1024,+128)
    const int bt = Row0 >> 10;
    const int c0 = Row0 & 1023;
    const int d0 = Col0 - 1024;
#pragma unroll
    for (int p = 0; p < 2; ++p) {
      __syncthreads();
      if (wm == p) {
#pragma unroll
        for (int m = 0; m < 4; ++m)
#pragma unroll
          for (int n = 0; n < 4; ++n) {
            int col = wn * 64 + n * 16 + lr;  // d_local
#pragma unroll
            for (int r = 0; r < 4; ++r)
              lds[col * 72 + m * 16 + lg * 4 + r] = f2h(acc[m][n][r]);  // T[d][c] pad 72
          }
      }
      __syncthreads();
#pragma unroll
      for (int it = 0; it < 4; ++it) {
        int cid = it * 256 + tid;
        int dl = cid >> 3, cc = (cid & 7) * 8;
        u16x8 vv = *(u16x8*)&lds[dl * 72 + cc];
        *(u16x8*)&Cv[(size_t)bt * 524288 + (size_t)(d0 + dl) * 1024 + c0 + p * 64 + cc] = vv;
      }
    }
    return;
  }
#pragma unroll
  for (int p = 0; p < 2; ++p) {
    __syncthreads();
    if (wm == p) {
#pragma unroll
      for (int m = 0; m < 4; ++m)
#pragma unroll
        for (int n = 0; n < 4; ++n) {
          int col = wn * 64 + n * 16 + lr;
#pragma unroll
          for (int r = 0; r < 4; ++r)
            lds[(m * 16 + lg * 4 + r) * 136 + col] = f2h(acc[m][n][r]);
        }
    }
    __syncthreads();
#pragma unroll
    for (int it = 0; it < 4; ++it) {
      int cid = it * 256 + tid;
      int rl = cid >> 4, cc = (cid & 15) * 8;
      u16x8 vv = *(u16x8*)&lds[rl * 136 + cc];
      int gr = Row0 + p * 64 + rl;
      int gc = Col0 + cc;
      if (!isV)
        *(u16x8*)&Cq[(size_t)gr * 1024 + gc] = vv;
      else
        *(u16x8*)&Cv[(size_t)gr * 512 + gc - 1024] = vv;
    }
  }
}

// ---------------- fp16 GEMM 128x128xK (unrolled), A[M,K], B^T[N,K], batched ----------------
// REMAP: 0 none, 1 = 2D XCD remap, 2 = 3D flatten+XCD remap (batched ops).
template <bool OUT16, int REMAP, int K>
__global__ __launch_bounds__(256)
void gemm_bt(const u16* __restrict__ A, const u16* __restrict__ Bt,
             void* __restrict__ Cp, const float* __restrict__ bias,
             int lda, int ldb, int ldc,
             long long sA, long long sB, long long sC, float scale) {
  __shared__ u16 lds[2 * 128 * 64];
  u16* lsA = lds;
  u16* lsB = lds + 128 * 64;
  const int tid = threadIdx.x;
  const int w = tid >> 6, l = tid & 63;
  const int lr = l & 15, lg = l >> 4;
  const int wm = w >> 1, wn = w & 1;
  int Row0, Col0, bz;
  if constexpr (REMAP == 1) {
    const int gx = gridDim.x;
    const int wk = xcd_remap(blockIdx.y * gx + blockIdx.x, gx * gridDim.y);
    Row0 = (wk / gx) * 128; Col0 = (wk % gx) * 128; bz = blockIdx.z;
  } else if constexpr (REMAP == 2) {
    const int gx = gridDim.x, gy = gridDim.y;
    const int d = blockIdx.x + gx * (blockIdx.y + gy * blockIdx.z);
    const int wk = xcd_remap(d, gx * gy * gridDim.z);
    Col0 = (wk % gx) * 128;
    int rest = wk / gx;
    Row0 = (rest % gy) * 128;
    bz = rest / gy;
  } else {
    Row0 = blockIdx.y * 128; Col0 = blockIdx.x * 128; bz = blockIdx.z;
  }
  const int gcol = ((l & 7) ^ (l >> 3)) * 8;

  const int srow = w * 32 + (l >> 3);
  const u16* baseA = A + (size_t)bz * sA + (size_t)(Row0 + srow) * lda + gcol;
  const u16* baseB = Bt + (size_t)bz * sB + (size_t)(Col0 + srow) * ldb + gcol;

  f32x4 acc[4][4];
  const f32x4 zero = {0.f, 0.f, 0.f, 0.f};
#pragma unroll
  for (int m = 0; m < 4; ++m)
#pragma unroll
    for (int n = 0; n < 4; ++n) acc[m][n] = zero;

#pragma unroll
  for (int k0 = 0; k0 < K; k0 += 64) {
    __syncthreads();
#pragma unroll
    for (int i = 0; i < 4; ++i) {
      gl2lds16(baseA + (size_t)(i * 8) * lda + k0, &lsA[w * 2048 + i * 512]);
      gl2lds16(baseB + (size_t)(i * 8) * ldb + k0, &lsB[w * 2048 + i * 512]);
    }
    __syncthreads();
#pragma unroll
    for (int kk = 0; kk < 64; kk += 32) {
      f16x8 af[4], bfv[4];
#pragma unroll
      for (int m = 0; m < 4; ++m)
        af[m] = ldf16(&lsA[swz(wm * 64 + m * 16 + lr, kk + 8 * lg)]);
#pragma unroll
      for (int n = 0; n < 4; ++n)
        bfv[n] = ldf16(&lsB[swz(wn * 64 + n * 16 + lr, kk + 8 * lg)]);
#pragma unroll
      for (int m = 0; m < 4; ++m)
#pragma unroll
        for (int n = 0; n < 4; ++n) acc[m][n] = mfma_f16(af[m], bfv[n], acc[m][n]);
    }
  }

  if constexpr (OUT16) {
    u16* Cb = (u16*)Cp + (size_t)bz * sC;
#pragma unroll
    for (int p = 0; p < 2; ++p) {
      __syncthreads();
      if (wm == p) {
#pragma unroll
        for (int m = 0; m < 4; ++m)
#pragma unroll
          for (int n = 0; n < 4; ++n) {
            int col = wn * 64 + n * 16 + lr;
            float bv = bias ? bias[Col0 + col] : 0.f;
#pragma unroll
            for (int r = 0; r < 4; ++r)
              lds[(m * 16 + lg * 4 + r) * 136 + col] = f2h(acc[m][n][r] * scale + bv);
          }
      }
      __syncthreads();
#pragma unroll
      for (int it = 0; it < 4; ++it) {
        int cid = it * 256 + tid;
        int rl = cid >> 4, cc = (cid & 15) * 8;
        u16x8 vv = *(u16x8*)&lds[rl * 136 + cc];
        *(u16x8*)&Cb[(size_t)(Row0 + p * 64 + rl) * ldc + Col0 + cc] = vv;
      }
    }
  } else {
    float* Cb = (float*)Cp + (size_t)bz * sC;
    float* ldsF = (float*)lds;  // [32][132] fp32
#pragma unroll
    for (int q = 0; q < 4; ++q) {
      __syncthreads();
      if (wm == (q >> 1)) {
        int mBase = (q & 1) * 2;
#pragma unroll
        for (int mi = 0; mi < 2; ++mi) {
          int m = mBase + mi;
#pragma unroll
          for (int n = 0; n < 4; ++n) {
            int col = wn * 64 + n * 16 + lr;
            float bv = bias ? bias[Col0 + col] : 0.f;
#pragma unroll
            for (int r = 0; r < 4; ++r)
              ldsF[(mi * 16 + lg * 4 + r) * 132 + col] = acc[m][n][r] * scale + bv;
          }
        }
      }
      __syncthreads();
#pragma unroll
      for (int it = 0; it < 4; ++it) {
        int cid = it * 256 + tid;
        int rw = cid >> 5, c4 = (cid & 31) * 4;
        float4 v = *(float4*)&ldsF[rw * 132 + c4];
        *(float4*)&Cb[(size_t)(Row0 + q * 32 + rw) * ldc + Col0 + c4] = v;
      }
    }
  }
}

// ---------------- fused temporal attention (fp16), one block per (b,c) ----------------
__global__ __launch_bounds__(256)
void attn_t_kernel(const u16* __restrict__ QK, const u16* __restrict__ Vb,
                   u16* __restrict__ O) {
  __shared__ u16 qs[32 * 520];
  __shared__ u16 ks[32 * 520];
  __shared__ u16 vT[512 * 40];
  __shared__ float Sf[32 * 36];
  __shared__ u16 Pf[32 * 40];

  const int tid = threadIdx.x;
  const int bc = blockIdx.x;  // b*1024 + c
  const int w = tid >> 6, l = tid & 63, lr = l & 15, lg = l >> 4;
  const int wr = w >> 1, wc = w & 1;
  const size_t base = (size_t)(bc >> 10) * 32768 + (bc & 1023);

#pragma unroll
  for (int i = 0; i < 8; ++i) {
    int t = w * 8 + i;
    const u16* rb = QK + (base + (size_t)t * 1024) * 1024;
    gl2lds16(rb + l * 8, &qs[t * 520]);
    gl2lds16(rb + 512 + l * 8, &ks[t * 520]);
  }
  {  // V staging, t-major lanes: conflict-free vT writes
    const int t = tid & 31;
    const int db0 = (tid >> 5) * 8;
    const u16* vrow = Vb + (base + (size_t)t * 1024) * 512;
#pragma unroll
    for (int j = 0; j < 8; ++j) {
      int db = db0 + j;
      u16x8 vv = *(const u16x8*)(vrow + db * 8);
#pragma unroll
      for (int e = 0; e < 8; ++e) vT[(db * 8 + e) * 40 + t] = vv[e];
    }
  }
  __syncthreads();

  f32x4 sacc = {0.f, 0.f, 0.f, 0.f};
#pragma unroll
  for (int kk = 0; kk < 512; kk += 32)
    sacc = mfma_f16(ldf16(&qs[(wr * 16 + lr) * 520 + kk + 8 * lg]),
                    ldf16(&ks[(wc * 16 + lr) * 520 + kk + 8 * lg]), sacc);
#pragma unroll
  for (int r = 0; r < 4; ++r)
    Sf[(wr * 16 + lg * 4 + r) * 36 + wc * 16 + lr] = sacc[r] * 0.125f;
  __syncthreads();

  {  // parallel softmax: 8 threads per row
    const int row = tid >> 3, c0 = (tid & 7) * 4;
    float4 sv = *(float4*)&Sf[row * 36 + c0];
    float mx = fmaxf(fmaxf(sv.x, sv.y), fmaxf(sv.z, sv.w));
#pragma unroll
    for (int o = 1; o < 8; o <<= 1) mx = fmaxf(mx, __shfl_xor(mx, o, 64));
    float e0 = __expf(sv.x - mx), e1 = __expf(sv.y - mx);
    float e2 = __expf(sv.z - mx), e3 = __expf(sv.w - mx);
    float sum = e0 + e1 + e2 + e3;
#pragma unroll
    for (int o = 1; o < 8; o <<= 1) sum += __shfl_xor(sum, o, 64);
    float inv = 1.f / sum;
    u16x4 p4 = {f2h(e0 * inv), f2h(e1 * inv), f2h(e2 * inv), f2h(e3 * inv)};
    *(u16x4*)&Pf[row * 40 + c0] = p4;
  }
  __syncthreads();

  {  // O = P @ V, staged into qs for coalesced u16x8 stores
    const int mr = w >> 1, nh = w & 1;
    f16x8 ap = ldf16(&Pf[(mr * 16 + lr) * 40 + 8 * lg]);
#pragma unroll
    for (int j = 0; j < 16; ++j) {
      int nc = (nh * 16 + j) * 16;
      f32x4 o = {0.f, 0.f, 0.f, 0.f};
      o = mfma_f16(ap, ldf16(&vT[(nc + lr) * 40 + 8 * lg]), o);
#pragma unroll
      for (int r = 0; r < 4; ++r)
        qs[(mr * 16 + lg * 4 + r) * 520 + nc + lr] = f2h(o[r]);
    }
  }
  __syncthreads();
#pragma unroll
  for (int it = 0; it < 8; ++it) {
    int cid = it * 256 + tid;
    int t = cid >> 6, col = (cid & 63) * 8;
    u16x8 vv = *(u16x8*)&qs[t * 520 + col];
    *(u16x8*)&O[(base + (size_t)t * 1024) * 512 + col] = vv;
  }
}

// ---------------- row softmax over 1024 fp16, in place ----------------
__global__ __launch_bounds__(256)
void softmax16_kernel(u16* __restrict__ S) {
  u16* p = S + ((size_t)blockIdx.x << 10);
  const int tid = threadIdx.x, w = tid >> 6, l = tid & 63;
  __shared__ float red[8];
  u16x4 raw = *(u16x4*)&p[tid << 2];
  float v0 = h2f(raw[0]), v1 = h2f(raw[1]), v2 = h2f(raw[2]), v3 = h2f(raw[3]);
  float m = fmaxf(fmaxf(v0, v1), fmaxf(v2, v3));
#pragma unroll
  for (int o = 1; o < 64; o <<= 1) m = fmaxf(m, __shfl_xor(m, o, 64));
  if (l == 0) red[w] = m;
  __syncthreads();
  m = fmaxf(fmaxf(red[0], red[1]), fmaxf(red[2], red[3]));
  v0 = __expf(v0 - m); v1 = __expf(v1 - m); v2 = __expf(v2 - m); v3 = __expf(v3 - m);
  float s = v0 + v1 + v2 + v3;
#pragma unroll
  for (int o = 1; o < 64; o <<= 1) s += __shfl_xor(s, o, 64);
  if (l == 0) red[4 + w] = s;
  __syncthreads();
  const float inv = 1.f / (red[4] + red[5] + red[6] + red[7]);
  u16x4 o4 = {f2h(v0 * inv), f2h(v1 * inv), f2h(v2 * inv), f2h(v3 * inv)};
  *(u16x4*)&p[tid << 2] = o4;
}

extern "C" void kernel_launch(void* const* d_in, const int* in_sizes, int n_in,
                              void* d_out, int out_size, void* d_ws, size_t ws_size,
                              hipStream_t stream) {
  (void)in_sizes; (void)n_in; (void)out_size; (void)ws_size;
  const float* x      = (const float*)d_in[0];
  const float* gam_t  = (const float*)d_in[1];
  const float* bet_t  = (const float*)d_in[2];
  const float* wqkv_t = (const float*)d_in[3];
  const float* wout_t = (const float*)d_in[4];
  const float* bout_t = (const float*)d_in[5];
  const float* gam_s  = (const float*)d_in[6];
  const float* bet_s  = (const float*)d_in[7];
  const float* wqkv_s = (const float*)d_in[8];
  const float* wout_s = (const float*)d_in[9];
  const float* bout_s = (const float*)d_in[10];
  float* out = (float*)d_out;

  char* ws = (char*)d_ws;
  size_t off = 0;
  auto alloc = [&](size_t bytes) -> char* {
    char* p = ws + off;
    off = (off + bytes + 255) & ~(size_t)255;
    return p;
  };
  // Total ~324 MiB. Aliases: h = S region; out1 = QK first half; Vt reuses Vb slot.
  u16* wqkvT_t = (u16*)alloc((size_t)1536 * 512 * 2);
  u16* woutT_t = (u16*)alloc((size_t)512 * 512 * 2);
  u16* wqkvT_s = (u16*)alloc((size_t)1536 * 512 * 2);
  u16* woutT_s = (u16*)alloc((size_t)512 * 512 * 2);
  u16* QK      = (u16*)alloc((size_t)65536 * 1024 * 2);      // 128 MiB
  u16* Vb      = (u16*)alloc((size_t)65536 * 512 * 2);       //  64 MiB (temporal V / spatial Vt)
  u16* attnO   = (u16*)alloc((size_t)65536 * 512 * 2);       //  64 MiB
  u16* S       = (u16*)alloc((size_t)32 * 1024 * 1024 * 2);  //  64 MiB (32-batch chunk)
  u16* h       = S;    // LN output (64 MiB), dead before S is written
  u16* out1    = QK;   // temporal block output fp16 (64 MiB)
  u16* Vt      = Vb;   // spatial V transposed [bt][512][1024]

  const dim3 blk(256);

  wT_all_kernel<<<2048, blk, 0, stream>>>(wqkv_t, wout_t, wqkv_s, wout_s,
                                          wqkvT_t, woutT_t, wqkvT_s, woutT_s);

  // ---- temporal ----
  ln_kernel<<<16384, blk, 0, stream>>>(x, gam_t, bet_t, h);
  gemm_qkv<false, 512><<<dim3(12, 512, 1), blk, 0, stream>>>(h, wqkvT_t, QK, Vb, 512, 512);
  attn_t_kernel<<<2048, blk, 0, stream>>>(QK, Vb, attnO);
  gemm_bt<true, 1, 512><<<dim3(4, 512, 1), blk, 0, stream>>>(
      attnO, woutT_t, out1, bout_t, 512, 512, 512, 0, 0, 0, 1.f);

  // ---- spatial ----
  ln16_kernel<<<16384, blk, 0, stream>>>(out1, gam_s, bet_s, h);
  gemm_qkv<true, 512><<<dim3(12, 512, 1), blk, 0, stream>>>(h, wqkvT_s, QK, Vt, 512, 512);

  for (int ch = 0; ch < 2; ++ch) {  // 32 (b,t) batches per chunk
    const u16* qkc = QK + (size_t)ch * 32 * 1024 * 1024;
    const u16* vtc = Vt + (size_t)ch * 32 * 512 * 1024;
    u16* attc = attnO + (size_t)ch * 32 * 1024 * 512;
    gemm_bt<true, 2, 512><<<dim3(8, 8, 32), blk, 0, stream>>>(
        qkc, qkc + 512, S, nullptr, 1024, 1024, 1024,
        1024LL * 1024, 1024LL * 1024, 1024LL * 1024, 0.125f);
    softmax16_kernel<<<32768, blk, 0, stream>>>(S);
    gemm_bt<true, 2, 1024><<<dim3(4, 8, 32), blk, 0, stream>>>(
        S, vtc, attc, nullptr, 1024, 1024, 512,
        1024LL * 1024, 512LL * 1024, 1024LL * 512, 1.f);
  }

  gemm_bt<false, 1, 512><<<dim3(4, 512, 1), blk, 0, stream>>>(
      attnO, woutT_s, out, bout_s, 512, 512, 512, 0, 0, 0, 1.f);
}